// Round 17
// baseline (789.847 us; speedup 1.0000x reference)
//
#include <hip/hip_runtime.h>
#include <hip/hip_bf16.h>

#define B_   4
#define L_   2048
#define DM   512
#define DI   1024
#define NST  16
#define DTR  32
#define ROWS  (B_ * L_)        // 8192
#define ROWS2 (2 * ROWS)       // 16384 (both directions)
#define NCHUNK 64
#define CLEN  (L_ / NCHUNK)    // 32
#define LN2R 1.4426950408889634f

typedef unsigned short u16;
typedef __attribute__((ext_vector_type(8))) short bf16x8;
typedef __attribute__((ext_vector_type(4))) float f32x4;
typedef __attribute__((ext_vector_type(4))) float float4v;
typedef __attribute__((ext_vector_type(2))) float f32x2;

__device__ __forceinline__ float bf2f(u16 h) {
  union { unsigned int u; float f; } v; v.u = ((unsigned int)h) << 16; return v.f;
}
__device__ __forceinline__ u16 f2bf(float f) {
  union { float f; unsigned int u; } v; v.f = f;
  unsigned int u = v.u;
  if ((u & 0x7fffffffu) > 0x7f800000u) return (u16)((u >> 16) | 0x0040u);
  return (u16)((u + 0x7fffu + ((u >> 16) & 1u)) >> 16);
}
__device__ __forceinline__ float sigmoidf_(float x) { return 1.f / (1.f + __expf(-x)); }

__device__ __forceinline__ f32x2 pk_mul(f32x2 a, f32x2 b) {
  f32x2 d; asm("v_pk_mul_f32 %0, %1, %2" : "=v"(d) : "v"(a), "v"(b)); return d;
}
__device__ __forceinline__ f32x2 pk_fma(f32x2 a, f32x2 b, f32x2 c) {
  f32x2 d; asm("v_pk_fma_f32 %0, %1, %2, %3" : "=v"(d) : "v"(a), "v"(b), "v"(c)); return d;
}

__device__ __forceinline__ void gload16(const u16* g, u16* l) {
  __builtin_amdgcn_global_load_lds(
      (const __attribute__((address_space(1))) void*)g,
      (__attribute__((address_space(3))) void*)l, 16, 0, 0);
}

// ---------------- f32 -> bf16 weight conversion ----------------
__global__ __launch_bounds__(256) void cvt_k(const float* __restrict__ in,
                                             u16* __restrict__ out, int n4) {
  int i = blockIdx.x * 256 + threadIdx.x;
  if (i >= n4) return;
  float4v v = *(const float4v*)&in[i * 4];
  u16 o[4];
  o[0] = f2bf(v.x); o[1] = f2bf(v.y); o[2] = f2bf(v.z); o[3] = f2bf(v.w);
  *(ulong1*)&out[i * 4] = *(ulong1*)o;
}

// ---------------- dt_w transpose: [4][DI][DTR] -> [4][DTR][DI] (f32) ----------------
__global__ __launch_bounds__(256) void trp_k(const float* __restrict__ in,
                                             float* __restrict__ out) {
  int o = blockIdx.x * 256 + threadIdx.x;
  int li = o >> 15;
  int k = (o >> 10) & (DTR - 1);
  int d = o & (DI - 1);
  out[o] = in[((size_t)li * DI + d) * DTR + k];
}

// ---------------- embed gather, both directions ----------------
__global__ __launch_bounds__(256) void embed_k(const int* __restrict__ ids,
                                               const float* __restrict__ emb,
                                               float* __restrict__ res) {
  int idx = blockIdx.x * 256 + threadIdx.x;   // ROWS2*DM
  int c = idx & (DM - 1);
  int row = idx >> 9;                          // 0..16383
  int dir = row >> 13;
  int r = row & (ROWS - 1);
  int b = r >> 11;
  int l = r & (L_ - 1);
  int sl = dir ? (L_ - 1 - l) : l;
  int id = ids[(b << 11) + sl];
  res[idx] = emb[(size_t)dir * 128 * DM + id * DM + c];
}

// ---------------- (res += hid); xn = rmsnorm(res) * w (per-dir weights) ----------------
template <bool ADD>
__global__ __launch_bounds__(256) void addnorm_k(float* __restrict__ res,
                                                 const float* __restrict__ hid,
                                                 const float* __restrict__ norm_w,
                                                 int layer,
                                                 u16* __restrict__ xn) {
  int row = blockIdx.x;                        // 0..16383
  int dir = row >> 13;
  const float* w = norm_w + (size_t)(dir * 2 + layer) * DM;
  int tid = threadIdx.x;
  int base = row * DM;
  float x0 = res[base + tid];
  float x1 = res[base + 256 + tid];
  if (ADD) {
    x0 += hid[base + tid];
    x1 += hid[base + 256 + tid];
    res[base + tid] = x0;
    res[base + 256 + tid] = x1;
  }
  float s = x0 * x0 + x1 * x1;
  for (int off = 32; off; off >>= 1) s += __shfl_xor(s, off);
  __shared__ float ps[4];
  if (!(tid & 63)) ps[tid >> 6] = s;
  __syncthreads();
  float tot = ps[0] + ps[1] + ps[2] + ps[3];
  float rs = 1.f / sqrtf(tot / (float)DM + 1e-5f);
  xn[base + tid]       = f2bf(x0 * rs * w[tid]);
  xn[base + 256 + tid] = f2bf(x1 * rs * w[tid + 256]);
}

// ---------------- in_proj: 256x256 tile, BK=32, 2 buffers (64 kB LDS -> 2 blk/CU) ----------------
#define MFMA_B16(a, b, c) __builtin_amdgcn_mfma_f32_16x16x32_bf16(a, b, c, 0, 0, 0)

__global__ __launch_bounds__(512) void g256_k(const u16* __restrict__ A,
                                              const u16* __restrict__ W,   // layer base (dir0)
                                              u16* __restrict__ outU,
                                              u16* __restrict__ outZ,
                                              int K) {
  __shared__ u16 As[2][256 * 32];   // 32 kB
  __shared__ u16 Wsh[2][256 * 32];  // 32 kB
  int tid = threadIdx.x;
  int lane = tid & 63;
  int wv = tid >> 6;
  int wr = wv >> 2, wc = wv & 3;    // 2M x 4N waves
  int bid = blockIdx.x;             // 512 blocks: 64 mt x 8 nt
  int xcd = bid & 7, jj = bid >> 3;
  int mt = xcd * 8 + (jj & 7);      // 0..63
  int nt = jj >> 3;                 // 0..7
  int m0 = mt * 256, n0 = nt * 256;
  const u16* Weff = W + (size_t)(m0 >> 13) * (size_t)2 * (2 * DI) * DM;
  f32x4 acc[8][4];
#pragma unroll
  for (int i = 0; i < 8; ++i)
#pragma unroll
    for (int j = 0; j < 4; ++j) acc[i][j] = (f32x4){0.f, 0.f, 0.f, 0.f};
  int rr = lane & 15;
  int sl = lane >> 4;
  int pofs = ((sl + (rr >> 1)) & 3) * 8;    // conflict-free swizzled read slot
  int lr = lane >> 2;
  int ls = ((lane & 3) - (lr >> 1)) & 3;    // matching pre-swizzled source slot

  auto stage = [&](int tau, int buf) {
#pragma unroll
    for (int j = 0; j < 2; ++j) {
      gload16(A + (size_t)(m0 + j * 128 + wv * 16 + lr) * K + tau * 32 + ls * 8,
              &As[buf][(j * 128 + wv * 16) * 32]);
      gload16(Weff + (size_t)(n0 + j * 128 + wv * 16 + lr) * K + tau * 32 + ls * 8,
              &Wsh[buf][(j * 128 + wv * 16) * 32]);
    }
  };

  int NK = K / 32;                  // 16
  stage(0, 0);
  for (int tau = 0; tau < NK; ++tau) {
    int buf = tau & 1;
    bool more = (tau + 1 < NK);
    if (more) stage(tau + 1, buf ^ 1);
    if (more)
      asm volatile("s_waitcnt vmcnt(4)" ::: "memory");
    else
      asm volatile("s_waitcnt vmcnt(0)" ::: "memory");
    __builtin_amdgcn_sched_barrier(0);
    __builtin_amdgcn_s_barrier();
    __builtin_amdgcn_sched_barrier(0);
    bf16x8 af[8], wf[4];
#pragma unroll
    for (int mi = 0; mi < 8; ++mi)
      af[mi] = *(bf16x8*)&As[buf][(wr * 128 + mi * 16 + rr) * 32 + pofs];
#pragma unroll
    for (int ni = 0; ni < 4; ++ni)
      wf[ni] = *(bf16x8*)&Wsh[buf][(wc * 64 + ni * 16 + rr) * 32 + pofs];
    __builtin_amdgcn_s_setprio(1);
#pragma unroll
    for (int mi = 0; mi < 8; ++mi)
#pragma unroll
      for (int ni = 0; ni < 4; ++ni)
        acc[mi][ni] = MFMA_B16(af[mi], wf[ni], acc[mi][ni]);
    __builtin_amdgcn_s_setprio(0);
    asm volatile("s_waitcnt lgkmcnt(0)" ::: "memory");
    __builtin_amdgcn_sched_barrier(0);
    __builtin_amdgcn_s_barrier();
    __builtin_amdgcn_sched_barrier(0);
  }
  int cr = (lane >> 4) << 2;
  int cc = lane & 15;
  u16* outp = (n0 < DI) ? outU : outZ;
  int cb0 = (n0 < DI) ? n0 : (n0 - DI);
#pragma unroll
  for (int mi = 0; mi < 8; ++mi)
#pragma unroll
    for (int ni = 0; ni < 4; ++ni) {
      int row = m0 + wr * 128 + mi * 16 + cr;
      int col = cb0 + wc * 64 + ni * 16 + cc;
#pragma unroll
      for (int j = 0; j < 4; ++j)
        outp[(size_t)(row + j) * DI + col] = f2bf(acc[mi][ni][j]);
    }
}

// ---------------- GEMM (generic): 4-ring, stage-ahead-3, per-dir weight stride ----------------
#define EPI_F32  0
#define EPI_BF16 1
#define EPI_BIAS 2

template <int BN, int EPI, int SK = 1>
__global__ __launch_bounds__(256) void gemm_bt(const u16* __restrict__ A,
                                               const u16* __restrict__ W,
                                               void* __restrict__ outp,
                                               const float* __restrict__ bias,
                                               int N, int K, size_t wsd) {
  constexpr int BM = 128, BK = 32;
  constexpr int NF = BN / 32;
  constexpr int G = (BN == 128) ? 4 : 3;
  __shared__ u16 As[4][BM * BK];
  __shared__ u16 Wsh[4][BN * BK];
  int tid = threadIdx.x;
  int lane = tid & 63;
  int wv = tid >> 6;
  int wr = wv >> 1, wc = wv & 1;
  int m0 = blockIdx.x * BM;
  int n0 = (SK > 1) ? 0 : blockIdx.y * BN;
  int koff = (SK > 1) ? blockIdx.y * (K / SK) : 0;
  int KS = K / SK;
  int NK = KS / BK;
  const u16* Weff = W + (size_t)(m0 >> 13) * wsd;
  f32x4 acc[4][NF];
#pragma unroll
  for (int i = 0; i < 4; ++i)
#pragma unroll
    for (int j = 0; j < NF; ++j) acc[i][j] = (f32x4){0.f, 0.f, 0.f, 0.f};
  int rr = lane & 15;
  int kk = (lane >> 4) << 3;
  int l4 = lane >> 2;
  int c8 = (lane & 3) << 3;
  const u16* Ag = A + (size_t)(m0 + l4) * K + koff + c8;
  const u16* Wg = Weff + (size_t)(n0 + l4) * K + koff + c8;

  auto stage = [&](int k0, int buf) {
    gload16(Ag + (size_t)(wv * 16) * K + k0, &As[buf][wv * 512]);
    gload16(Ag + (size_t)((wv + 4) * 16) * K + k0, &As[buf][(wv + 4) * 512]);
    gload16(Wg + (size_t)(wv * 16) * K + k0, &Wsh[buf][wv * 512]);
    if (BN == 128)
      gload16(Wg + (size_t)((wv + 4) * 16) * K + k0, &Wsh[buf][(wv + 4) * 512]);
  };

  stage(0, 0); stage(BK, 1); stage(2 * BK, 2);
  for (int k = 0; k < NK; ++k) {
    if (k < NK - 2)
      asm volatile("s_waitcnt vmcnt(%0)" :: "n"(2 * G) : "memory");
    else if (k == NK - 2)
      asm volatile("s_waitcnt vmcnt(%0)" :: "n"(G) : "memory");
    else
      asm volatile("s_waitcnt vmcnt(0)" ::: "memory");
    __builtin_amdgcn_s_barrier();
    __builtin_amdgcn_sched_barrier(0);
    if (k + 3 < NK) stage((k + 3) * BK, (k + 3) & 3);
    __builtin_amdgcn_sched_barrier(0);
    int cur = k & 3;
    bf16x8 af[4], wf[NF];
#pragma unroll
    for (int mi = 0; mi < 4; ++mi)
      af[mi] = *(bf16x8*)&As[cur][(wr * 64 + mi * 16 + rr) * BK + kk];
#pragma unroll
    for (int ni = 0; ni < NF; ++ni)
      wf[ni] = *(bf16x8*)&Wsh[cur][(wc * (BN / 2) + ni * 16 + rr) * BK + kk];
#pragma unroll
    for (int mi = 0; mi < 4; ++mi)
#pragma unroll
      for (int ni = 0; ni < NF; ++ni)
        acc[mi][ni] = __builtin_amdgcn_mfma_f32_16x16x32_bf16(af[mi], wf[ni], acc[mi][ni], 0, 0, 0);
  }
  int cr = (lane >> 4) << 2;
  int cc = lane & 15;
  float* outF = (float*)outp +
      ((SK > 1) ? (size_t)blockIdx.y * (size_t)gridDim.x * BM * N : 0);
#pragma unroll
  for (int mi = 0; mi < 4; ++mi)
#pragma unroll
    for (int ni = 0; ni < NF; ++ni) {
      int row = m0 + wr * 64 + mi * 16 + cr;
      int col = n0 + wc * (BN / 2) + ni * 16 + cc;
      float bv = (EPI == EPI_BIAS) ? bias[col] : 0.f;
#pragma unroll
      for (int j = 0; j < 4; ++j) {
        float v = acc[mi][ni][j] + bv;
        if (EPI == EPI_BF16)
          ((u16*)outp)[(size_t)(row + j) * N + col] = f2bf(v);
        else
          outF[(size_t)(row + j) * N + col] = v;
      }
    }
}

// ---------------- depthwise causal conv + SiLU, both dirs ----------------
__global__ __launch_bounds__(256) void conv_k(const u16* __restrict__ xzu,
                                              const float* __restrict__ conv_w,
                                              const float* __restrict__ conv_b,
                                              int layer,
                                              u16* __restrict__ uh) {
  int idx = blockIdx.x * 256 + threadIdx.x;        // ROWS2*DI
  int c = idx & (DI - 1);
  int row = idx >> 10;
  int dir = row >> 13;
  int l = row & (L_ - 1);
  const float* cw = conv_w + (size_t)(dir * 2 + layer) * DI * 4;
  const float* cb = conv_b + (size_t)(dir * 2 + layer) * DI;
  float acc = cb[c];
#pragma unroll
  for (int j = 0; j < 4; ++j) {
    int ls = l + j - 3;
    if (ls >= 0)
      acc += bf2f(xzu[(size_t)(row + j - 3) * DI + c]) * cw[c * 4 + j];
  }
  float s = acc * sigmoidf_(acc);
  uh[idx] = f2bf(s);
}

// A-structure check
__device__ __forceinline__ bool a_fast(const float* alog, int d, float& a20) {
  a20 = -__expf(alog[d * NST]) * LN2R;
  bool fast = true;
#pragma unroll
  for (int n = 1; n < NST; ++n) {
    float an = -__expf(alog[d * NST + n]) * LN2R;
    fast &= (fabsf(an - (float)(n + 1) * a20) <= 1e-5f * (float)(n + 1) * fabsf(a20));
  }
  return fast;
}

// stage xs[CLEN][64] by summing 4 x_proj split-K partials (rowbase in rows)
__device__ __forceinline__ void stage_xs(float (*xs)[64], const float* xp,
                                         size_t rowbase, int tid) {
  size_t base = rowbase * 64;
  const float4v* s0 = (const float4v*)(xp + base);
  const float4v* s1 = (const float4v*)(xp + (size_t)ROWS2 * 64 + base);
  const float4v* s2 = (const float4v*)(xp + (size_t)2 * ROWS2 * 64 + base);
  const float4v* s3 = (const float4v*)(xp + (size_t)3 * ROWS2 * 64 + base);
  float4v* dst = (float4v*)&xs[0][0];
#pragma unroll
  for (int i = 0; i < CLEN / 16; ++i)
    dst[tid + i * 256] = s0[tid + i * 256] + s1[tid + i * 256] +
                         s2[tid + i * 256] + s3[tid + i * 256];
}

// dt = softplus(dot(xs[t][0..31], w2) + bias), 4 independent accumulator chains
__device__ __forceinline__ float dt_of(const float (*xs)[64], int t,
                                       const f32x2* w2, float bias) {
  const f32x2* x = (const f32x2*)&xs[t][0];
  f32x2 a0 = {bias, 0.f}, a1 = {0.f, 0.f}, a2 = {0.f, 0.f}, a3 = {0.f, 0.f};
#pragma unroll
  for (int j = 0; j < 4; ++j) {
    a0 = pk_fma(x[4 * j],     w2[4 * j],     a0);
    a1 = pk_fma(x[4 * j + 1], w2[4 * j + 1], a1);
    a2 = pk_fma(x[4 * j + 2], w2[4 * j + 2], a2);
    a3 = pk_fma(x[4 * j + 3], w2[4 * j + 3], a3);
  }
  float a = (a0.x + a0.y) + (a1.x + a1.y) + ((a2.x + a2.y) + (a3.x + a3.y));
  return (a > 15.f) ? a : __logf(1.f + __expf(a));
}

// ---------------- pass 1: dt + local scan + y_loc + S (both dirs) ----------------
// chk stored bf16 (a-half at [idx], h-half at [H+idx]).
__global__ __launch_bounds__(256) void dtscan1_k(u16* uS,
                                                 const float* __restrict__ xp,
                                                 const float* __restrict__ dtw_t,
                                                 const float* __restrict__ dtb,
                                                 const float* __restrict__ alog_,
                                                 const float* __restrict__ Dp,
                                                 int layer,
                                                 u16* __restrict__ ylg,
                                                 u16* __restrict__ chk) {
  __shared__ float xs[CLEN][64];                  // 8 kB
  int blk = blockIdx.x;            // 2048 = nb(8) x chunks(64) x dgroup(4)
  int db = blk & 3;
  int c  = (blk >> 2) & (NCHUNK - 1);
  int nb = blk >> 8;               // dir*4 + b
  int dir = nb >> 2;
  int tid = threadIdx.x;
  int d  = db * 256 + tid;
  int li = dir * 2 + layer;
  const float* dtwT = dtw_t + (size_t)li * DTR * DI;
  const float* alog = alog_ + (size_t)li * DI * NST;
  int t0 = c * CLEN;
  size_t rowbase = (size_t)nb * L_ + t0;
  stage_xs(xs, xp, rowbase, tid);
  f32x2 w2[16];
#pragma unroll
  for (int j = 0; j < 16; ++j)
    w2[j] = (f32x2){dtwT[(size_t)(2 * j) * DI + d], dtwT[(size_t)(2 * j + 1) * DI + d]};
  float bias = dtb[(size_t)li * DI + d];
  float Dv = Dp[(size_t)li * DI + d];
  float a20;
  bool fast = a_fast(alog, d, a20);
  __syncthreads();
  float S = 0.f;
  size_t ubase = rowbase * DI + d;
  f32x2 h2[8];
#pragma unroll
  for (int q = 0; q < 8; ++q) h2[q] = (f32x2){0.f, 0.f};
  float uv = bf2f(uS[ubase]);
  for (int t = 0; t < CLEN; ++t) {
    float uv_nx = (t + 1 < CLEN) ? bf2f(uS[ubase + DI]) : 0.f;
    float dtv = dt_of(xs, t, w2, bias);
    float du = dtv * uv;
    S += dtv;
    f32x2 accA = {0.f, 0.f}, accB = {0.f, 0.f};
    if (fast) {
      float p1 = exp2f(dtv * a20);
      float p2 = p1 * p1;
      f32x2 pw = {p1, p2};
      f32x2 pst = {p2, p2};
      f32x2 du2 = {du, du};
#pragma unroll
      for (int k = 0; k < 4; ++k) {
        f32x4 bv = *(const f32x4*)&xs[t][DTR + k * 4];
        f32x4 cv = *(const f32x4*)&xs[t][DTR + NST + k * 4];
        f32x2 blo = __builtin_shufflevector(bv, bv, 0, 1);
        f32x2 bhi = __builtin_shufflevector(bv, bv, 2, 3);
        f32x2 clo = __builtin_shufflevector(cv, cv, 0, 1);
        f32x2 chi = __builtin_shufflevector(cv, cv, 2, 3);
        h2[2 * k]     = pk_fma(pw, h2[2 * k], pk_mul(du2, blo));
        accA          = pk_fma(h2[2 * k], clo, accA);
        pw = pk_mul(pw, pst);
        h2[2 * k + 1] = pk_fma(pw, h2[2 * k + 1], pk_mul(du2, bhi));
        accB          = pk_fma(h2[2 * k + 1], chi, accB);
        if (k < 3) pw = pk_mul(pw, pst);
      }
    } else {
#pragma unroll
      for (int q = 0; q < 8; ++q) {
        float e0 = exp2f(dtv * -__expf(alog[d * NST + 2 * q]) * LN2R);
        float e1 = exp2f(dtv * -__expf(alog[d * NST + 2 * q + 1]) * LN2R);
        f32x2 bv = *(const f32x2*)&xs[t][DTR + q * 2];
        f32x2 cv = *(const f32x2*)&xs[t][DTR + NST + q * 2];
        h2[q] = pk_fma((f32x2){e0, e1}, h2[q], pk_mul((f32x2){du, du}, bv));
        if (q & 1) accB = pk_fma(h2[q], cv, accB);
        else       accA = pk_fma(h2[q], cv, accA);
      }
    }
    float yloc = (accA.x + accA.y) + (accB.x + accB.y) + uv * Dv;
    ylg[ubase] = f2bf(yloc);
    uS[ubase]  = f2bf(S);          // after uv read; same thread, same slot
    uv = uv_nx;
    ubase += DI;
  }
  const size_t H = (size_t)8 * NCHUNK * DI * NST;
  size_t idx = ((size_t)(nb * NCHUNK + c) * DI + d) * NST;
#pragma unroll
  for (int n = 0; n < NST; ++n) {
    float an = -__expf(alog[d * NST + n]) * LN2R;
    chk[idx + n]     = f2bf(exp2f(an * S));
    chk[H + idx + n] = f2bf((n & 1) ? h2[n >> 1].y : h2[n >> 1].x);
  }
}

// pass 2: sequential chunk combine (both dirs), bf16 records, f32 accumulate
__global__ __launch_bounds__(256) void scan2_k(u16* __restrict__ chk) {
  int j = blockIdx.x * 256 + threadIdx.x;   // 131072 = 8*DI*NST
  int n = j & 15;
  int d = (j >> 4) & (DI - 1);
  int nb = j >> 14;
  const size_t H = (size_t)8 * NCHUNK * DI * NST;
  float h = 0.f;
  for (int c = 0; c < NCHUNK; ++c) {
    size_t idx = ((size_t)(nb * NCHUNK + c) * DI + d) * NST + n;
    float a = bf2f(chk[idx]);
    float hl = bf2f(chk[H + idx]);
    chk[H + idx] = f2bf(h);
    h = a * h + hl;
  }
}

// pass 3 (lite): y = y_loc + sum_n C_t[n]*exp2(A2[n]*S_t)*h0[n]; fused gate.
__global__ __launch_bounds__(256) void scan3lite_k(const u16* __restrict__ uS,
                                                   const float* __restrict__ xp,
                                                   const float* __restrict__ alog_,
                                                   int layer,
                                                   const u16* __restrict__ chk,
                                                   const u16* __restrict__ xzz,
                                                   u16* ylg) {
  __shared__ float xc[CLEN][NST];                 // 2 kB: C columns only
  int blk = blockIdx.x;
  int db = blk & 3;
  int c  = (blk >> 2) & (NCHUNK - 1);
  int nb = blk >> 8;
  int dir = nb >> 2;
  int tid = threadIdx.x;
  int d  = db * 256 + tid;
  int li = dir * 2 + layer;
  const float* alog = alog_ + (size_t)li * DI * NST;
  int t0 = c * CLEN;
  size_t rowbase = (size_t)nb * L_ + t0;
  if (tid < CLEN * 4) {
    int r = tid >> 2, v = tid & 3;                // CLEN rows x 4 vec4
    size_t base = (rowbase + r) * 64 + DTR + NST + v * 4;
    float4v s = *(const float4v*)(xp + base)
              + *(const float4v*)(xp + (size_t)ROWS2 * 64 + base)
              + *(const float4v*)(xp + (size_t)2 * ROWS2 * 64 + base)
              + *(const float4v*)(xp + (size_t)3 * ROWS2 * 64 + base);
    *(float4v*)&xc[r][v * 4] = s;
  }
  float a20;
  bool fast = a_fast(alog, d, a20);
  const size_t H = (size_t)8 * NCHUNK * DI * NST;
  size_t cidx = ((size_t)(nb * NCHUNK + c) * DI + d) * NST;
  f32x2 h2[8];
#pragma unroll
  for (int q = 0; q < 8; ++q)
    h2[q] = (f32x2){bf2f(chk[H + cidx + 2 * q]), bf2f(chk[H + cidx + 2 * q + 1])};
  float A2g[NST];
  if (!fast) {
#pragma unroll
    for (int n = 0; n < NST; ++n) A2g[n] = -__expf(alog[d * NST + n]) * LN2R;
  }
  __syncthreads();
  size_t ubase = rowbase * DI + d;
  float S = bf2f(uS[ubase]);
  for (int t = 0; t < CLEN; ++t) {
    float S_nx = (t + 1 < CLEN) ? bf2f(uS[ubase + DI]) : 0.f;
    f32x2 corrA = {0.f, 0.f}, corrB = {0.f, 0.f};
    if (fast) {
      float w1 = exp2f(a20 * S);
      float w2_ = w1 * w1;
      f32x2 pw = {w1, w2_};
      f32x2 pst = {w2_, w2_};
#pragma unroll
      for (int q = 0; q < 8; ++q) {
        f32x2 cp = *(const f32x2*)&xc[t][2 * q];
        if (q & 1) corrB = pk_fma(pk_mul(pw, h2[q]), cp, corrB);
        else       corrA = pk_fma(pk_mul(pw, h2[q]), cp, corrA);
        if (q < 7) pw = pk_mul(pw, pst);
      }
    } else {
#pragma unroll
      for (int q = 0; q < 8; ++q) {
        f32x2 e = {exp2f(A2g[2 * q] * S), exp2f(A2g[2 * q + 1] * S)};
        f32x2 cp = *(const f32x2*)&xc[t][2 * q];
        if (q & 1) corrB = pk_fma(pk_mul(e, h2[q]), cp, corrB);
        else       corrA = pk_fma(pk_mul(e, h2[q]), cp, corrA);
      }
    }
    float y = bf2f(ylg[ubase]) + (corrA.x + corrA.y) + (corrB.x + corrB.y);
    float z = bf2f(xzz[ubase]);
    ylg[ubase] = f2bf(y * z * sigmoidf_(z));
    S = S_nx;
    ubase += DI;
  }
}

// ---------------- final rmsnorm(hid+res) -> concat buffer, both dirs ----------------
__global__ __launch_bounds__(256) void fincat_k(const float* __restrict__ hid,
                                                const float* __restrict__ res,
                                                const float* __restrict__ norm_f,
                                                u16* __restrict__ cat) {
  int row = blockIdx.x;                 // 0..16383
  int dir = row >> 13;
  const float* w = norm_f + (size_t)dir * DM;
  int tid = threadIdx.x;
  int base = row * DM;
  float x0 = hid[base + tid] + res[base + tid];
  float x1 = hid[base + 256 + tid] + res[base + 256 + tid];
  float s = x0 * x0 + x1 * x1;
  for (int off = 32; off; off >>= 1) s += __shfl_xor(s, off);
  __shared__ float ps[4];
  if (!(tid & 63)) ps[tid >> 6] = s;
  __syncthreads();
  float tot = ps[0] + ps[1] + ps[2] + ps[3];
  float rs = 1.f / sqrtf(tot / (float)DM + 1e-5f);
  int r = row & (ROWS - 1);
  int b = r >> 11, l = r & (L_ - 1);
  size_t drow = dir ? ((size_t)(b << 11) + (L_ - 1 - l)) : (size_t)r;
  size_t obase = drow * (2 * DM) + (size_t)dir * DM;
  cat[obase + tid]       = f2bf(x0 * rs * w[tid]);
  cat[obase + 256 + tid] = f2bf(x1 * rs * w[tid + 256]);
}

extern "C" void kernel_launch(void* const* d_in, const int* in_sizes, int n_in,
                              void* d_out, int out_size, void* d_ws, size_t ws_size,
                              hipStream_t stream) {
  const int*   ids      = (const int*)d_in[0];
  const float* embed    = (const float*)d_in[2];
  const float* in_w     = (const float*)d_in[3];
  const float* conv_w   = (const float*)d_in[4];
  const float* conv_b   = (const float*)d_in[5];
  const float* x_w      = (const float*)d_in[6];
  const float* dt_w     = (const float*)d_in[7];
  const float* dt_bias  = (const float*)d_in[8];
  const float* A_log    = (const float*)d_in[9];
  const float* Dp       = (const float*)d_in[10];
  const float* out_w    = (const float*)d_in[11];
  const float* norm_w   = (const float*)d_in[12];
  const float* norm_f   = (const float*)d_in[13];
  const float* proj_w   = (const float*)d_in[14];
  const float* proj_b   = (const float*)d_in[15];

  char* ws = (char*)d_ws;
  size_t off = 0;
  auto alloc = [&](size_t bytes) {
    void* p = ws + off;
    off += (bytes + 255) & ~(size_t)255;
    return p;
  };
  float* res  = (float*)alloc((size_t)ROWS2 * DM * 4);       // 33.6 MB
  float* hid  = (float*)alloc((size_t)ROWS2 * DM * 4);       // 33.6 MB (x_proj partials alias)
  u16*   xnyg = (u16*)alloc((size_t)ROWS2 * DI * 2);         // 33.6 MB (xn | y_loc | yg)
  u16*   xzz  = (u16*)alloc((size_t)ROWS2 * DI * 2);         // 33.6 MB (z half)
  void*  shrd = alloc((size_t)ROWS2 * DI * 2);               // 33.6 MB (xzu | chk bf16 | cat)
  u16*   u_h  = (u16*)alloc((size_t)ROWS2 * DI * 2);         // 33.6 MB (uh | S)
  const int N_IN  = 4 * 2 * DI * DM;
  const int N_XW  = 4 * 64 * DI;
  const int N_OW  = 4 * DM * DI;
  const int N_PW  = DM * 2 * DM;
  const int N_DTW = 4 * DTR * DI;
  u16*   in_wb  = (u16*)alloc((size_t)N_IN * 2);             //  8.4 MB
  u16*   x_wb   = (u16*)alloc((size_t)N_XW * 2);
  u16*   out_wb = (u16*)alloc((size_t)N_OW * 2);
  u16*   pr_wb  = (u16*)alloc((size_t)N_PW * 2);
  float* dtw_t  = (float*)alloc((size_t)N_DTW * 4);
  if (off > ws_size) return;

  u16*   xzu = (u16*)shrd;
  u16*   chk = (u16*)shrd;
  u16*   cat = (u16*)shrd;

  cvt_k<<<(N_IN / 4 + 255) / 256, 256, 0, stream>>>(in_w, in_wb, N_IN / 4);
  cvt_k<<<(N_XW / 4 + 255) / 256, 256, 0, stream>>>(x_w, x_wb, N_XW / 4);
  cvt_k<<<(N_OW / 4 + 255) / 256, 256, 0, stream>>>(out_w, out_wb, N_OW / 4);
  cvt_k<<<(N_PW / 4 + 255) / 256, 256, 0, stream>>>(proj_w, pr_wb, N_PW / 4);
  trp_k<<<N_DTW / 256, 256, 0, stream>>>(dt_w, dtw_t);

  embed_k<<<ROWS2 * DM / 256, 256, 0, stream>>>(ids, embed, res);
  for (int i = 0; i < 2; ++i) {
    if (i == 0)
      addnorm_k<false><<<ROWS2, 256, 0, stream>>>(res, hid, norm_w, i, xnyg);
    else
      addnorm_k<true><<<ROWS2, 256, 0, stream>>>(res, hid, norm_w, i, xnyg);
    g256_k<<<512, 512, 0, stream>>>(
        xnyg, in_wb + (size_t)i * 2 * DI * DM, xzu, xzz, DM);
    conv_k<<<ROWS2 * DI / 256, 256, 0, stream>>>(xzu, conv_w, conv_b, i, u_h);
    gemm_bt<64, EPI_F32, 4><<<dim3(ROWS2 / 128, 4), 256, 0, stream>>>(
        u_h, x_wb + (size_t)i * 64 * DI, hid, nullptr, 64, DI, (size_t)2 * 64 * DI);
    dtscan1_k<<<2048, 256, 0, stream>>>(u_h, hid, dtw_t, dt_bias, A_log, Dp, i,
                                        xnyg, chk);
    scan2_k<<<512, 256, 0, stream>>>(chk);
    scan3lite_k<<<2048, 256, 0, stream>>>(u_h, hid, A_log, i, chk, xzz, xnyg);
    gemm_bt<64, EPI_F32><<<dim3(ROWS2 / 128, DM / 64), 256, 0, stream>>>(
        xnyg, out_wb + (size_t)i * DM * DI, hid, nullptr, DM, DI, (size_t)2 * DM * DI);
  }
  fincat_k<<<ROWS2, 256, 0, stream>>>(hid, res, norm_f, cat);
  gemm_bt<64, EPI_BIAS><<<dim3(ROWS / 128, DM / 64), 256, 0, stream>>>(
      cat, pr_wb, (float*)d_out, proj_b, DM, DI, 0);
}

// Round 18
// 771.640 us; speedup vs baseline: 1.0236x; 1.0236x over previous
//
#include <hip/hip_runtime.h>
#include <hip/hip_bf16.h>

#define B_   4
#define L_   2048
#define DM   512
#define DI   1024
#define NST  16
#define DTR  32
#define ROWS  (B_ * L_)        // 8192
#define ROWS2 (2 * ROWS)       // 16384 (both directions)
#define NCHUNK 32
#define CLEN  (L_ / NCHUNK)    // 64
#define LN2R 1.4426950408889634f

typedef unsigned short u16;
typedef __attribute__((ext_vector_type(8))) short bf16x8;
typedef __attribute__((ext_vector_type(4))) float f32x4;
typedef __attribute__((ext_vector_type(4))) float float4v;
typedef __attribute__((ext_vector_type(2))) float f32x2;

__device__ __forceinline__ float bf2f(u16 h) {
  union { unsigned int u; float f; } v; v.u = ((unsigned int)h) << 16; return v.f;
}
__device__ __forceinline__ u16 f2bf(float f) {
  union { float f; unsigned int u; } v; v.f = f;
  unsigned int u = v.u;
  if ((u & 0x7fffffffu) > 0x7f800000u) return (u16)((u >> 16) | 0x0040u);
  return (u16)((u + 0x7fffu + ((u >> 16) & 1u)) >> 16);
}
__device__ __forceinline__ float sigmoidf_(float x) { return 1.f / (1.f + __expf(-x)); }

__device__ __forceinline__ f32x2 pk_mul(f32x2 a, f32x2 b) {
  f32x2 d; asm("v_pk_mul_f32 %0, %1, %2" : "=v"(d) : "v"(a), "v"(b)); return d;
}
__device__ __forceinline__ f32x2 pk_fma(f32x2 a, f32x2 b, f32x2 c) {
  f32x2 d; asm("v_pk_fma_f32 %0, %1, %2, %3" : "=v"(d) : "v"(a), "v"(b), "v"(c)); return d;
}

__device__ __forceinline__ void gload16(const u16* g, u16* l) {
  __builtin_amdgcn_global_load_lds(
      (const __attribute__((address_space(1))) void*)g,
      (__attribute__((address_space(3))) void*)l, 16, 0, 0);
}

// ---------------- f32 -> bf16 weight conversion ----------------
__global__ __launch_bounds__(256) void cvt_k(const float* __restrict__ in,
                                             u16* __restrict__ out, int n4) {
  int i = blockIdx.x * 256 + threadIdx.x;
  if (i >= n4) return;
  float4v v = *(const float4v*)&in[i * 4];
  u16 o[4];
  o[0] = f2bf(v.x); o[1] = f2bf(v.y); o[2] = f2bf(v.z); o[3] = f2bf(v.w);
  *(ulong1*)&out[i * 4] = *(ulong1*)o;
}

// ---------------- dt_w transpose: [4][DI][DTR] -> [4][DTR][DI] (f32) ----------------
__global__ __launch_bounds__(256) void trp_k(const float* __restrict__ in,
                                             float* __restrict__ out) {
  int o = blockIdx.x * 256 + threadIdx.x;
  int li = o >> 15;
  int k = (o >> 10) & (DTR - 1);
  int d = o & (DI - 1);
  out[o] = in[((size_t)li * DI + d) * DTR + k];
}

// ---------------- embed gather, both directions ----------------
__global__ __launch_bounds__(256) void embed_k(const int* __restrict__ ids,
                                               const float* __restrict__ emb,
                                               float* __restrict__ res) {
  int idx = blockIdx.x * 256 + threadIdx.x;   // ROWS2*DM
  int c = idx & (DM - 1);
  int row = idx >> 9;                          // 0..16383
  int dir = row >> 13;
  int r = row & (ROWS - 1);
  int b = r >> 11;
  int l = r & (L_ - 1);
  int sl = dir ? (L_ - 1 - l) : l;
  int id = ids[(b << 11) + sl];
  res[idx] = emb[(size_t)dir * 128 * DM + id * DM + c];
}

// ---------------- (res += hid); xn = rmsnorm(res) * w (per-dir weights) ----------------
template <bool ADD>
__global__ __launch_bounds__(256) void addnorm_k(float* __restrict__ res,
                                                 const float* __restrict__ hid,
                                                 const float* __restrict__ norm_w,
                                                 int layer,
                                                 u16* __restrict__ xn) {
  int row = blockIdx.x;                        // 0..16383
  int dir = row >> 13;
  const float* w = norm_w + (size_t)(dir * 2 + layer) * DM;
  int tid = threadIdx.x;
  int base = row * DM;
  float x0 = res[base + tid];
  float x1 = res[base + 256 + tid];
  if (ADD) {
    x0 += hid[base + tid];
    x1 += hid[base + 256 + tid];
    res[base + tid] = x0;
    res[base + 256 + tid] = x1;
  }
  float s = x0 * x0 + x1 * x1;
  for (int off = 32; off; off >>= 1) s += __shfl_xor(s, off);
  __shared__ float ps[4];
  if (!(tid & 63)) ps[tid >> 6] = s;
  __syncthreads();
  float tot = ps[0] + ps[1] + ps[2] + ps[3];
  float rs = 1.f / sqrtf(tot / (float)DM + 1e-5f);
  xn[base + tid]       = f2bf(x0 * rs * w[tid]);
  xn[base + 256 + tid] = f2bf(x1 * rs * w[tid + 256]);
}

// ---------------- in_proj: 256x256 tile, BK=32, 2 buffers (64 kB LDS -> 2 blk/CU) ----------------
#define MFMA_B16(a, b, c) __builtin_amdgcn_mfma_f32_16x16x32_bf16(a, b, c, 0, 0, 0)

__global__ __launch_bounds__(512) void g256_k(const u16* __restrict__ A,
                                              const u16* __restrict__ W,   // layer base (dir0)
                                              u16* __restrict__ outU,
                                              u16* __restrict__ outZ,
                                              int K) {
  __shared__ u16 As[2][256 * 32];   // 32 kB
  __shared__ u16 Wsh[2][256 * 32];  // 32 kB
  int tid = threadIdx.x;
  int lane = tid & 63;
  int wv = tid >> 6;
  int wr = wv >> 2, wc = wv & 3;    // 2M x 4N waves
  int bid = blockIdx.x;             // 512 blocks: 64 mt x 8 nt
  int xcd = bid & 7, jj = bid >> 3;
  int mt = xcd * 8 + (jj & 7);      // 0..63
  int nt = jj >> 3;                 // 0..7
  int m0 = mt * 256, n0 = nt * 256;
  const u16* Weff = W + (size_t)(m0 >> 13) * (size_t)2 * (2 * DI) * DM;
  f32x4 acc[8][4];
#pragma unroll
  for (int i = 0; i < 8; ++i)
#pragma unroll
    for (int j = 0; j < 4; ++j) acc[i][j] = (f32x4){0.f, 0.f, 0.f, 0.f};
  int rr = lane & 15;
  int sl = lane >> 4;
  int pofs = ((sl + (rr >> 1)) & 3) * 8;    // conflict-free swizzled read slot
  int lr = lane >> 2;
  int ls = ((lane & 3) - (lr >> 1)) & 3;    // matching pre-swizzled source slot

  auto stage = [&](int tau, int buf) {
#pragma unroll
    for (int j = 0; j < 2; ++j) {
      gload16(A + (size_t)(m0 + j * 128 + wv * 16 + lr) * K + tau * 32 + ls * 8,
              &As[buf][(j * 128 + wv * 16) * 32]);
      gload16(Weff + (size_t)(n0 + j * 128 + wv * 16 + lr) * K + tau * 32 + ls * 8,
              &Wsh[buf][(j * 128 + wv * 16) * 32]);
    }
  };

  int NK = K / 32;                  // 16
  stage(0, 0);
  for (int tau = 0; tau < NK; ++tau) {
    int buf = tau & 1;
    bool more = (tau + 1 < NK);
    if (more) stage(tau + 1, buf ^ 1);
    if (more)
      asm volatile("s_waitcnt vmcnt(4)" ::: "memory");
    else
      asm volatile("s_waitcnt vmcnt(0)" ::: "memory");
    __builtin_amdgcn_sched_barrier(0);
    __builtin_amdgcn_s_barrier();
    __builtin_amdgcn_sched_barrier(0);
    bf16x8 af[8], wf[4];
#pragma unroll
    for (int mi = 0; mi < 8; ++mi)
      af[mi] = *(bf16x8*)&As[buf][(wr * 128 + mi * 16 + rr) * 32 + pofs];
#pragma unroll
    for (int ni = 0; ni < 4; ++ni)
      wf[ni] = *(bf16x8*)&Wsh[buf][(wc * 64 + ni * 16 + rr) * 32 + pofs];
    __builtin_amdgcn_s_setprio(1);
#pragma unroll
    for (int mi = 0; mi < 8; ++mi)
#pragma unroll
      for (int ni = 0; ni < 4; ++ni)
        acc[mi][ni] = MFMA_B16(af[mi], wf[ni], acc[mi][ni]);
    __builtin_amdgcn_s_setprio(0);
    asm volatile("s_waitcnt lgkmcnt(0)" ::: "memory");
    __builtin_amdgcn_sched_barrier(0);
    __builtin_amdgcn_s_barrier();
    __builtin_amdgcn_sched_barrier(0);
  }
  int cr = (lane >> 4) << 2;
  int cc = lane & 15;
  u16* outp = (n0 < DI) ? outU : outZ;
  int cb0 = (n0 < DI) ? n0 : (n0 - DI);
#pragma unroll
  for (int mi = 0; mi < 8; ++mi)
#pragma unroll
    for (int ni = 0; ni < 4; ++ni) {
      int row = m0 + wr * 128 + mi * 16 + cr;
      int col = cb0 + wc * 64 + ni * 16 + cc;
#pragma unroll
      for (int j = 0; j < 4; ++j)
        outp[(size_t)(row + j) * DI + col] = f2bf(acc[mi][ni][j]);
    }
}

// ---------------- GEMM (generic): 4-ring, stage-ahead-3, per-dir weight stride ----------------
#define EPI_F32  0
#define EPI_BF16 1
#define EPI_BIAS 2

template <int BN, int EPI, int SK = 1>
__global__ __launch_bounds__(256) void gemm_bt(const u16* __restrict__ A,
                                               const u16* __restrict__ W,
                                               void* __restrict__ outp,
                                               const float* __restrict__ bias,
                                               int N, int K, size_t wsd) {
  constexpr int BM = 128, BK = 32;
  constexpr int NF = BN / 32;
  constexpr int G = (BN == 128) ? 4 : 3;
  __shared__ u16 As[4][BM * BK];
  __shared__ u16 Wsh[4][BN * BK];
  int tid = threadIdx.x;
  int lane = tid & 63;
  int wv = tid >> 6;
  int wr = wv >> 1, wc = wv & 1;
  int m0 = blockIdx.x * BM;
  int n0 = (SK > 1) ? 0 : blockIdx.y * BN;
  int koff = (SK > 1) ? blockIdx.y * (K / SK) : 0;
  int KS = K / SK;
  int NK = KS / BK;
  const u16* Weff = W + (size_t)(m0 >> 13) * wsd;
  f32x4 acc[4][NF];
#pragma unroll
  for (int i = 0; i < 4; ++i)
#pragma unroll
    for (int j = 0; j < NF; ++j) acc[i][j] = (f32x4){0.f, 0.f, 0.f, 0.f};
  int rr = lane & 15;
  int kk = (lane >> 4) << 3;
  int l4 = lane >> 2;
  int c8 = (lane & 3) << 3;
  const u16* Ag = A + (size_t)(m0 + l4) * K + koff + c8;
  const u16* Wg = Weff + (size_t)(n0 + l4) * K + koff + c8;

  auto stage = [&](int k0, int buf) {
    gload16(Ag + (size_t)(wv * 16) * K + k0, &As[buf][wv * 512]);
    gload16(Ag + (size_t)((wv + 4) * 16) * K + k0, &As[buf][(wv + 4) * 512]);
    gload16(Wg + (size_t)(wv * 16) * K + k0, &Wsh[buf][wv * 512]);
    if (BN == 128)
      gload16(Wg + (size_t)((wv + 4) * 16) * K + k0, &Wsh[buf][(wv + 4) * 512]);
  };

  stage(0, 0); stage(BK, 1); stage(2 * BK, 2);
  for (int k = 0; k < NK; ++k) {
    if (k < NK - 2)
      asm volatile("s_waitcnt vmcnt(%0)" :: "n"(2 * G) : "memory");
    else if (k == NK - 2)
      asm volatile("s_waitcnt vmcnt(%0)" :: "n"(G) : "memory");
    else
      asm volatile("s_waitcnt vmcnt(0)" ::: "memory");
    __builtin_amdgcn_s_barrier();
    __builtin_amdgcn_sched_barrier(0);
    if (k + 3 < NK) stage((k + 3) * BK, (k + 3) & 3);
    __builtin_amdgcn_sched_barrier(0);
    int cur = k & 3;
    bf16x8 af[4], wf[NF];
#pragma unroll
    for (int mi = 0; mi < 4; ++mi)
      af[mi] = *(bf16x8*)&As[cur][(wr * 64 + mi * 16 + rr) * BK + kk];
#pragma unroll
    for (int ni = 0; ni < NF; ++ni)
      wf[ni] = *(bf16x8*)&Wsh[cur][(wc * (BN / 2) + ni * 16 + rr) * BK + kk];
#pragma unroll
    for (int mi = 0; mi < 4; ++mi)
#pragma unroll
      for (int ni = 0; ni < NF; ++ni)
        acc[mi][ni] = __builtin_amdgcn_mfma_f32_16x16x32_bf16(af[mi], wf[ni], acc[mi][ni], 0, 0, 0);
  }
  int cr = (lane >> 4) << 2;
  int cc = lane & 15;
  float* outF = (float*)outp +
      ((SK > 1) ? (size_t)blockIdx.y * (size_t)gridDim.x * BM * N : 0);
#pragma unroll
  for (int mi = 0; mi < 4; ++mi)
#pragma unroll
    for (int ni = 0; ni < NF; ++ni) {
      int row = m0 + wr * 64 + mi * 16 + cr;
      int col = n0 + wc * (BN / 2) + ni * 16 + cc;
      float bv = (EPI == EPI_BIAS) ? bias[col] : 0.f;
#pragma unroll
      for (int j = 0; j < 4; ++j) {
        float v = acc[mi][ni][j] + bv;
        if (EPI == EPI_BF16)
          ((u16*)outp)[(size_t)(row + j) * N + col] = f2bf(v);
        else
          outF[(size_t)(row + j) * N + col] = v;
      }
    }
}

// ---------------- depthwise causal conv + SiLU, both dirs ----------------
__global__ __launch_bounds__(256) void conv_k(const u16* __restrict__ xzu,
                                              const float* __restrict__ conv_w,
                                              const float* __restrict__ conv_b,
                                              int layer,
                                              u16* __restrict__ uh) {
  int idx = blockIdx.x * 256 + threadIdx.x;        // ROWS2*DI
  int c = idx & (DI - 1);
  int row = idx >> 10;
  int dir = row >> 13;
  int l = row & (L_ - 1);
  const float* cw = conv_w + (size_t)(dir * 2 + layer) * DI * 4;
  const float* cb = conv_b + (size_t)(dir * 2 + layer) * DI;
  float acc = cb[c];
#pragma unroll
  for (int j = 0; j < 4; ++j) {
    int ls = l + j - 3;
    if (ls >= 0)
      acc += bf2f(xzu[(size_t)(row + j - 3) * DI + c]) * cw[c * 4 + j];
  }
  float s = acc * sigmoidf_(acc);
  uh[idx] = f2bf(s);
}

// A-structure check
__device__ __forceinline__ bool a_fast(const float* alog, int d, float& a20) {
  a20 = -__expf(alog[d * NST]) * LN2R;
  bool fast = true;
#pragma unroll
  for (int n = 1; n < NST; ++n) {
    float an = -__expf(alog[d * NST + n]) * LN2R;
    fast &= (fabsf(an - (float)(n + 1) * a20) <= 1e-5f * (float)(n + 1) * fabsf(a20));
  }
  return fast;
}

// stage xs[CLEN][64] by summing 4 x_proj split-K partials (rowbase in rows)
__device__ __forceinline__ void stage_xs(float (*xs)[64], const float* xp,
                                         size_t rowbase, int tid) {
  size_t base = rowbase * 64;
  const float4v* s0 = (const float4v*)(xp + base);
  const float4v* s1 = (const float4v*)(xp + (size_t)ROWS2 * 64 + base);
  const float4v* s2 = (const float4v*)(xp + (size_t)2 * ROWS2 * 64 + base);
  const float4v* s3 = (const float4v*)(xp + (size_t)3 * ROWS2 * 64 + base);
  float4v* dst = (float4v*)&xs[0][0];
#pragma unroll
  for (int i = 0; i < CLEN / 16; ++i)
    dst[tid + i * 256] = s0[tid + i * 256] + s1[tid + i * 256] +
                         s2[tid + i * 256] + s3[tid + i * 256];
}

// dt = softplus(dot(xs[t][0..31], w2) + bias), 4 independent accumulator chains
__device__ __forceinline__ float dt_of(const float (*xs)[64], int t,
                                       const f32x2* w2, float bias) {
  const f32x2* x = (const f32x2*)&xs[t][0];
  f32x2 a0 = {bias, 0.f}, a1 = {0.f, 0.f}, a2 = {0.f, 0.f}, a3 = {0.f, 0.f};
#pragma unroll
  for (int j = 0; j < 4; ++j) {
    a0 = pk_fma(x[4 * j],     w2[4 * j],     a0);
    a1 = pk_fma(x[4 * j + 1], w2[4 * j + 1], a1);
    a2 = pk_fma(x[4 * j + 2], w2[4 * j + 2], a2);
    a3 = pk_fma(x[4 * j + 3], w2[4 * j + 3], a3);
  }
  float a = (a0.x + a0.y) + (a1.x + a1.y) + ((a2.x + a2.y) + (a3.x + a3.y));
  return (a > 15.f) ? a : __logf(1.f + __expf(a));
}

// ---------------- pass 1: dt + local scan + y_loc + S (both dirs) ----------------
__global__ __launch_bounds__(256) void dtscan1_k(u16* uS,
                                                 const float* __restrict__ xp,
                                                 const float* __restrict__ dtw_t,
                                                 const float* __restrict__ dtb,
                                                 const float* __restrict__ alog_,
                                                 const float* __restrict__ Dp,
                                                 int layer,
                                                 u16* __restrict__ ylg,
                                                 float* __restrict__ chk) {
  __shared__ float xs[CLEN][64];                  // 16 kB
  int blk = blockIdx.x;            // 1024 = nb(8) x chunks(32) x dgroup(4)
  int db = blk & 3;
  int c  = (blk >> 2) & (NCHUNK - 1);
  int nb = blk >> 7;               // dir*4 + b
  int dir = nb >> 2;
  int tid = threadIdx.x;
  int d  = db * 256 + tid;
  int li = dir * 2 + layer;
  const float* dtwT = dtw_t + (size_t)li * DTR * DI;
  const float* alog = alog_ + (size_t)li * DI * NST;
  int t0 = c * CLEN;
  size_t rowbase = (size_t)nb * L_ + t0;
  stage_xs(xs, xp, rowbase, tid);
  f32x2 w2[16];
#pragma unroll
  for (int j = 0; j < 16; ++j)
    w2[j] = (f32x2){dtwT[(size_t)(2 * j) * DI + d], dtwT[(size_t)(2 * j + 1) * DI + d]};
  float bias = dtb[(size_t)li * DI + d];
  float Dv = Dp[(size_t)li * DI + d];
  float a20;
  bool fast = a_fast(alog, d, a20);
  __syncthreads();
  float S = 0.f;
  size_t ubase = rowbase * DI + d;
  f32x2 h2[8];
#pragma unroll
  for (int q = 0; q < 8; ++q) h2[q] = (f32x2){0.f, 0.f};
  float uv = bf2f(uS[ubase]);
#pragma unroll 2
  for (int t = 0; t < CLEN; ++t) {
    float uv_nx = (t + 1 < CLEN) ? bf2f(uS[ubase + DI]) : 0.f;
    float dtv = dt_of(xs, t, w2, bias);
    float du = dtv * uv;
    S += dtv;
    f32x2 accA = {0.f, 0.f}, accB = {0.f, 0.f};
    if (fast) {
      float p1 = exp2f(dtv * a20);
      float p2 = p1 * p1;
      f32x2 pw = {p1, p2};
      f32x2 pst = {p2, p2};
      f32x2 du2 = {du, du};
#pragma unroll
      for (int k = 0; k < 4; ++k) {
        f32x4 bv = *(const f32x4*)&xs[t][DTR + k * 4];
        f32x4 cv = *(const f32x4*)&xs[t][DTR + NST + k * 4];
        f32x2 blo = __builtin_shufflevector(bv, bv, 0, 1);
        f32x2 bhi = __builtin_shufflevector(bv, bv, 2, 3);
        f32x2 clo = __builtin_shufflevector(cv, cv, 0, 1);
        f32x2 chi = __builtin_shufflevector(cv, cv, 2, 3);
        h2[2 * k]     = pk_fma(pw, h2[2 * k], pk_mul(du2, blo));
        accA          = pk_fma(h2[2 * k], clo, accA);
        pw = pk_mul(pw, pst);
        h2[2 * k + 1] = pk_fma(pw, h2[2 * k + 1], pk_mul(du2, bhi));
        accB          = pk_fma(h2[2 * k + 1], chi, accB);
        if (k < 3) pw = pk_mul(pw, pst);
      }
    } else {
#pragma unroll
      for (int q = 0; q < 8; ++q) {
        float e0 = exp2f(dtv * -__expf(alog[d * NST + 2 * q]) * LN2R);
        float e1 = exp2f(dtv * -__expf(alog[d * NST + 2 * q + 1]) * LN2R);
        f32x2 bv = *(const f32x2*)&xs[t][DTR + q * 2];
        f32x2 cv = *(const f32x2*)&xs[t][DTR + NST + q * 2];
        h2[q] = pk_fma((f32x2){e0, e1}, h2[q], pk_mul((f32x2){du, du}, bv));
        if (q & 1) accB = pk_fma(h2[q], cv, accB);
        else       accA = pk_fma(h2[q], cv, accA);
      }
    }
    float yloc = (accA.x + accA.y) + (accB.x + accB.y) + uv * Dv;
    ylg[ubase] = f2bf(yloc);
    uS[ubase]  = f2bf(S);          // after uv read; same thread, same slot
    uv = uv_nx;
    ubase += DI;
  }
  const size_t H = (size_t)8 * NCHUNK * DI * NST;
  size_t idx = ((size_t)(nb * NCHUNK + c) * DI + d) * NST;
#pragma unroll
  for (int n = 0; n < NST; ++n) {
    float an = -__expf(alog[d * NST + n]) * LN2R;
    chk[idx + n]     = exp2f(an * S);
    chk[H + idx + n] = (n & 1) ? h2[n >> 1].y : h2[n >> 1].x;
  }
}

// pass 2: sequential chunk combine (both dirs)
__global__ __launch_bounds__(256) void scan2_k(float* __restrict__ chk) {
  int j = blockIdx.x * 256 + threadIdx.x;   // 131072 = 8*DI*NST
  int n = j & 15;
  int d = (j >> 4) & (DI - 1);
  int nb = j >> 14;
  const size_t H = (size_t)8 * NCHUNK * DI * NST;
  float h = 0.f;
  for (int c = 0; c < NCHUNK; ++c) {
    size_t idx = ((size_t)(nb * NCHUNK + c) * DI + d) * NST + n;
    float a = chk[idx];
    float hl = chk[H + idx];
    chk[H + idx] = h;
    h = a * h + hl;
  }
}

// pass 3 (lite): y = y_loc + sum_n C_t[n]*exp2(A2[n]*S_t)*h0[n]; fused gate.
__global__ __launch_bounds__(256) void scan3lite_k(const u16* __restrict__ uS,
                                                   const float* __restrict__ xp,
                                                   const float* __restrict__ alog_,
                                                   int layer,
                                                   const float* __restrict__ chk,
                                                   const u16* __restrict__ xzz,
                                                   u16* ylg) {
  __shared__ float xc[CLEN][NST];                 // 4 kB: C columns only
  int blk = blockIdx.x;
  int db = blk & 3;
  int c  = (blk >> 2) & (NCHUNK - 1);
  int nb = blk >> 7;
  int dir = nb >> 2;
  int tid = threadIdx.x;
  int d  = db * 256 + tid;
  int li = dir * 2 + layer;
  const float* alog = alog_ + (size_t)li * DI * NST;
  int t0 = c * CLEN;
  size_t rowbase = (size_t)nb * L_ + t0;
  {
    int r = tid >> 2, v = tid & 3;                // 64 rows x 4 vec4
    size_t base = (rowbase + r) * 64 + DTR + NST + v * 4;
    float4v s = *(const float4v*)(xp + base)
              + *(const float4v*)(xp + (size_t)ROWS2 * 64 + base)
              + *(const float4v*)(xp + (size_t)2 * ROWS2 * 64 + base)
              + *(const float4v*)(xp + (size_t)3 * ROWS2 * 64 + base);
    *(float4v*)&xc[r][v * 4] = s;
  }
  float a20;
  bool fast = a_fast(alog, d, a20);
  const size_t H = (size_t)8 * NCHUNK * DI * NST;
  size_t cidx = ((size_t)(nb * NCHUNK + c) * DI + d) * NST;
  f32x2 h2[8];
#pragma unroll
  for (int q = 0; q < 8; ++q) h2[q] = *(const f32x2*)&chk[H + cidx + 2 * q];
  float A2g[NST];
  if (!fast) {
#pragma unroll
    for (int n = 0; n < NST; ++n) A2g[n] = -__expf(alog[d * NST + n]) * LN2R;
  }
  __syncthreads();
  size_t ubase = rowbase * DI + d;
  float S = bf2f(uS[ubase]);
#pragma unroll 2
  for (int t = 0; t < CLEN; ++t) {
    float S_nx = (t + 1 < CLEN) ? bf2f(uS[ubase + DI]) : 0.f;
    f32x2 corrA = {0.f, 0.f}, corrB = {0.f, 0.f};
    if (fast) {
      float w1 = exp2f(a20 * S);
      float w2_ = w1 * w1;
      f32x2 pw = {w1, w2_};
      f32x2 pst = {w2_, w2_};
#pragma unroll
      for (int q = 0; q < 8; ++q) {
        f32x2 cp = *(const f32x2*)&xc[t][2 * q];
        if (q & 1) corrB = pk_fma(pk_mul(pw, h2[q]), cp, corrB);
        else       corrA = pk_fma(pk_mul(pw, h2[q]), cp, corrA);
        if (q < 7) pw = pk_mul(pw, pst);
      }
    } else {
#pragma unroll
      for (int q = 0; q < 8; ++q) {
        f32x2 e = {exp2f(A2g[2 * q] * S), exp2f(A2g[2 * q + 1] * S)};
        f32x2 cp = *(const f32x2*)&xc[t][2 * q];
        if (q & 1) corrB = pk_fma(pk_mul(e, h2[q]), cp, corrB);
        else       corrA = pk_fma(pk_mul(e, h2[q]), cp, corrA);
      }
    }
    float y = bf2f(ylg[ubase]) + (corrA.x + corrA.y) + (corrB.x + corrB.y);
    float z = bf2f(xzz[ubase]);
    ylg[ubase] = f2bf(y * z * sigmoidf_(z));
    S = S_nx;
    ubase += DI;
  }
}

// ---------------- final rmsnorm(hid+res) -> concat buffer, both dirs ----------------
__global__ __launch_bounds__(256) void fincat_k(const float* __restrict__ hid,
                                                const float* __restrict__ res,
                                                const float* __restrict__ norm_f,
                                                u16* __restrict__ cat) {
  int row = blockIdx.x;                 // 0..16383
  int dir = row >> 13;
  const float* w = norm_f + (size_t)dir * DM;
  int tid = threadIdx.x;
  int base = row * DM;
  float x0 = hid[base + tid] + res[base + tid];
  float x1 = hid[base + 256 + tid] + res[base + 256 + tid];
  float s = x0 * x0 + x1 * x1;
  for (int off = 32; off; off >>= 1) s += __shfl_xor(s, off);
  __shared__ float ps[4];
  if (!(tid & 63)) ps[tid >> 6] = s;
  __syncthreads();
  float tot = ps[0] + ps[1] + ps[2] + ps[3];
  float rs = 1.f / sqrtf(tot / (float)DM + 1e-5f);
  int r = row & (ROWS - 1);
  int b = r >> 11, l = r & (L_ - 1);
  size_t drow = dir ? ((size_t)(b << 11) + (L_ - 1 - l)) : (size_t)r;
  size_t obase = drow * (2 * DM) + (size_t)dir * DM;
  cat[obase + tid]       = f2bf(x0 * rs * w[tid]);
  cat[obase + 256 + tid] = f2bf(x1 * rs * w[tid + 256]);
}

extern "C" void kernel_launch(void* const* d_in, const int* in_sizes, int n_in,
                              void* d_out, int out_size, void* d_ws, size_t ws_size,
                              hipStream_t stream) {
  const int*   ids      = (const int*)d_in[0];
  const float* embed    = (const float*)d_in[2];
  const float* in_w     = (const float*)d_in[3];
  const float* conv_w   = (const float*)d_in[4];
  const float* conv_b   = (const float*)d_in[5];
  const float* x_w      = (const float*)d_in[6];
  const float* dt_w     = (const float*)d_in[7];
  const float* dt_bias  = (const float*)d_in[8];
  const float* A_log    = (const float*)d_in[9];
  const float* Dp       = (const float*)d_in[10];
  const float* out_w    = (const float*)d_in[11];
  const float* norm_w   = (const float*)d_in[12];
  const float* norm_f   = (const float*)d_in[13];
  const float* proj_w   = (const float*)d_in[14];
  const float* proj_b   = (const float*)d_in[15];

  char* ws = (char*)d_ws;
  size_t off = 0;
  auto alloc = [&](size_t bytes) {
    void* p = ws + off;
    off += (bytes + 255) & ~(size_t)255;
    return p;
  };
  float* res  = (float*)alloc((size_t)ROWS2 * DM * 4);       // 33.6 MB
  float* hid  = (float*)alloc((size_t)ROWS2 * DM * 4);       // 33.6 MB (x_proj partials alias)
  u16*   xnyg = (u16*)alloc((size_t)ROWS2 * DI * 2);         // 33.6 MB (xn | y_loc | yg)
  u16*   xzz  = (u16*)alloc((size_t)ROWS2 * DI * 2);         // 33.6 MB (z half)
  void*  shrd = alloc((size_t)ROWS2 * DI * 2);               // 33.6 MB (xzu | chk | cat)
  u16*   u_h  = (u16*)alloc((size_t)ROWS2 * DI * 2);         // 33.6 MB (uh | S)
  const int N_IN  = 4 * 2 * DI * DM;
  const int N_XW  = 4 * 64 * DI;
  const int N_OW  = 4 * DM * DI;
  const int N_PW  = DM * 2 * DM;
  const int N_DTW = 4 * DTR * DI;
  u16*   in_wb  = (u16*)alloc((size_t)N_IN * 2);             //  8.4 MB
  u16*   x_wb   = (u16*)alloc((size_t)N_XW * 2);
  u16*   out_wb = (u16*)alloc((size_t)N_OW * 2);
  u16*   pr_wb  = (u16*)alloc((size_t)N_PW * 2);
  float* dtw_t  = (float*)alloc((size_t)N_DTW * 4);
  if (off > ws_size) return;

  u16*   xzu = (u16*)shrd;
  float* chk = (float*)shrd;
  u16*   cat = (u16*)shrd;

  cvt_k<<<(N_IN / 4 + 255) / 256, 256, 0, stream>>>(in_w, in_wb, N_IN / 4);
  cvt_k<<<(N_XW / 4 + 255) / 256, 256, 0, stream>>>(x_w, x_wb, N_XW / 4);
  cvt_k<<<(N_OW / 4 + 255) / 256, 256, 0, stream>>>(out_w, out_wb, N_OW / 4);
  cvt_k<<<(N_PW / 4 + 255) / 256, 256, 0, stream>>>(proj_w, pr_wb, N_PW / 4);
  trp_k<<<N_DTW / 256, 256, 0, stream>>>(dt_w, dtw_t);

  embed_k<<<ROWS2 * DM / 256, 256, 0, stream>>>(ids, embed, res);
  for (int i = 0; i < 2; ++i) {
    if (i == 0)
      addnorm_k<false><<<ROWS2, 256, 0, stream>>>(res, hid, norm_w, i, xnyg);
    else
      addnorm_k<true><<<ROWS2, 256, 0, stream>>>(res, hid, norm_w, i, xnyg);
    g256_k<<<512, 512, 0, stream>>>(
        xnyg, in_wb + (size_t)i * 2 * DI * DM, xzu, xzz, DM);
    conv_k<<<ROWS2 * DI / 256, 256, 0, stream>>>(xzu, conv_w, conv_b, i, u_h);
    gemm_bt<64, EPI_F32, 4><<<dim3(ROWS2 / 128, 4), 256, 0, stream>>>(
        u_h, x_wb + (size_t)i * 64 * DI, hid, nullptr, 64, DI, (size_t)2 * 64 * DI);
    dtscan1_k<<<1024, 256, 0, stream>>>(u_h, hid, dtw_t, dt_bias, A_log, Dp, i,
                                        xnyg, chk);
    scan2_k<<<512, 256, 0, stream>>>(chk);
    scan3lite_k<<<1024, 256, 0, stream>>>(u_h, hid, A_log, i, chk, xzz, xnyg);
    gemm_bt<64, EPI_F32><<<dim3(ROWS2 / 128, DM / 64), 256, 0, stream>>>(
        xnyg, out_wb + (size_t)i * DM * DI, hid, nullptr, DM, DI, (size_t)2 * DM * DI);
  }
  fincat_k<<<ROWS2, 256, 0, stream>>>(hid, res, norm_f, cat);
  gemm_bt<64, EPI_BIAS><<<dim3(ROWS / 128, DM / 64), 256, 0, stream>>>(
      cat, pr_wb, (float*)d_out, proj_b, DM, DI, 0);
}

// Round 19
// 740.420 us; speedup vs baseline: 1.0668x; 1.0422x over previous
//
#include <hip/hip_runtime.h>
#include <hip/hip_bf16.h>

#define B_   4
#define L_   2048
#define DM   512
#define DI   1024
#define NST  16
#define DTR  32
#define ROWS  (B_ * L_)        // 8192
#define ROWS2 (2 * ROWS)       // 16384 (both directions)
#define NCHUNK 32
#define CLEN  (L_ / NCHUNK)    // 64
#define LN2R 1.4426950408889634f

typedef unsigned short u16;
typedef unsigned int u32;
typedef __attribute__((ext_vector_type(8))) short bf16x8;
typedef __attribute__((ext_vector_type(4))) float f32x4;
typedef __attribute__((ext_vector_type(4))) float float4v;
typedef __attribute__((ext_vector_type(2))) float f32x2;

__device__ __forceinline__ float bf2f(u16 h) {
  union { unsigned int u; float f; } v; v.u = ((unsigned int)h) << 16; return v.f;
}
__device__ __forceinline__ u16 f2bf(float f) {
  union { float f; unsigned int u; } v; v.f = f;
  unsigned int u = v.u;
  if ((u & 0x7fffffffu) > 0x7f800000u) return (u16)((u >> 16) | 0x0040u);
  return (u16)((u + 0x7fffu + ((u >> 16) & 1u)) >> 16);
}
// packed f32->bf16x2 (1 instr): low = cvt(a), high = cvt(b)
__device__ __forceinline__ u32 cvtpk_bf16(float a, float b) {
  u32 r; asm("v_cvt_pk_bf16_f32 %0, %1, %2" : "=v"(r) : "v"(a), "v"(b)); return r;
}
__device__ __forceinline__ float sigmoidf_(float x) { return 1.f / (1.f + __expf(-x)); }

__device__ __forceinline__ f32x2 pk_mul(f32x2 a, f32x2 b) {
  f32x2 d; asm("v_pk_mul_f32 %0, %1, %2" : "=v"(d) : "v"(a), "v"(b)); return d;
}
__device__ __forceinline__ f32x2 pk_fma(f32x2 a, f32x2 b, f32x2 c) {
  f32x2 d; asm("v_pk_fma_f32 %0, %1, %2, %3" : "=v"(d) : "v"(a), "v"(b), "v"(c)); return d;
}

__device__ __forceinline__ void gload16(const u16* g, u16* l) {
  __builtin_amdgcn_global_load_lds(
      (const __attribute__((address_space(1))) void*)g,
      (__attribute__((address_space(3))) void*)l, 16, 0, 0);
}

// ---------------- f32 -> bf16 weight conversion ----------------
__global__ __launch_bounds__(256) void cvt_k(const float* __restrict__ in,
                                             u16* __restrict__ out, int n4) {
  int i = blockIdx.x * 256 + threadIdx.x;
  if (i >= n4) return;
  float4v v = *(const float4v*)&in[i * 4];
  u16 o[4];
  o[0] = f2bf(v.x); o[1] = f2bf(v.y); o[2] = f2bf(v.z); o[3] = f2bf(v.w);
  *(ulong1*)&out[i * 4] = *(ulong1*)o;
}

// ---------------- dt_w transpose: [4][DI][DTR] -> [4][DTR][DI] (f32) ----------------
__global__ __launch_bounds__(256) void trp_k(const float* __restrict__ in,
                                             float* __restrict__ out) {
  int o = blockIdx.x * 256 + threadIdx.x;
  int li = o >> 15;
  int k = (o >> 10) & (DTR - 1);
  int d = o & (DI - 1);
  out[o] = in[((size_t)li * DI + d) * DTR + k];
}

// ---------------- embed gather, both directions ----------------
__global__ __launch_bounds__(256) void embed_k(const int* __restrict__ ids,
                                               const float* __restrict__ emb,
                                               float* __restrict__ res) {
  int idx = blockIdx.x * 256 + threadIdx.x;   // ROWS2*DM
  int c = idx & (DM - 1);
  int row = idx >> 9;                          // 0..16383
  int dir = row >> 13;
  int r = row & (ROWS - 1);
  int b = r >> 11;
  int l = r & (L_ - 1);
  int sl = dir ? (L_ - 1 - l) : l;
  int id = ids[(b << 11) + sl];
  res[idx] = emb[(size_t)dir * 128 * DM + id * DM + c];
}

// ---------------- (res += hid); xn = rmsnorm(res) * w (per-dir weights) ----------------
template <bool ADD>
__global__ __launch_bounds__(256) void addnorm_k(float* __restrict__ res,
                                                 const float* __restrict__ hid,
                                                 const float* __restrict__ norm_w,
                                                 int layer,
                                                 u16* __restrict__ xn) {
  int row = blockIdx.x;                        // 0..16383
  int dir = row >> 13;
  const float* w = norm_w + (size_t)(dir * 2 + layer) * DM;
  int tid = threadIdx.x;
  int base = row * DM;
  float x0 = res[base + tid];
  float x1 = res[base + 256 + tid];
  if (ADD) {
    x0 += hid[base + tid];
    x1 += hid[base + 256 + tid];
    res[base + tid] = x0;
    res[base + 256 + tid] = x1;
  }
  float s = x0 * x0 + x1 * x1;
  for (int off = 32; off; off >>= 1) s += __shfl_xor(s, off);
  __shared__ float ps[4];
  if (!(tid & 63)) ps[tid >> 6] = s;
  __syncthreads();
  float tot = ps[0] + ps[1] + ps[2] + ps[3];
  float rs = 1.f / sqrtf(tot / (float)DM + 1e-5f);
  xn[base + tid]       = f2bf(x0 * rs * w[tid]);
  xn[base + 256 + tid] = f2bf(x1 * rs * w[tid + 256]);
}

// ---------------- in_proj: 256x256 tile, BK=32, 2 buffers (64 kB LDS -> 2 blk/CU) ----------------
#define MFMA_B16(a, b, c) __builtin_amdgcn_mfma_f32_16x16x32_bf16(a, b, c, 0, 0, 0)

__global__ __launch_bounds__(512) void g256_k(const u16* __restrict__ A,
                                              const u16* __restrict__ W,   // layer base (dir0)
                                              u16* __restrict__ outU,
                                              u16* __restrict__ outZ,
                                              int K) {
  __shared__ u16 As[2][256 * 32];   // 32 kB
  __shared__ u16 Wsh[2][256 * 32];  // 32 kB
  int tid = threadIdx.x;
  int lane = tid & 63;
  int wv = tid >> 6;
  int wr = wv >> 2, wc = wv & 3;    // 2M x 4N waves
  int bid = blockIdx.x;             // 512 blocks: 64 mt x 8 nt
  int xcd = bid & 7, jj = bid >> 3;
  int mt = xcd * 8 + (jj & 7);      // 0..63
  int nt = jj >> 3;                 // 0..7
  int m0 = mt * 256, n0 = nt * 256;
  const u16* Weff = W + (size_t)(m0 >> 13) * (size_t)2 * (2 * DI) * DM;
  f32x4 acc[8][4];
#pragma unroll
  for (int i = 0; i < 8; ++i)
#pragma unroll
    for (int j = 0; j < 4; ++j) acc[i][j] = (f32x4){0.f, 0.f, 0.f, 0.f};
  int rr = lane & 15;
  int sl = lane >> 4;
  int pofs = ((sl + (rr >> 1)) & 3) * 8;    // conflict-free swizzled read slot
  int lr = lane >> 2;
  int ls = ((lane & 3) - (lr >> 1)) & 3;    // matching pre-swizzled source slot

  auto stage = [&](int tau, int buf) {
#pragma unroll
    for (int j = 0; j < 2; ++j) {
      gload16(A + (size_t)(m0 + j * 128 + wv * 16 + lr) * K + tau * 32 + ls * 8,
              &As[buf][(j * 128 + wv * 16) * 32]);
      gload16(Weff + (size_t)(n0 + j * 128 + wv * 16 + lr) * K + tau * 32 + ls * 8,
              &Wsh[buf][(j * 128 + wv * 16) * 32]);
    }
  };

  int NK = K / 32;                  // 16
  stage(0, 0);
  for (int tau = 0; tau < NK; ++tau) {
    int buf = tau & 1;
    bool more = (tau + 1 < NK);
    if (more) stage(tau + 1, buf ^ 1);
    if (more)
      asm volatile("s_waitcnt vmcnt(4)" ::: "memory");
    else
      asm volatile("s_waitcnt vmcnt(0)" ::: "memory");
    __builtin_amdgcn_sched_barrier(0);
    __builtin_amdgcn_s_barrier();
    __builtin_amdgcn_sched_barrier(0);
    bf16x8 af[8], wf[4];
#pragma unroll
    for (int mi = 0; mi < 8; ++mi)
      af[mi] = *(bf16x8*)&As[buf][(wr * 128 + mi * 16 + rr) * 32 + pofs];
#pragma unroll
    for (int ni = 0; ni < 4; ++ni)
      wf[ni] = *(bf16x8*)&Wsh[buf][(wc * 64 + ni * 16 + rr) * 32 + pofs];
    __builtin_amdgcn_s_setprio(1);
#pragma unroll
    for (int mi = 0; mi < 8; ++mi)
#pragma unroll
      for (int ni = 0; ni < 4; ++ni)
        acc[mi][ni] = MFMA_B16(af[mi], wf[ni], acc[mi][ni]);
    __builtin_amdgcn_s_setprio(0);
    asm volatile("s_waitcnt lgkmcnt(0)" ::: "memory");
    __builtin_amdgcn_sched_barrier(0);
    __builtin_amdgcn_s_barrier();
    __builtin_amdgcn_sched_barrier(0);
  }
  int cr = (lane >> 4) << 2;
  int cc = lane & 15;
  u16* outp = (n0 < DI) ? outU : outZ;
  int cb0 = (n0 < DI) ? n0 : (n0 - DI);
#pragma unroll
  for (int mi = 0; mi < 8; ++mi)
#pragma unroll
    for (int ni = 0; ni < 4; ++ni) {
      int row = m0 + wr * 128 + mi * 16 + cr;
      int col = cb0 + wc * 64 + ni * 16 + cc;
#pragma unroll
      for (int j = 0; j < 4; ++j)
        outp[(size_t)(row + j) * DI + col] = f2bf(acc[mi][ni][j]);
    }
}

// ---------------- GEMM (generic): 4-ring, stage-ahead-3, per-dir weight stride ----------------
#define EPI_F32  0
#define EPI_BF16 1
#define EPI_BIAS 2

template <int BN, int EPI, int SK = 1>
__global__ __launch_bounds__(256) void gemm_bt(const u16* __restrict__ A,
                                               const u16* __restrict__ W,
                                               void* __restrict__ outp,
                                               const float* __restrict__ bias,
                                               int N, int K, size_t wsd) {
  constexpr int BM = 128, BK = 32;
  constexpr int NF = BN / 32;
  constexpr int G = (BN == 128) ? 4 : 3;
  __shared__ u16 As[4][BM * BK];
  __shared__ u16 Wsh[4][BN * BK];
  int tid = threadIdx.x;
  int lane = tid & 63;
  int wv = tid >> 6;
  int wr = wv >> 1, wc = wv & 1;
  int m0 = blockIdx.x * BM;
  int n0 = (SK > 1) ? 0 : blockIdx.y * BN;
  int koff = (SK > 1) ? blockIdx.y * (K / SK) : 0;
  int KS = K / SK;
  int NK = KS / BK;
  const u16* Weff = W + (size_t)(m0 >> 13) * wsd;
  f32x4 acc[4][NF];
#pragma unroll
  for (int i = 0; i < 4; ++i)
#pragma unroll
    for (int j = 0; j < NF; ++j) acc[i][j] = (f32x4){0.f, 0.f, 0.f, 0.f};
  int rr = lane & 15;
  int kk = (lane >> 4) << 3;
  int l4 = lane >> 2;
  int c8 = (lane & 3) << 3;
  const u16* Ag = A + (size_t)(m0 + l4) * K + koff + c8;
  const u16* Wg = Weff + (size_t)(n0 + l4) * K + koff + c8;

  auto stage = [&](int k0, int buf) {
    gload16(Ag + (size_t)(wv * 16) * K + k0, &As[buf][wv * 512]);
    gload16(Ag + (size_t)((wv + 4) * 16) * K + k0, &As[buf][(wv + 4) * 512]);
    gload16(Wg + (size_t)(wv * 16) * K + k0, &Wsh[buf][wv * 512]);
    if (BN == 128)
      gload16(Wg + (size_t)((wv + 4) * 16) * K + k0, &Wsh[buf][(wv + 4) * 512]);
  };

  stage(0, 0); stage(BK, 1); stage(2 * BK, 2);
  for (int k = 0; k < NK; ++k) {
    if (k < NK - 2)
      asm volatile("s_waitcnt vmcnt(%0)" :: "n"(2 * G) : "memory");
    else if (k == NK - 2)
      asm volatile("s_waitcnt vmcnt(%0)" :: "n"(G) : "memory");
    else
      asm volatile("s_waitcnt vmcnt(0)" ::: "memory");
    __builtin_amdgcn_s_barrier();
    __builtin_amdgcn_sched_barrier(0);
    if (k + 3 < NK) stage((k + 3) * BK, (k + 3) & 3);
    __builtin_amdgcn_sched_barrier(0);
    int cur = k & 3;
    bf16x8 af[4], wf[NF];
#pragma unroll
    for (int mi = 0; mi < 4; ++mi)
      af[mi] = *(bf16x8*)&As[cur][(wr * 64 + mi * 16 + rr) * BK + kk];
#pragma unroll
    for (int ni = 0; ni < NF; ++ni)
      wf[ni] = *(bf16x8*)&Wsh[cur][(wc * (BN / 2) + ni * 16 + rr) * BK + kk];
#pragma unroll
    for (int mi = 0; mi < 4; ++mi)
#pragma unroll
      for (int ni = 0; ni < NF; ++ni)
        acc[mi][ni] = __builtin_amdgcn_mfma_f32_16x16x32_bf16(af[mi], wf[ni], acc[mi][ni], 0, 0, 0);
  }
  int cr = (lane >> 4) << 2;
  int cc = lane & 15;
  float* outF = (float*)outp +
      ((SK > 1) ? (size_t)blockIdx.y * (size_t)gridDim.x * BM * N : 0);
#pragma unroll
  for (int mi = 0; mi < 4; ++mi)
#pragma unroll
    for (int ni = 0; ni < NF; ++ni) {
      int row = m0 + wr * 64 + mi * 16 + cr;
      int col = n0 + wc * (BN / 2) + ni * 16 + cc;
      float bv = (EPI == EPI_BIAS) ? bias[col] : 0.f;
#pragma unroll
      for (int j = 0; j < 4; ++j) {
        float v = acc[mi][ni][j] + bv;
        if (EPI == EPI_BF16)
          ((u16*)outp)[(size_t)(row + j) * N + col] = f2bf(v);
        else
          outF[(size_t)(row + j) * N + col] = v;
      }
    }
}

// ---------------- depthwise causal conv + SiLU, both dirs ----------------
__global__ __launch_bounds__(256) void conv_k(const u16* __restrict__ xzu,
                                              const float* __restrict__ conv_w,
                                              const float* __restrict__ conv_b,
                                              int layer,
                                              u16* __restrict__ uh) {
  int idx = blockIdx.x * 256 + threadIdx.x;        // ROWS2*DI
  int c = idx & (DI - 1);
  int row = idx >> 10;
  int dir = row >> 13;
  int l = row & (L_ - 1);
  const float* cw = conv_w + (size_t)(dir * 2 + layer) * DI * 4;
  const float* cb = conv_b + (size_t)(dir * 2 + layer) * DI;
  float acc = cb[c];
#pragma unroll
  for (int j = 0; j < 4; ++j) {
    int ls = l + j - 3;
    if (ls >= 0)
      acc += bf2f(xzu[(size_t)(row + j - 3) * DI + c]) * cw[c * 4 + j];
  }
  float s = acc * sigmoidf_(acc);
  uh[idx] = f2bf(s);
}

// A-structure check
__device__ __forceinline__ bool a_fast(const float* alog, int d, float& a20) {
  a20 = -__expf(alog[d * NST]) * LN2R;
  bool fast = true;
#pragma unroll
  for (int n = 1; n < NST; ++n) {
    float an = -__expf(alog[d * NST + n]) * LN2R;
    fast &= (fabsf(an - (float)(n + 1) * a20) <= 1e-5f * (float)(n + 1) * fabsf(a20));
  }
  return fast;
}

// stage xs[CLEN][64] by summing 4 x_proj split-K partials (rowbase in rows)
__device__ __forceinline__ void stage_xs(float (*xs)[64], const float* xp,
                                         size_t rowbase, int tid) {
  size_t base = rowbase * 64;
  const float4v* s0 = (const float4v*)(xp + base);
  const float4v* s1 = (const float4v*)(xp + (size_t)ROWS2 * 64 + base);
  const float4v* s2 = (const float4v*)(xp + (size_t)2 * ROWS2 * 64 + base);
  const float4v* s3 = (const float4v*)(xp + (size_t)3 * ROWS2 * 64 + base);
  float4v* dst = (float4v*)&xs[0][0];
#pragma unroll
  for (int i = 0; i < CLEN / 16; ++i)
    dst[tid + i * 256] = s0[tid + i * 256] + s1[tid + i * 256] +
                         s2[tid + i * 256] + s3[tid + i * 256];
}

// dt = softplus(dot(xs[t][0..31], w2) + bias), 4 independent accumulator chains
__device__ __forceinline__ float dt_of(const float (*xs)[64], int t,
                                       const f32x2* w2, float bias) {
  const f32x2* x = (const f32x2*)&xs[t][0];
  f32x2 a0 = {bias, 0.f}, a1 = {0.f, 0.f}, a2 = {0.f, 0.f}, a3 = {0.f, 0.f};
#pragma unroll
  for (int j = 0; j < 4; ++j) {
    a0 = pk_fma(x[4 * j],     w2[4 * j],     a0);
    a1 = pk_fma(x[4 * j + 1], w2[4 * j + 1], a1);
    a2 = pk_fma(x[4 * j + 2], w2[4 * j + 2], a2);
    a3 = pk_fma(x[4 * j + 3], w2[4 * j + 3], a3);
  }
  float a = (a0.x + a0.y) + (a1.x + a1.y) + ((a2.x + a2.y) + (a3.x + a3.y));
  return (a > 15.f) ? a : __logf(1.f + __expf(a));
}

// ---------------- pass 1: dt + local scan + y_loc + S (both dirs) ----------------
__global__ __launch_bounds__(256) void dtscan1_k(u16* uS,
                                                 const float* __restrict__ xp,
                                                 const float* __restrict__ dtw_t,
                                                 const float* __restrict__ dtb,
                                                 const float* __restrict__ alog_,
                                                 const float* __restrict__ Dp,
                                                 int layer,
                                                 u16* __restrict__ ylg,
                                                 float* __restrict__ chk) {
  __shared__ float xs[CLEN][64];                  // 16 kB
  int blk = blockIdx.x;            // 1024 = nb(8) x chunks(32) x dgroup(4)
  int db = blk & 3;
  int c  = (blk >> 2) & (NCHUNK - 1);
  int nb = blk >> 7;               // dir*4 + b
  int dir = nb >> 2;
  int tid = threadIdx.x;
  int d  = db * 256 + tid;
  int li = dir * 2 + layer;
  const float* dtwT = dtw_t + (size_t)li * DTR * DI;
  const float* alog = alog_ + (size_t)li * DI * NST;
  int t0 = c * CLEN;
  size_t rowbase = (size_t)nb * L_ + t0;
  stage_xs(xs, xp, rowbase, tid);
  f32x2 w2[16];
#pragma unroll
  for (int j = 0; j < 16; ++j)
    w2[j] = (f32x2){dtwT[(size_t)(2 * j) * DI + d], dtwT[(size_t)(2 * j + 1) * DI + d]};
  float bias = dtb[(size_t)li * DI + d];
  float Dv = Dp[(size_t)li * DI + d];
  float a20;
  bool fast = a_fast(alog, d, a20);
  __syncthreads();
  float S = 0.f;
  size_t ubase = rowbase * DI + d;
  f32x2 h2[8];
#pragma unroll
  for (int q = 0; q < 8; ++q) h2[q] = (f32x2){0.f, 0.f};
  float uv = bf2f(uS[ubase]);
  for (int t = 0; t < CLEN; ++t) {
    float uv_nx = (t + 1 < CLEN) ? bf2f(uS[ubase + DI]) : 0.f;
    float dtv = dt_of(xs, t, w2, bias);
    float du = dtv * uv;
    S += dtv;
    f32x2 accA = {0.f, 0.f}, accB = {0.f, 0.f};
    if (fast) {
      float p1 = exp2f(dtv * a20);
      float p2 = p1 * p1;
      f32x2 pw = {p1, p2};
      f32x2 pst = {p2, p2};
      f32x2 du2 = {du, du};
#pragma unroll
      for (int k = 0; k < 4; ++k) {
        f32x4 bv = *(const f32x4*)&xs[t][DTR + k * 4];
        f32x4 cv = *(const f32x4*)&xs[t][DTR + NST + k * 4];
        f32x2 blo = __builtin_shufflevector(bv, bv, 0, 1);
        f32x2 bhi = __builtin_shufflevector(bv, bv, 2, 3);
        f32x2 clo = __builtin_shufflevector(cv, cv, 0, 1);
        f32x2 chi = __builtin_shufflevector(cv, cv, 2, 3);
        h2[2 * k]     = pk_fma(pw, h2[2 * k], pk_mul(du2, blo));
        accA          = pk_fma(h2[2 * k], clo, accA);
        pw = pk_mul(pw, pst);
        h2[2 * k + 1] = pk_fma(pw, h2[2 * k + 1], pk_mul(du2, bhi));
        accB          = pk_fma(h2[2 * k + 1], chi, accB);
        if (k < 3) pw = pk_mul(pw, pst);
      }
    } else {
#pragma unroll
      for (int q = 0; q < 8; ++q) {
        float e0 = exp2f(dtv * -__expf(alog[d * NST + 2 * q]) * LN2R);
        float e1 = exp2f(dtv * -__expf(alog[d * NST + 2 * q + 1]) * LN2R);
        f32x2 bv = *(const f32x2*)&xs[t][DTR + q * 2];
        f32x2 cv = *(const f32x2*)&xs[t][DTR + NST + q * 2];
        h2[q] = pk_fma((f32x2){e0, e1}, h2[q], pk_mul((f32x2){du, du}, bv));
        if (q & 1) accB = pk_fma(h2[q], cv, accB);
        else       accA = pk_fma(h2[q], cv, accA);
      }
    }
    float yloc = (accA.x + accA.y) + (accB.x + accB.y) + uv * Dv;
    u32 pk = cvtpk_bf16(yloc, S);   // 1 instr: lo=bf16(yloc), hi=bf16(S)
    ylg[ubase] = (u16)pk;
    uS[ubase]  = (u16)(pk >> 16);   // after uv read; same thread, same slot
    uv = uv_nx;
    ubase += DI;
  }
  const size_t H = (size_t)8 * NCHUNK * DI * NST;
  size_t idx = ((size_t)(nb * NCHUNK + c) * DI + d) * NST;
#pragma unroll
  for (int n = 0; n < NST; ++n) {
    float an = -__expf(alog[d * NST + n]) * LN2R;
    chk[idx + n]     = exp2f(an * S);
    chk[H + idx + n] = (n & 1) ? h2[n >> 1].y : h2[n >> 1].x;
  }
}

// pass 2: sequential chunk combine (both dirs)
__global__ __launch_bounds__(256) void scan2_k(float* __restrict__ chk) {
  int j = blockIdx.x * 256 + threadIdx.x;   // 131072 = 8*DI*NST
  int n = j & 15;
  int d = (j >> 4) & (DI - 1);
  int nb = j >> 14;
  const size_t H = (size_t)8 * NCHUNK * DI * NST;
  float h = 0.f;
  for (int c = 0; c < NCHUNK; ++c) {
    size_t idx = ((size_t)(nb * NCHUNK + c) * DI + d) * NST + n;
    float a = chk[idx];
    float hl = chk[H + idx];
    chk[H + idx] = h;
    h = a * h + hl;
  }
}

// pass 3 (lite): y = y_loc + sum_n C_t[n]*exp2(A2[n]*S_t)*h0[n]; fused gate.
__global__ __launch_bounds__(256) void scan3lite_k(const u16* __restrict__ uS,
                                                   const float* __restrict__ xp,
                                                   const float* __restrict__ alog_,
                                                   int layer,
                                                   const float* __restrict__ chk,
                                                   const u16* __restrict__ xzz,
                                                   u16* ylg) {
  __shared__ float xc[CLEN][NST];                 // 4 kB: C columns only
  int blk = blockIdx.x;
  int db = blk & 3;
  int c  = (blk >> 2) & (NCHUNK - 1);
  int nb = blk >> 7;
  int dir = nb >> 2;
  int tid = threadIdx.x;
  int d  = db * 256 + tid;
  int li = dir * 2 + layer;
  const float* alog = alog_ + (size_t)li * DI * NST;
  int t0 = c * CLEN;
  size_t rowbase = (size_t)nb * L_ + t0;
  {
    int r = tid >> 2, v = tid & 3;                // 64 rows x 4 vec4
    size_t base = (rowbase + r) * 64 + DTR + NST + v * 4;
    float4v s = *(const float4v*)(xp + base)
              + *(const float4v*)(xp + (size_t)ROWS2 * 64 + base)
              + *(const float4v*)(xp + (size_t)2 * ROWS2 * 64 + base)
              + *(const float4v*)(xp + (size_t)3 * ROWS2 * 64 + base);
    *(float4v*)&xc[r][v * 4] = s;
  }
  float a20;
  bool fast = a_fast(alog, d, a20);
  const size_t H = (size_t)8 * NCHUNK * DI * NST;
  size_t cidx = ((size_t)(nb * NCHUNK + c) * DI + d) * NST;
  f32x2 h2[8];
#pragma unroll
  for (int q = 0; q < 8; ++q) h2[q] = *(const f32x2*)&chk[H + cidx + 2 * q];
  float A2g[NST];
  if (!fast) {
#pragma unroll
    for (int n = 0; n < NST; ++n) A2g[n] = -__expf(alog[d * NST + n]) * LN2R;
  }
  __syncthreads();
  size_t ubase = rowbase * DI + d;
  float S = bf2f(uS[ubase]);
  for (int t = 0; t < CLEN; ++t) {
    float S_nx = (t + 1 < CLEN) ? bf2f(uS[ubase + DI]) : 0.f;
    f32x2 corrA = {0.f, 0.f}, corrB = {0.f, 0.f};
    if (fast) {
      float w1 = exp2f(a20 * S);
      float w2_ = w1 * w1;
      f32x2 pw = {w1, w2_};
      f32x2 pst = {w2_, w2_};
#pragma unroll
      for (int q = 0; q < 8; ++q) {
        f32x2 cp = *(const f32x2*)&xc[t][2 * q];
        if (q & 1) corrB = pk_fma(pk_mul(pw, h2[q]), cp, corrB);
        else       corrA = pk_fma(pk_mul(pw, h2[q]), cp, corrA);
        if (q < 7) pw = pk_mul(pw, pst);
      }
    } else {
#pragma unroll
      for (int q = 0; q < 8; ++q) {
        f32x2 e = {exp2f(A2g[2 * q] * S), exp2f(A2g[2 * q + 1] * S)};
        f32x2 cp = *(const f32x2*)&xc[t][2 * q];
        if (q & 1) corrB = pk_fma(pk_mul(e, h2[q]), cp, corrB);
        else       corrA = pk_fma(pk_mul(e, h2[q]), cp, corrA);
      }
    }
    float y = bf2f(ylg[ubase]) + (corrA.x + corrA.y) + (corrB.x + corrB.y);
    float z = bf2f(xzz[ubase]);
    float g = y * z * sigmoidf_(z);
    ylg[ubase] = (u16)cvtpk_bf16(g, g);
    S = S_nx;
    ubase += DI;
  }
}

// ---------------- final rmsnorm(hid+res) -> concat buffer, both dirs ----------------
__global__ __launch_bounds__(256) void fincat_k(const float* __restrict__ hid,
                                                const float* __restrict__ res,
                                                const float* __restrict__ norm_f,
                                                u16* __restrict__ cat) {
  int row = blockIdx.x;                 // 0..16383
  int dir = row >> 13;
  const float* w = norm_f + (size_t)dir * DM;
  int tid = threadIdx.x;
  int base = row * DM;
  float x0 = hid[base + tid] + res[base + tid];
  float x1 = hid[base + 256 + tid] + res[base + 256 + tid];
  float s = x0 * x0 + x1 * x1;
  for (int off = 32; off; off >>= 1) s += __shfl_xor(s, off);
  __shared__ float ps[4];
  if (!(tid & 63)) ps[tid >> 6] = s;
  __syncthreads();
  float tot = ps[0] + ps[1] + ps[2] + ps[3];
  float rs = 1.f / sqrtf(tot / (float)DM + 1e-5f);
  int r = row & (ROWS - 1);
  int b = r >> 11, l = r & (L_ - 1);
  size_t drow = dir ? ((size_t)(b << 11) + (L_ - 1 - l)) : (size_t)r;
  size_t obase = drow * (2 * DM) + (size_t)dir * DM;
  cat[obase + tid]       = f2bf(x0 * rs * w[tid]);
  cat[obase + 256 + tid] = f2bf(x1 * rs * w[tid + 256]);
}

extern "C" void kernel_launch(void* const* d_in, const int* in_sizes, int n_in,
                              void* d_out, int out_size, void* d_ws, size_t ws_size,
                              hipStream_t stream) {
  const int*   ids      = (const int*)d_in[0];
  const float* embed    = (const float*)d_in[2];
  const float* in_w     = (const float*)d_in[3];
  const float* conv_w   = (const float*)d_in[4];
  const float* conv_b   = (const float*)d_in[5];
  const float* x_w      = (const float*)d_in[6];
  const float* dt_w     = (const float*)d_in[7];
  const float* dt_bias  = (const float*)d_in[8];
  const float* A_log    = (const float*)d_in[9];
  const float* Dp       = (const float*)d_in[10];
  const float* out_w    = (const float*)d_in[11];
  const float* norm_w   = (const float*)d_in[12];
  const float* norm_f   = (const float*)d_in[13];
  const float* proj_w   = (const float*)d_in[14];
  const float* proj_b   = (const float*)d_in[15];

  char* ws = (char*)d_ws;
  size_t off = 0;
  auto alloc = [&](size_t bytes) {
    void* p = ws + off;
    off += (bytes + 255) & ~(size_t)255;
    return p;
  };
  float* res  = (float*)alloc((size_t)ROWS2 * DM * 4);       // 33.6 MB
  float* hid  = (float*)alloc((size_t)ROWS2 * DM * 4);       // 33.6 MB (x_proj partials alias)
  u16*   xnyg = (u16*)alloc((size_t)ROWS2 * DI * 2);         // 33.6 MB (xn | y_loc | yg)
  u16*   xzz  = (u16*)alloc((size_t)ROWS2 * DI * 2);         // 33.6 MB (z half)
  void*  shrd = alloc((size_t)ROWS2 * DI * 2);               // 33.6 MB (xzu | chk | cat)
  u16*   u_h  = (u16*)alloc((size_t)ROWS2 * DI * 2);         // 33.6 MB (uh | S)
  const int N_IN  = 4 * 2 * DI * DM;
  const int N_XW  = 4 * 64 * DI;
  const int N_OW  = 4 * DM * DI;
  const int N_PW  = DM * 2 * DM;
  const int N_DTW = 4 * DTR * DI;
  u16*   in_wb  = (u16*)alloc((size_t)N_IN * 2);             //  8.4 MB
  u16*   x_wb   = (u16*)alloc((size_t)N_XW * 2);
  u16*   out_wb = (u16*)alloc((size_t)N_OW * 2);
  u16*   pr_wb  = (u16*)alloc((size_t)N_PW * 2);
  float* dtw_t  = (float*)alloc((size_t)N_DTW * 4);
  if (off > ws_size) return;

  u16*   xzu = (u16*)shrd;
  float* chk = (float*)shrd;
  u16*   cat = (u16*)shrd;

  cvt_k<<<(N_IN / 4 + 255) / 256, 256, 0, stream>>>(in_w, in_wb, N_IN / 4);
  cvt_k<<<(N_XW / 4 + 255) / 256, 256, 0, stream>>>(x_w, x_wb, N_XW / 4);
  cvt_k<<<(N_OW / 4 + 255) / 256, 256, 0, stream>>>(out_w, out_wb, N_OW / 4);
  cvt_k<<<(N_PW / 4 + 255) / 256, 256, 0, stream>>>(proj_w, pr_wb, N_PW / 4);
  trp_k<<<N_DTW / 256, 256, 0, stream>>>(dt_w, dtw_t);

  embed_k<<<ROWS2 * DM / 256, 256, 0, stream>>>(ids, embed, res);
  for (int i = 0; i < 2; ++i) {
    if (i == 0)
      addnorm_k<false><<<ROWS2, 256, 0, stream>>>(res, hid, norm_w, i, xnyg);
    else
      addnorm_k<true><<<ROWS2, 256, 0, stream>>>(res, hid, norm_w, i, xnyg);
    g256_k<<<512, 512, 0, stream>>>(
        xnyg, in_wb + (size_t)i * 2 * DI * DM, xzu, xzz, DM);
    conv_k<<<ROWS2 * DI / 256, 256, 0, stream>>>(xzu, conv_w, conv_b, i, u_h);
    gemm_bt<64, EPI_F32, 4><<<dim3(ROWS2 / 128, 4), 256, 0, stream>>>(
        u_h, x_wb + (size_t)i * 64 * DI, hid, nullptr, 64, DI, (size_t)2 * 64 * DI);
    dtscan1_k<<<1024, 256, 0, stream>>>(u_h, hid, dtw_t, dt_bias, A_log, Dp, i,
                                        xnyg, chk);
    scan2_k<<<512, 256, 0, stream>>>(chk);
    scan3lite_k<<<1024, 256, 0, stream>>>(u_h, hid, A_log, i, chk, xzz, xnyg);
    gemm_bt<64, EPI_F32><<<dim3(ROWS2 / 128, DM / 64), 256, 0, stream>>>(
        xnyg, out_wb + (size_t)i * DM * DI, hid, nullptr, DM, DI, (size_t)2 * DM * DI);
  }
  fincat_k<<<ROWS2, 256, 0, stream>>>(hid, res, norm_f, cat);
  gemm_bt<64, EPI_BIAS><<<dim3(ROWS / 128, DM / 64), 256, 0, stream>>>(
      cat, pr_wb, (float*)d_out, proj_b, DM, DI, 0);
}

// Round 20
// 733.328 us; speedup vs baseline: 1.0771x; 1.0097x over previous
//
#include <hip/hip_runtime.h>
#include <hip/hip_bf16.h>

#define B_   4
#define L_   2048
#define DM   512
#define DI   1024
#define NST  16
#define DTR  32
#define ROWS  (B_ * L_)        // 8192
#define ROWS2 (2 * ROWS)       // 16384 (both directions)
#define NCHUNK 32
#define CLEN  (L_ / NCHUNK)    // 64
#define LN2R 1.4426950408889634f

typedef unsigned short u16;
typedef unsigned int u32;
typedef __attribute__((ext_vector_type(8))) short bf16x8;
typedef __attribute__((ext_vector_type(8))) unsigned short us8;
typedef __attribute__((ext_vector_type(4))) unsigned short us4;
typedef __attribute__((ext_vector_type(4))) float f32x4;
typedef __attribute__((ext_vector_type(4))) float float4v;
typedef __attribute__((ext_vector_type(2))) float f32x2;

__device__ __forceinline__ float bf2f(u16 h) {
  union { unsigned int u; float f; } v; v.u = ((unsigned int)h) << 16; return v.f;
}
__device__ __forceinline__ u16 f2bf(float f) {
  union { float f; unsigned int u; } v; v.f = f;
  unsigned int u = v.u;
  if ((u & 0x7fffffffu) > 0x7f800000u) return (u16)((u >> 16) | 0x0040u);
  return (u16)((u + 0x7fffu + ((u >> 16) & 1u)) >> 16);
}
// packed f32->bf16x2 (1 instr): low = cvt(a), high = cvt(b)
__device__ __forceinline__ u32 cvtpk_bf16(float a, float b) {
  u32 r; asm("v_cvt_pk_bf16_f32 %0, %1, %2" : "=v"(r) : "v"(a), "v"(b)); return r;
}
__device__ __forceinline__ float sigmoidf_(float x) { return 1.f / (1.f + __expf(-x)); }

__device__ __forceinline__ f32x2 pk_mul(f32x2 a, f32x2 b) {
  f32x2 d; asm("v_pk_mul_f32 %0, %1, %2" : "=v"(d) : "v"(a), "v"(b)); return d;
}
__device__ __forceinline__ f32x2 pk_fma(f32x2 a, f32x2 b, f32x2 c) {
  f32x2 d; asm("v_pk_fma_f32 %0, %1, %2, %3" : "=v"(d) : "v"(a), "v"(b), "v"(c)); return d;
}

__device__ __forceinline__ void gload16(const u16* g, u16* l) {
  __builtin_amdgcn_global_load_lds(
      (const __attribute__((address_space(1))) void*)g,
      (__attribute__((address_space(3))) void*)l, 16, 0, 0);
}

// ---------------- f32 -> bf16 weight conversion ----------------
__global__ __launch_bounds__(256) void cvt_k(const float* __restrict__ in,
                                             u16* __restrict__ out, int n4) {
  int i = blockIdx.x * 256 + threadIdx.x;
  if (i >= n4) return;
  float4v v = *(const float4v*)&in[i * 4];
  u16 o[4];
  o[0] = f2bf(v.x); o[1] = f2bf(v.y); o[2] = f2bf(v.z); o[3] = f2bf(v.w);
  *(ulong1*)&out[i * 4] = *(ulong1*)o;
}

// ---------------- dt_w transpose: [4][DI][DTR] -> [4][DTR][DI] (f32) ----------------
__global__ __launch_bounds__(256) void trp_k(const float* __restrict__ in,
                                             float* __restrict__ out) {
  int o = blockIdx.x * 256 + threadIdx.x;
  int li = o >> 15;
  int k = (o >> 10) & (DTR - 1);
  int d = o & (DI - 1);
  out[o] = in[((size_t)li * DI + d) * DTR + k];
}

// ---------------- embed gather, both directions ----------------
__global__ __launch_bounds__(256) void embed_k(const int* __restrict__ ids,
                                               const float* __restrict__ emb,
                                               float* __restrict__ res) {
  int idx = blockIdx.x * 256 + threadIdx.x;   // ROWS2*DM
  int c = idx & (DM - 1);
  int row = idx >> 9;                          // 0..16383
  int dir = row >> 13;
  int r = row & (ROWS - 1);
  int b = r >> 11;
  int l = r & (L_ - 1);
  int sl = dir ? (L_ - 1 - l) : l;
  int id = ids[(b << 11) + sl];
  res[idx] = emb[(size_t)dir * 128 * DM + id * DM + c];
}

// ---------------- (res += hid); xn = rmsnorm(res) * w (per-dir weights) ----------------
template <bool ADD>
__global__ __launch_bounds__(256) void addnorm_k(float* __restrict__ res,
                                                 const float* __restrict__ hid,
                                                 const float* __restrict__ norm_w,
                                                 int layer,
                                                 u16* __restrict__ xn) {
  int row = blockIdx.x;                        // 0..16383
  int dir = row >> 13;
  const float* w = norm_w + (size_t)(dir * 2 + layer) * DM;
  int tid = threadIdx.x;
  int base = row * DM;
  float x0 = res[base + tid];
  float x1 = res[base + 256 + tid];
  if (ADD) {
    x0 += hid[base + tid];
    x1 += hid[base + 256 + tid];
    res[base + tid] = x0;
    res[base + 256 + tid] = x1;
  }
  float s = x0 * x0 + x1 * x1;
  for (int off = 32; off; off >>= 1) s += __shfl_xor(s, off);
  __shared__ float ps[4];
  if (!(tid & 63)) ps[tid >> 6] = s;
  __syncthreads();
  float tot = ps[0] + ps[1] + ps[2] + ps[3];
  float rs = 1.f / sqrtf(tot / (float)DM + 1e-5f);
  xn[base + tid]       = f2bf(x0 * rs * w[tid]);
  xn[base + 256 + tid] = f2bf(x1 * rs * w[tid + 256]);
}

// ---------------- in_proj: 256x256 tile, BK=32, 2 buffers (64 kB LDS -> 2 blk/CU) ----------------
#define MFMA_B16(a, b, c) __builtin_amdgcn_mfma_f32_16x16x32_bf16(a, b, c, 0, 0, 0)

__global__ __launch_bounds__(512) void g256_k(const u16* __restrict__ A,
                                              const u16* __restrict__ W,   // layer base (dir0)
                                              u16* __restrict__ outU,
                                              u16* __restrict__ outZ,
                                              int K) {
  __shared__ u16 As[2][256 * 32];   // 32 kB
  __shared__ u16 Wsh[2][256 * 32];  // 32 kB
  int tid = threadIdx.x;
  int lane = tid & 63;
  int wv = tid >> 6;
  int wr = wv >> 2, wc = wv & 3;    // 2M x 4N waves
  int bid = blockIdx.x;             // 512 blocks: 64 mt x 8 nt
  int xcd = bid & 7, jj = bid >> 3;
  int mt = xcd * 8 + (jj & 7);      // 0..63
  int nt = jj >> 3;                 // 0..7
  int m0 = mt * 256, n0 = nt * 256;
  const u16* Weff = W + (size_t)(m0 >> 13) * (size_t)2 * (2 * DI) * DM;
  f32x4 acc[8][4];
#pragma unroll
  for (int i = 0; i < 8; ++i)
#pragma unroll
    for (int j = 0; j < 4; ++j) acc[i][j] = (f32x4){0.f, 0.f, 0.f, 0.f};
  int rr = lane & 15;
  int sl = lane >> 4;
  int pofs = ((sl + (rr >> 1)) & 3) * 8;    // conflict-free swizzled read slot
  int lr = lane >> 2;
  int ls = ((lane & 3) - (lr >> 1)) & 3;    // matching pre-swizzled source slot

  auto stage = [&](int tau, int buf) {
#pragma unroll
    for (int j = 0; j < 2; ++j) {
      gload16(A + (size_t)(m0 + j * 128 + wv * 16 + lr) * K + tau * 32 + ls * 8,
              &As[buf][(j * 128 + wv * 16) * 32]);
      gload16(Weff + (size_t)(n0 + j * 128 + wv * 16 + lr) * K + tau * 32 + ls * 8,
              &Wsh[buf][(j * 128 + wv * 16) * 32]);
    }
  };

  int NK = K / 32;                  // 16
  stage(0, 0);
  for (int tau = 0; tau < NK; ++tau) {
    int buf = tau & 1;
    bool more = (tau + 1 < NK);
    if (more) stage(tau + 1, buf ^ 1);
    if (more)
      asm volatile("s_waitcnt vmcnt(4)" ::: "memory");
    else
      asm volatile("s_waitcnt vmcnt(0)" ::: "memory");
    __builtin_amdgcn_sched_barrier(0);
    __builtin_amdgcn_s_barrier();
    __builtin_amdgcn_sched_barrier(0);
    bf16x8 af[8], wf[4];
#pragma unroll
    for (int mi = 0; mi < 8; ++mi)
      af[mi] = *(bf16x8*)&As[buf][(wr * 128 + mi * 16 + rr) * 32 + pofs];
#pragma unroll
    for (int ni = 0; ni < 4; ++ni)
      wf[ni] = *(bf16x8*)&Wsh[buf][(wc * 64 + ni * 16 + rr) * 32 + pofs];
    __builtin_amdgcn_s_setprio(1);
#pragma unroll
    for (int mi = 0; mi < 8; ++mi)
#pragma unroll
      for (int ni = 0; ni < 4; ++ni)
        acc[mi][ni] = MFMA_B16(af[mi], wf[ni], acc[mi][ni]);
    __builtin_amdgcn_s_setprio(0);
    asm volatile("s_waitcnt lgkmcnt(0)" ::: "memory");
    __builtin_amdgcn_sched_barrier(0);
    __builtin_amdgcn_s_barrier();
    __builtin_amdgcn_sched_barrier(0);
  }
  int cr = (lane >> 4) << 2;
  int cc = lane & 15;
  u16* outp = (n0 < DI) ? outU : outZ;
  int cb0 = (n0 < DI) ? n0 : (n0 - DI);
#pragma unroll
  for (int mi = 0; mi < 8; ++mi)
#pragma unroll
    for (int ni = 0; ni < 4; ++ni) {
      int row = m0 + wr * 128 + mi * 16 + cr;
      int col = cb0 + wc * 64 + ni * 16 + cc;
#pragma unroll
      for (int j = 0; j < 4; ++j)
        outp[(size_t)(row + j) * DI + col] = f2bf(acc[mi][ni][j]);
    }
}

// ---------------- GEMM (generic): 4-ring, stage-ahead-3, per-dir weight stride ----------------
#define EPI_F32  0
#define EPI_BF16 1
#define EPI_BIAS 2

template <int BN, int EPI, int SK = 1>
__global__ __launch_bounds__(256) void gemm_bt(const u16* __restrict__ A,
                                               const u16* __restrict__ W,
                                               void* __restrict__ outp,
                                               const float* __restrict__ bias,
                                               int N, int K, size_t wsd) {
  constexpr int BM = 128, BK = 32;
  constexpr int NF = BN / 32;
  constexpr int G = (BN == 128) ? 4 : 3;
  __shared__ u16 As[4][BM * BK];
  __shared__ u16 Wsh[4][BN * BK];
  int tid = threadIdx.x;
  int lane = tid & 63;
  int wv = tid >> 6;
  int wr = wv >> 1, wc = wv & 1;
  int m0 = blockIdx.x * BM;
  int n0 = (SK > 1) ? 0 : blockIdx.y * BN;
  int koff = (SK > 1) ? blockIdx.y * (K / SK) : 0;
  int KS = K / SK;
  int NK = KS / BK;
  const u16* Weff = W + (size_t)(m0 >> 13) * wsd;
  f32x4 acc[4][NF];
#pragma unroll
  for (int i = 0; i < 4; ++i)
#pragma unroll
    for (int j = 0; j < NF; ++j) acc[i][j] = (f32x4){0.f, 0.f, 0.f, 0.f};
  int rr = lane & 15;
  int kk = (lane >> 4) << 3;
  int l4 = lane >> 2;
  int c8 = (lane & 3) << 3;
  const u16* Ag = A + (size_t)(m0 + l4) * K + koff + c8;
  const u16* Wg = Weff + (size_t)(n0 + l4) * K + koff + c8;

  auto stage = [&](int k0, int buf) {
    gload16(Ag + (size_t)(wv * 16) * K + k0, &As[buf][wv * 512]);
    gload16(Ag + (size_t)((wv + 4) * 16) * K + k0, &As[buf][(wv + 4) * 512]);
    gload16(Wg + (size_t)(wv * 16) * K + k0, &Wsh[buf][wv * 512]);
    if (BN == 128)
      gload16(Wg + (size_t)((wv + 4) * 16) * K + k0, &Wsh[buf][(wv + 4) * 512]);
  };

  stage(0, 0); stage(BK, 1); stage(2 * BK, 2);
  for (int k = 0; k < NK; ++k) {
    if (k < NK - 2)
      asm volatile("s_waitcnt vmcnt(%0)" :: "n"(2 * G) : "memory");
    else if (k == NK - 2)
      asm volatile("s_waitcnt vmcnt(%0)" :: "n"(G) : "memory");
    else
      asm volatile("s_waitcnt vmcnt(0)" ::: "memory");
    __builtin_amdgcn_s_barrier();
    __builtin_amdgcn_sched_barrier(0);
    if (k + 3 < NK) stage((k + 3) * BK, (k + 3) & 3);
    __builtin_amdgcn_sched_barrier(0);
    int cur = k & 3;
    bf16x8 af[4], wf[NF];
#pragma unroll
    for (int mi = 0; mi < 4; ++mi)
      af[mi] = *(bf16x8*)&As[cur][(wr * 64 + mi * 16 + rr) * BK + kk];
#pragma unroll
    for (int ni = 0; ni < NF; ++ni)
      wf[ni] = *(bf16x8*)&Wsh[cur][(wc * (BN / 2) + ni * 16 + rr) * BK + kk];
#pragma unroll
    for (int mi = 0; mi < 4; ++mi)
#pragma unroll
      for (int ni = 0; ni < NF; ++ni)
        acc[mi][ni] = __builtin_amdgcn_mfma_f32_16x16x32_bf16(af[mi], wf[ni], acc[mi][ni], 0, 0, 0);
  }
  int cr = (lane >> 4) << 2;
  int cc = lane & 15;
  size_t poff = (SK > 1) ? (size_t)blockIdx.y * (size_t)gridDim.x * BM * N : 0;
#pragma unroll
  for (int mi = 0; mi < 4; ++mi)
#pragma unroll
    for (int ni = 0; ni < NF; ++ni) {
      int row = m0 + wr * 64 + mi * 16 + cr;
      int col = n0 + wc * (BN / 2) + ni * 16 + cc;
      float bv = (EPI == EPI_BIAS) ? bias[col] : 0.f;
#pragma unroll
      for (int j = 0; j < 4; ++j) {
        float v = acc[mi][ni][j] + bv;
        if (EPI == EPI_BF16)
          ((u16*)outp)[poff + (size_t)(row + j) * N + col] = f2bf(v);
        else
          ((float*)outp)[poff + (size_t)(row + j) * N + col] = v;
      }
    }
}

// ---------------- depthwise causal conv + SiLU, both dirs ----------------
__global__ __launch_bounds__(256) void conv_k(const u16* __restrict__ xzu,
                                              const float* __restrict__ conv_w,
                                              const float* __restrict__ conv_b,
                                              int layer,
                                              u16* __restrict__ uh) {
  int idx = blockIdx.x * 256 + threadIdx.x;        // ROWS2*DI
  int c = idx & (DI - 1);
  int row = idx >> 10;
  int dir = row >> 13;
  int l = row & (L_ - 1);
  const float* cw = conv_w + (size_t)(dir * 2 + layer) * DI * 4;
  const float* cb = conv_b + (size_t)(dir * 2 + layer) * DI;
  float acc = cb[c];
#pragma unroll
  for (int j = 0; j < 4; ++j) {
    int ls = l + j - 3;
    if (ls >= 0)
      acc += bf2f(xzu[(size_t)(row + j - 3) * DI + c]) * cw[c * 4 + j];
  }
  float s = acc * sigmoidf_(acc);
  uh[idx] = f2bf(s);
}

// A-structure check
__device__ __forceinline__ bool a_fast(const float* alog, int d, float& a20) {
  a20 = -__expf(alog[d * NST]) * LN2R;
  bool fast = true;
#pragma unroll
  for (int n = 1; n < NST; ++n) {
    float an = -__expf(alog[d * NST + n]) * LN2R;
    fast &= (fabsf(an - (float)(n + 1) * a20) <= 1e-5f * (float)(n + 1) * fabsf(a20));
  }
  return fast;
}

// stage xs[CLEN][64] by summing 4 bf16 x_proj split-K partials (rowbase in rows)
__device__ __forceinline__ void stage_xs(float (*xs)[64], const u16* xp,
                                         size_t rowbase, int tid) {
  size_t base = rowbase * 64;
  const size_t P = (size_t)ROWS2 * 64;
#pragma unroll
  for (int i = 0; i < (CLEN * 64) / (8 * 256); ++i) {   // CLEN=64 -> 2 iters
    size_t e = base + ((size_t)tid + i * 256) * 8;
    us8 a = *(const us8*)(xp + e);
    us8 b = *(const us8*)(xp + P + e);
    us8 c = *(const us8*)(xp + 2 * P + e);
    us8 d = *(const us8*)(xp + 3 * P + e);
    float* dst = &xs[0][0] + ((size_t)tid + i * 256) * 8;
#pragma unroll
    for (int j = 0; j < 8; ++j)
      dst[j] = (bf2f(a[j]) + bf2f(b[j])) + (bf2f(c[j]) + bf2f(d[j]));
  }
}

// dt = softplus(dot(xs[t][0..31], w2) + bias), 4 independent accumulator chains
__device__ __forceinline__ float dt_of(const float (*xs)[64], int t,
                                       const f32x2* w2, float bias) {
  const f32x2* x = (const f32x2*)&xs[t][0];
  f32x2 a0 = {bias, 0.f}, a1 = {0.f, 0.f}, a2 = {0.f, 0.f}, a3 = {0.f, 0.f};
#pragma unroll
  for (int j = 0; j < 4; ++j) {
    a0 = pk_fma(x[4 * j],     w2[4 * j],     a0);
    a1 = pk_fma(x[4 * j + 1], w2[4 * j + 1], a1);
    a2 = pk_fma(x[4 * j + 2], w2[4 * j + 2], a2);
    a3 = pk_fma(x[4 * j + 3], w2[4 * j + 3], a3);
  }
  float a = (a0.x + a0.y) + (a1.x + a1.y) + ((a2.x + a2.y) + (a3.x + a3.y));
  return (a > 15.f) ? a : __logf(1.f + __expf(a));
}

// ---------------- pass 1: dt + local scan + y_loc + S (both dirs) ----------------
__global__ __launch_bounds__(256) void dtscan1_k(u16* uS,
                                                 const u16* __restrict__ xp,
                                                 const float* __restrict__ dtw_t,
                                                 const float* __restrict__ dtb,
                                                 const float* __restrict__ alog_,
                                                 const float* __restrict__ Dp,
                                                 int layer,
                                                 u16* __restrict__ ylg,
                                                 float* __restrict__ chk) {
  __shared__ float xs[CLEN][64];                  // 16 kB
  int blk = blockIdx.x;            // 1024 = nb(8) x chunks(32) x dgroup(4)
  int db = blk & 3;
  int c  = (blk >> 2) & (NCHUNK - 1);
  int nb = blk >> 7;               // dir*4 + b
  int dir = nb >> 2;
  int tid = threadIdx.x;
  int d  = db * 256 + tid;
  int li = dir * 2 + layer;
  const float* dtwT = dtw_t + (size_t)li * DTR * DI;
  const float* alog = alog_ + (size_t)li * DI * NST;
  int t0 = c * CLEN;
  size_t rowbase = (size_t)nb * L_ + t0;
  stage_xs(xs, xp, rowbase, tid);
  f32x2 w2[16];
#pragma unroll
  for (int j = 0; j < 16; ++j)
    w2[j] = (f32x2){dtwT[(size_t)(2 * j) * DI + d], dtwT[(size_t)(2 * j + 1) * DI + d]};
  float bias = dtb[(size_t)li * DI + d];
  float Dv = Dp[(size_t)li * DI + d];
  float a20;
  bool fast = a_fast(alog, d, a20);
  __syncthreads();
  float S = 0.f;
  size_t ubase = rowbase * DI + d;
  f32x2 h2[8];
#pragma unroll
  for (int q = 0; q < 8; ++q) h2[q] = (f32x2){0.f, 0.f};
  float uv = bf2f(uS[ubase]);
  for (int t = 0; t < CLEN; ++t) {
    float uv_nx = (t + 1 < CLEN) ? bf2f(uS[ubase + DI]) : 0.f;
    float dtv = dt_of(xs, t, w2, bias);
    float du = dtv * uv;
    S += dtv;
    f32x2 accA = {0.f, 0.f}, accB = {0.f, 0.f};
    if (fast) {
      float p1 = exp2f(dtv * a20);
      float p2 = p1 * p1;
      f32x2 pw = {p1, p2};
      f32x2 pst = {p2, p2};
      f32x2 du2 = {du, du};
#pragma unroll
      for (int k = 0; k < 4; ++k) {
        f32x4 bv = *(const f32x4*)&xs[t][DTR + k * 4];
        f32x4 cv = *(const f32x4*)&xs[t][DTR + NST + k * 4];
        f32x2 blo = __builtin_shufflevector(bv, bv, 0, 1);
        f32x2 bhi = __builtin_shufflevector(bv, bv, 2, 3);
        f32x2 clo = __builtin_shufflevector(cv, cv, 0, 1);
        f32x2 chi = __builtin_shufflevector(cv, cv, 2, 3);
        h2[2 * k]     = pk_fma(pw, h2[2 * k], pk_mul(du2, blo));
        accA          = pk_fma(h2[2 * k], clo, accA);
        pw = pk_mul(pw, pst);
        h2[2 * k + 1] = pk_fma(pw, h2[2 * k + 1], pk_mul(du2, bhi));
        accB          = pk_fma(h2[2 * k + 1], chi, accB);
        if (k < 3) pw = pk_mul(pw, pst);
      }
    } else {
#pragma unroll
      for (int q = 0; q < 8; ++q) {
        float e0 = exp2f(dtv * -__expf(alog[d * NST + 2 * q]) * LN2R);
        float e1 = exp2f(dtv * -__expf(alog[d * NST + 2 * q + 1]) * LN2R);
        f32x2 bv = *(const f32x2*)&xs[t][DTR + q * 2];
        f32x2 cv = *(const f32x2*)&xs[t][DTR + NST + q * 2];
        h2[q] = pk_fma((f32x2){e0, e1}, h2[q], pk_mul((f32x2){du, du}, bv));
        if (q & 1) accB = pk_fma(h2[q], cv, accB);
        else       accA = pk_fma(h2[q], cv, accA);
      }
    }
    float yloc = (accA.x + accA.y) + (accB.x + accB.y) + uv * Dv;
    u32 pk = cvtpk_bf16(yloc, S);   // 1 instr: lo=bf16(yloc), hi=bf16(S)
    ylg[ubase] = (u16)pk;
    uS[ubase]  = (u16)(pk >> 16);   // after uv read; same thread, same slot
    uv = uv_nx;
    ubase += DI;
  }
  const size_t H = (size_t)8 * NCHUNK * DI * NST;
  size_t idx = ((size_t)(nb * NCHUNK + c) * DI + d) * NST;
#pragma unroll
  for (int n = 0; n < NST; ++n) {
    float an = -__expf(alog[d * NST + n]) * LN2R;
    chk[idx + n]     = exp2f(an * S);
    chk[H + idx + n] = (n & 1) ? h2[n >> 1].y : h2[n >> 1].x;
  }
}

// pass 2: sequential chunk combine (both dirs)
__global__ __launch_bounds__(256) void scan2_k(float* __restrict__ chk) {
  int j = blockIdx.x * 256 + threadIdx.x;   // 131072 = 8*DI*NST
  int n = j & 15;
  int d = (j >> 4) & (DI - 1);
  int nb = j >> 14;
  const size_t H = (size_t)8 * NCHUNK * DI * NST;
  float h = 0.f;
  for (int c = 0; c < NCHUNK; ++c) {
    size_t idx = ((size_t)(nb * NCHUNK + c) * DI + d) * NST + n;
    float a = chk[idx];
    float hl = chk[H + idx];
    chk[H + idx] = h;
    h = a * h + hl;
  }
}

// pass 3 (lite): y = y_loc + sum_n C_t[n]*exp2(A2[n]*S_t)*h0[n]; fused gate.
__global__ __launch_bounds__(256) void scan3lite_k(const u16* __restrict__ uS,
                                                   const u16* __restrict__ xp,
                                                   const float* __restrict__ alog_,
                                                   int layer,
                                                   const float* __restrict__ chk,
                                                   const u16* __restrict__ xzz,
                                                   u16* ylg) {
  __shared__ float xc[CLEN][NST];                 // 4 kB: C columns only
  int blk = blockIdx.x;
  int db = blk & 3;
  int c  = (blk >> 2) & (NCHUNK - 1);
  int nb = blk >> 7;
  int dir = nb >> 2;
  int tid = threadIdx.x;
  int d  = db * 256 + tid;
  int li = dir * 2 + layer;
  const float* alog = alog_ + (size_t)li * DI * NST;
  int t0 = c * CLEN;
  size_t rowbase = (size_t)nb * L_ + t0;
  {
    int r = tid >> 2, v = tid & 3;                // 64 rows x 4 vec4
    const size_t P = (size_t)ROWS2 * 64;
    size_t e = (rowbase + r) * 64 + DTR + NST + v * 4;
    us4 a = *(const us4*)(xp + e);
    us4 b = *(const us4*)(xp + P + e);
    us4 c2 = *(const us4*)(xp + 2 * P + e);
    us4 d2 = *(const us4*)(xp + 3 * P + e);
#pragma unroll
    for (int j = 0; j < 4; ++j)
      xc[r][v * 4 + j] = (bf2f(a[j]) + bf2f(b[j])) + (bf2f(c2[j]) + bf2f(d2[j]));
  }
  float a20;
  bool fast = a_fast(alog, d, a20);
  const size_t H = (size_t)8 * NCHUNK * DI * NST;
  size_t cidx = ((size_t)(nb * NCHUNK + c) * DI + d) * NST;
  f32x2 h2[8];
#pragma unroll
  for (int q = 0; q < 8; ++q) h2[q] = *(const f32x2*)&chk[H + cidx + 2 * q];
  float A2g[NST];
  if (!fast) {
#pragma unroll
    for (int n = 0; n < NST; ++n) A2g[n] = -__expf(alog[d * NST + n]) * LN2R;
  }
  __syncthreads();
  size_t ubase = rowbase * DI + d;
  float S = bf2f(uS[ubase]);
  for (int t = 0; t < CLEN; ++t) {
    float S_nx = (t + 1 < CLEN) ? bf2f(uS[ubase + DI]) : 0.f;
    f32x2 corrA = {0.f, 0.f}, corrB = {0.f, 0.f};
    if (fast) {
      float w1 = exp2f(a20 * S);
      float w2_ = w1 * w1;
      f32x2 pw = {w1, w2_};
      f32x2 pst = {w2_, w2_};
#pragma unroll
      for (int q = 0; q < 8; ++q) {
        f32x2 cp = *(const f32x2*)&xc[t][2 * q];
        if (q & 1) corrB = pk_fma(pk_mul(pw, h2[q]), cp, corrB);
        else       corrA = pk_fma(pk_mul(pw, h2[q]), cp, corrA);
        if (q < 7) pw = pk_mul(pw, pst);
      }
    } else {
#pragma unroll
      for (int q = 0; q < 8; ++q) {
        f32x2 e = {exp2f(A2g[2 * q] * S), exp2f(A2g[2 * q + 1] * S)};
        f32x2 cp = *(const f32x2*)&xc[t][2 * q];
        if (q & 1) corrB = pk_fma(pk_mul(e, h2[q]), cp, corrB);
        else       corrA = pk_fma(pk_mul(e, h2[q]), cp, corrA);
      }
    }
    float y = bf2f(ylg[ubase]) + (corrA.x + corrA.y) + (corrB.x + corrB.y);
    float z = bf2f(xzz[ubase]);
    float g = y * z * sigmoidf_(z);
    ylg[ubase] = (u16)cvtpk_bf16(g, g);
    S = S_nx;
    ubase += DI;
  }
}

// ---------------- final rmsnorm(hid+res) -> concat buffer, both dirs ----------------
__global__ __launch_bounds__(256) void fincat_k(const float* __restrict__ hid,
                                                const float* __restrict__ res,
                                                const float* __restrict__ norm_f,
                                                u16* __restrict__ cat) {
  int row = blockIdx.x;                 // 0..16383
  int dir = row >> 13;
  const float* w = norm_f + (size_t)dir * DM;
  int tid = threadIdx.x;
  int base = row * DM;
  float x0 = hid[base + tid] + res[base + tid];
  float x1 = hid[base + 256 + tid] + res[base + 256 + tid];
  float s = x0 * x0 + x1 * x1;
  for (int off = 32; off; off >>= 1) s += __shfl_xor(s, off);
  __shared__ float ps[4];
  if (!(tid & 63)) ps[tid >> 6] = s;
  __syncthreads();
  float tot = ps[0] + ps[1] + ps[2] + ps[3];
  float rs = 1.f / sqrtf(tot / (float)DM + 1e-5f);
  int r = row & (ROWS - 1);
  int b = r >> 11, l = r & (L_ - 1);
  size_t drow = dir ? ((size_t)(b << 11) + (L_ - 1 - l)) : (size_t)r;
  size_t obase = drow * (2 * DM) + (size_t)dir * DM;
  cat[obase + tid]       = f2bf(x0 * rs * w[tid]);
  cat[obase + 256 + tid] = f2bf(x1 * rs * w[tid + 256]);
}

extern "C" void kernel_launch(void* const* d_in, const int* in_sizes, int n_in,
                              void* d_out, int out_size, void* d_ws, size_t ws_size,
                              hipStream_t stream) {
  const int*   ids      = (const int*)d_in[0];
  const float* embed    = (const float*)d_in[2];
  const float* in_w     = (const float*)d_in[3];
  const float* conv_w   = (const float*)d_in[4];
  const float* conv_b   = (const float*)d_in[5];
  const float* x_w      = (const float*)d_in[6];
  const float* dt_w     = (const float*)d_in[7];
  const float* dt_bias  = (const float*)d_in[8];
  const float* A_log    = (const float*)d_in[9];
  const float* Dp       = (const float*)d_in[10];
  const float* out_w    = (const float*)d_in[11];
  const float* norm_w   = (const float*)d_in[12];
  const float* norm_f   = (const float*)d_in[13];
  const float* proj_w   = (const float*)d_in[14];
  const float* proj_b   = (const float*)d_in[15];

  char* ws = (char*)d_ws;
  size_t off = 0;
  auto alloc = [&](size_t bytes) {
    void* p = ws + off;
    off += (bytes + 255) & ~(size_t)255;
    return p;
  };
  float* res  = (float*)alloc((size_t)ROWS2 * DM * 4);       // 33.6 MB
  float* hid  = (float*)alloc((size_t)ROWS2 * DM * 4);       // 33.6 MB (x_proj bf16 partials alias)
  u16*   xnyg = (u16*)alloc((size_t)ROWS2 * DI * 2);         // 33.6 MB (xn | y_loc | yg)
  u16*   xzz  = (u16*)alloc((size_t)ROWS2 * DI * 2);         // 33.6 MB (z half)
  void*  shrd = alloc((size_t)ROWS2 * DI * 2);               // 33.6 MB (xzu | chk | cat)
  u16*   u_h  = (u16*)alloc((size_t)ROWS2 * DI * 2);         // 33.6 MB (uh | S)
  const int N_IN  = 4 * 2 * DI * DM;
  const int N_XW  = 4 * 64 * DI;
  const int N_OW  = 4 * DM * DI;
  const int N_PW  = DM * 2 * DM;
  const int N_DTW = 4 * DTR * DI;
  u16*   in_wb  = (u16*)alloc((size_t)N_IN * 2);             //  8.4 MB
  u16*   x_wb   = (u16*)alloc((size_t)N_XW * 2);
  u16*   out_wb = (u16*)alloc((size_t)N_OW * 2);
  u16*   pr_wb  = (u16*)alloc((size_t)N_PW * 2);
  float* dtw_t  = (float*)alloc((size_t)N_DTW * 4);
  if (off > ws_size) return;

  u16*   xzu = (u16*)shrd;
  float* chk = (float*)shrd;
  u16*   cat = (u16*)shrd;
  u16*   xpb = (u16*)hid;       // bf16 x_proj partials: 4 x ROWS2 x 64 u16 = 8.4 MB

  cvt_k<<<(N_IN / 4 + 255) / 256, 256, 0, stream>>>(in_w, in_wb, N_IN / 4);
  cvt_k<<<(N_XW / 4 + 255) / 256, 256, 0, stream>>>(x_w, x_wb, N_XW / 4);
  cvt_k<<<(N_OW / 4 + 255) / 256, 256, 0, stream>>>(out_w, out_wb, N_OW / 4);
  cvt_k<<<(N_PW / 4 + 255) / 256, 256, 0, stream>>>(proj_w, pr_wb, N_PW / 4);
  trp_k<<<N_DTW / 256, 256, 0, stream>>>(dt_w, dtw_t);

  embed_k<<<ROWS2 * DM / 256, 256, 0, stream>>>(ids, embed, res);
  for (int i = 0; i < 2; ++i) {
    if (i == 0)
      addnorm_k<false><<<ROWS2, 256, 0, stream>>>(res, hid, norm_w, i, xnyg);
    else
      addnorm_k<true><<<ROWS2, 256, 0, stream>>>(res, hid, norm_w, i, xnyg);
    g256_k<<<512, 512, 0, stream>>>(
        xnyg, in_wb + (size_t)i * 2 * DI * DM, xzu, xzz, DM);
    conv_k<<<ROWS2 * DI / 256, 256, 0, stream>>>(xzu, conv_w, conv_b, i, u_h);
    gemm_bt<64, EPI_BF16, 4><<<dim3(ROWS2 / 128, 4), 256, 0, stream>>>(
        u_h, x_wb + (size_t)i * 64 * DI, xpb, nullptr, 64, DI, (size_t)2 * 64 * DI);
    dtscan1_k<<<1024, 256, 0, stream>>>(u_h, xpb, dtw_t, dt_bias, A_log, Dp, i,
                                        xnyg, chk);
    scan2_k<<<512, 256, 0, stream>>>(chk);
    scan3lite_k<<<1024, 256, 0, stream>>>(u_h, xpb, A_log, i, chk, xzz, xnyg);
    gemm_bt<64, EPI_F32><<<dim3(ROWS2 / 128, DM / 64), 256, 0, stream>>>(
        xnyg, out_wb + (size_t)i * DM * DI, hid, nullptr, DM, DI, (size_t)2 * DM * DI);
  }
  fincat_k<<<ROWS2, 256, 0, stream>>>(hid, res, norm_f, cat);
  gemm_bt<64, EPI_BIAS><<<dim3(ROWS / 128, DM / 64), 256, 0, stream>>>(
      cat, pr_wb, (float*)d_out, proj_b, DM, DI, 0);
}

// Round 21
// 720.984 us; speedup vs baseline: 1.0955x; 1.0171x over previous
//
#include <hip/hip_runtime.h>
#include <hip/hip_bf16.h>

#define B_   4
#define L_   2048
#define DM   512
#define DI   1024
#define NST  16
#define DTR  32
#define ROWS  (B_ * L_)        // 8192
#define ROWS2 (2 * ROWS)       // 16384 (both directions)
#define NCHUNK 32
#define CLEN  (L_ / NCHUNK)    // 64
#define LN2R 1.4426950408889634f

typedef unsigned short u16;
typedef unsigned int u32;
typedef __attribute__((ext_vector_type(8))) short bf16x8;
typedef __attribute__((ext_vector_type(8))) unsigned short us8;
typedef __attribute__((ext_vector_type(4))) unsigned short us4;
typedef __attribute__((ext_vector_type(4))) float f32x4;
typedef __attribute__((ext_vector_type(4))) float float4v;
typedef __attribute__((ext_vector_type(2))) float f32x2;

__device__ __forceinline__ float bf2f(u16 h) {
  union { unsigned int u; float f; } v; v.u = ((unsigned int)h) << 16; return v.f;
}
__device__ __forceinline__ u16 f2bf(float f) {
  union { float f; unsigned int u; } v; v.f = f;
  unsigned int u = v.u;
  if ((u & 0x7fffffffu) > 0x7f800000u) return (u16)((u >> 16) | 0x0040u);
  return (u16)((u + 0x7fffu + ((u >> 16) & 1u)) >> 16);
}
// packed f32->bf16x2 (1 instr): low = cvt(a), high = cvt(b)
__device__ __forceinline__ u32 cvtpk_bf16(float a, float b) {
  u32 r; asm("v_cvt_pk_bf16_f32 %0, %1, %2" : "=v"(r) : "v"(a), "v"(b)); return r;
}
__device__ __forceinline__ float sigmoidf_(float x) { return 1.f / (1.f + __expf(-x)); }

__device__ __forceinline__ f32x2 pk_mul(f32x2 a, f32x2 b) {
  f32x2 d; asm("v_pk_mul_f32 %0, %1, %2" : "=v"(d) : "v"(a), "v"(b)); return d;
}
__device__ __forceinline__ f32x2 pk_fma(f32x2 a, f32x2 b, f32x2 c) {
  f32x2 d; asm("v_pk_fma_f32 %0, %1, %2, %3" : "=v"(d) : "v"(a), "v"(b), "v"(c)); return d;
}

__device__ __forceinline__ void gload16(const u16* g, u16* l) {
  __builtin_amdgcn_global_load_lds(
      (const __attribute__((address_space(1))) void*)g,
      (__attribute__((address_space(3))) void*)l, 16, 0, 0);
}

// ---------------- f32 -> bf16 weight conversion ----------------
__global__ __launch_bounds__(256) void cvt_k(const float* __restrict__ in,
                                             u16* __restrict__ out, int n4) {
  int i = blockIdx.x * 256 + threadIdx.x;
  if (i >= n4) return;
  float4v v = *(const float4v*)&in[i * 4];
  u16 o[4];
  o[0] = f2bf(v.x); o[1] = f2bf(v.y); o[2] = f2bf(v.z); o[3] = f2bf(v.w);
  *(ulong1*)&out[i * 4] = *(ulong1*)o;
}

// ---------------- dt_w transpose: [4][DI][DTR] -> [4][DTR][DI] (f32) ----------------
__global__ __launch_bounds__(256) void trp_k(const float* __restrict__ in,
                                             float* __restrict__ out) {
  int o = blockIdx.x * 256 + threadIdx.x;
  int li = o >> 15;
  int k = (o >> 10) & (DTR - 1);
  int d = o & (DI - 1);
  out[o] = in[((size_t)li * DI + d) * DTR + k];
}

// ---------------- embed gather, both directions ----------------
__global__ __launch_bounds__(256) void embed_k(const int* __restrict__ ids,
                                               const float* __restrict__ emb,
                                               float* __restrict__ res) {
  int idx = blockIdx.x * 256 + threadIdx.x;   // ROWS2*DM
  int c = idx & (DM - 1);
  int row = idx >> 9;                          // 0..16383
  int dir = row >> 13;
  int r = row & (ROWS - 1);
  int b = r >> 11;
  int l = r & (L_ - 1);
  int sl = dir ? (L_ - 1 - l) : l;
  int id = ids[(b << 11) + sl];
  res[idx] = emb[(size_t)dir * 128 * DM + id * DM + c];
}

// ---------------- (res += hid16); xn = rmsnorm(res) * w (per-dir weights) ----------------
template <bool ADD>
__global__ __launch_bounds__(256) void addnorm_k(float* __restrict__ res,
                                                 const u16* __restrict__ hid,
                                                 const float* __restrict__ norm_w,
                                                 int layer,
                                                 u16* __restrict__ xn) {
  int row = blockIdx.x;                        // 0..16383
  int dir = row >> 13;
  const float* w = norm_w + (size_t)(dir * 2 + layer) * DM;
  int tid = threadIdx.x;
  int base = row * DM;
  float x0 = res[base + tid];
  float x1 = res[base + 256 + tid];
  if (ADD) {
    x0 += bf2f(hid[base + tid]);
    x1 += bf2f(hid[base + 256 + tid]);
    res[base + tid] = x0;
    res[base + 256 + tid] = x1;
  }
  float s = x0 * x0 + x1 * x1;
  for (int off = 32; off; off >>= 1) s += __shfl_xor(s, off);
  __shared__ float ps[4];
  if (!(tid & 63)) ps[tid >> 6] = s;
  __syncthreads();
  float tot = ps[0] + ps[1] + ps[2] + ps[3];
  float rs = 1.f / sqrtf(tot / (float)DM + 1e-5f);
  xn[base + tid]       = f2bf(x0 * rs * w[tid]);
  xn[base + 256 + tid] = f2bf(x1 * rs * w[tid + 256]);
}

// ---------------- in_proj: 256x256 tile, BK=32, 2 buffers (64 kB LDS -> 2 blk/CU) ----------------
#define MFMA_B16(a, b, c) __builtin_amdgcn_mfma_f32_16x16x32_bf16(a, b, c, 0, 0, 0)

__global__ __launch_bounds__(512) void g256_k(const u16* __restrict__ A,
                                              const u16* __restrict__ W,   // layer base (dir0)
                                              u16* __restrict__ outU,
                                              u16* __restrict__ outZ,
                                              int K) {
  __shared__ u16 As[2][256 * 32];   // 32 kB
  __shared__ u16 Wsh[2][256 * 32];  // 32 kB
  int tid = threadIdx.x;
  int lane = tid & 63;
  int wv = tid >> 6;
  int wr = wv >> 2, wc = wv & 3;    // 2M x 4N waves
  int bid = blockIdx.x;             // 512 blocks: 64 mt x 8 nt
  int xcd = bid & 7, jj = bid >> 3;
  int mt = xcd * 8 + (jj & 7);      // 0..63
  int nt = jj >> 3;                 // 0..7
  int m0 = mt * 256, n0 = nt * 256;
  const u16* Weff = W + (size_t)(m0 >> 13) * (size_t)2 * (2 * DI) * DM;
  f32x4 acc[8][4];
#pragma unroll
  for (int i = 0; i < 8; ++i)
#pragma unroll
    for (int j = 0; j < 4; ++j) acc[i][j] = (f32x4){0.f, 0.f, 0.f, 0.f};
  int rr = lane & 15;
  int sl = lane >> 4;
  int pofs = ((sl + (rr >> 1)) & 3) * 8;    // conflict-free swizzled read slot
  int lr = lane >> 2;
  int ls = ((lane & 3) - (lr >> 1)) & 3;    // matching pre-swizzled source slot

  auto stage = [&](int tau, int buf) {
#pragma unroll
    for (int j = 0; j < 2; ++j) {
      gload16(A + (size_t)(m0 + j * 128 + wv * 16 + lr) * K + tau * 32 + ls * 8,
              &As[buf][(j * 128 + wv * 16) * 32]);
      gload16(Weff + (size_t)(n0 + j * 128 + wv * 16 + lr) * K + tau * 32 + ls * 8,
              &Wsh[buf][(j * 128 + wv * 16) * 32]);
    }
  };

  int NK = K / 32;                  // 16
  stage(0, 0);
  for (int tau = 0; tau < NK; ++tau) {
    int buf = tau & 1;
    bool more = (tau + 1 < NK);
    if (more) stage(tau + 1, buf ^ 1);
    if (more)
      asm volatile("s_waitcnt vmcnt(4)" ::: "memory");
    else
      asm volatile("s_waitcnt vmcnt(0)" ::: "memory");
    __builtin_amdgcn_sched_barrier(0);
    __builtin_amdgcn_s_barrier();
    __builtin_amdgcn_sched_barrier(0);
    bf16x8 af[8], wf[4];
#pragma unroll
    for (int mi = 0; mi < 8; ++mi)
      af[mi] = *(bf16x8*)&As[buf][(wr * 128 + mi * 16 + rr) * 32 + pofs];
#pragma unroll
    for (int ni = 0; ni < 4; ++ni)
      wf[ni] = *(bf16x8*)&Wsh[buf][(wc * 64 + ni * 16 + rr) * 32 + pofs];
    __builtin_amdgcn_s_setprio(1);
#pragma unroll
    for (int mi = 0; mi < 8; ++mi)
#pragma unroll
      for (int ni = 0; ni < 4; ++ni)
        acc[mi][ni] = MFMA_B16(af[mi], wf[ni], acc[mi][ni]);
    __builtin_amdgcn_s_setprio(0);
    asm volatile("s_waitcnt lgkmcnt(0)" ::: "memory");
    __builtin_amdgcn_sched_barrier(0);
    __builtin_amdgcn_s_barrier();
    __builtin_amdgcn_sched_barrier(0);
  }
  int cr = (lane >> 4) << 2;
  int cc = lane & 15;
  u16* outp = (n0 < DI) ? outU : outZ;
  int cb0 = (n0 < DI) ? n0 : (n0 - DI);
#pragma unroll
  for (int mi = 0; mi < 8; ++mi)
#pragma unroll
    for (int ni = 0; ni < 4; ++ni) {
      int row = m0 + wr * 128 + mi * 16 + cr;
      int col = cb0 + wc * 64 + ni * 16 + cc;
#pragma unroll
      for (int j = 0; j < 4; ++j)
        outp[(size_t)(row + j) * DI + col] = f2bf(acc[mi][ni][j]);
    }
}

// ---------------- GEMM (generic): 4-ring, stage-ahead-3, per-dir weight stride ----------------
#define EPI_F32  0
#define EPI_BF16 1
#define EPI_BIAS 2

template <int BN, int EPI, int SK = 1>
__global__ __launch_bounds__(256) void gemm_bt(const u16* __restrict__ A,
                                               const u16* __restrict__ W,
                                               void* __restrict__ outp,
                                               const float* __restrict__ bias,
                                               int N, int K, size_t wsd) {
  constexpr int BM = 128, BK = 32;
  constexpr int NF = BN / 32;
  constexpr int G = (BN == 128) ? 4 : 3;
  __shared__ u16 As[4][BM * BK];
  __shared__ u16 Wsh[4][BN * BK];
  int tid = threadIdx.x;
  int lane = tid & 63;
  int wv = tid >> 6;
  int wr = wv >> 1, wc = wv & 1;
  int m0 = blockIdx.x * BM;
  int n0 = (SK > 1) ? 0 : blockIdx.y * BN;
  int koff = (SK > 1) ? blockIdx.y * (K / SK) : 0;
  int KS = K / SK;
  int NK = KS / BK;
  const u16* Weff = W + (size_t)(m0 >> 13) * wsd;
  f32x4 acc[4][NF];
#pragma unroll
  for (int i = 0; i < 4; ++i)
#pragma unroll
    for (int j = 0; j < NF; ++j) acc[i][j] = (f32x4){0.f, 0.f, 0.f, 0.f};
  int rr = lane & 15;
  int kk = (lane >> 4) << 3;
  int l4 = lane >> 2;
  int c8 = (lane & 3) << 3;
  const u16* Ag = A + (size_t)(m0 + l4) * K + koff + c8;
  const u16* Wg = Weff + (size_t)(n0 + l4) * K + koff + c8;

  auto stage = [&](int k0, int buf) {
    gload16(Ag + (size_t)(wv * 16) * K + k0, &As[buf][wv * 512]);
    gload16(Ag + (size_t)((wv + 4) * 16) * K + k0, &As[buf][(wv + 4) * 512]);
    gload16(Wg + (size_t)(wv * 16) * K + k0, &Wsh[buf][wv * 512]);
    if (BN == 128)
      gload16(Wg + (size_t)((wv + 4) * 16) * K + k0, &Wsh[buf][(wv + 4) * 512]);
  };

  stage(0, 0); stage(BK, 1); stage(2 * BK, 2);
  for (int k = 0; k < NK; ++k) {
    if (k < NK - 2)
      asm volatile("s_waitcnt vmcnt(%0)" :: "n"(2 * G) : "memory");
    else if (k == NK - 2)
      asm volatile("s_waitcnt vmcnt(%0)" :: "n"(G) : "memory");
    else
      asm volatile("s_waitcnt vmcnt(0)" ::: "memory");
    __builtin_amdgcn_s_barrier();
    __builtin_amdgcn_sched_barrier(0);
    if (k + 3 < NK) stage((k + 3) * BK, (k + 3) & 3);
    __builtin_amdgcn_sched_barrier(0);
    int cur = k & 3;
    bf16x8 af[4], wf[NF];
#pragma unroll
    for (int mi = 0; mi < 4; ++mi)
      af[mi] = *(bf16x8*)&As[cur][(wr * 64 + mi * 16 + rr) * BK + kk];
#pragma unroll
    for (int ni = 0; ni < NF; ++ni)
      wf[ni] = *(bf16x8*)&Wsh[cur][(wc * (BN / 2) + ni * 16 + rr) * BK + kk];
#pragma unroll
    for (int mi = 0; mi < 4; ++mi)
#pragma unroll
      for (int ni = 0; ni < NF; ++ni)
        acc[mi][ni] = __builtin_amdgcn_mfma_f32_16x16x32_bf16(af[mi], wf[ni], acc[mi][ni], 0, 0, 0);
  }
  int cr = (lane >> 4) << 2;
  int cc = lane & 15;
  size_t poff = (SK > 1) ? (size_t)blockIdx.y * (size_t)gridDim.x * BM * N : 0;
#pragma unroll
  for (int mi = 0; mi < 4; ++mi)
#pragma unroll
    for (int ni = 0; ni < NF; ++ni) {
      int row = m0 + wr * 64 + mi * 16 + cr;
      int col = n0 + wc * (BN / 2) + ni * 16 + cc;
      float bv = (EPI == EPI_BIAS) ? bias[col] : 0.f;
#pragma unroll
      for (int j = 0; j < 4; ++j) {
        float v = acc[mi][ni][j] + bv;
        if (EPI == EPI_BF16)
          ((u16*)outp)[poff + (size_t)(row + j) * N + col] = f2bf(v);
        else
          ((float*)outp)[poff + (size_t)(row + j) * N + col] = v;
      }
    }
}

// ---------------- depthwise causal conv + SiLU, both dirs ----------------
__global__ __launch_bounds__(256) void conv_k(const u16* __restrict__ xzu,
                                              const float* __restrict__ conv_w,
                                              const float* __restrict__ conv_b,
                                              int layer,
                                              u16* __restrict__ uh) {
  int idx = blockIdx.x * 256 + threadIdx.x;        // ROWS2*DI
  int c = idx & (DI - 1);
  int row = idx >> 10;
  int dir = row >> 13;
  int l = row & (L_ - 1);
  const float* cw = conv_w + (size_t)(dir * 2 + layer) * DI * 4;
  const float* cb = conv_b + (size_t)(dir * 2 + layer) * DI;
  float acc = cb[c];
#pragma unroll
  for (int j = 0; j < 4; ++j) {
    int ls = l + j - 3;
    if (ls >= 0)
      acc += bf2f(xzu[(size_t)(row + j - 3) * DI + c]) * cw[c * 4 + j];
  }
  float s = acc * sigmoidf_(acc);
  uh[idx] = f2bf(s);
}

// A-structure check
__device__ __forceinline__ bool a_fast(const float* alog, int d, float& a20) {
  a20 = -__expf(alog[d * NST]) * LN2R;
  bool fast = true;
#pragma unroll
  for (int n = 1; n < NST; ++n) {
    float an = -__expf(alog[d * NST + n]) * LN2R;
    fast &= (fabsf(an - (float)(n + 1) * a20) <= 1e-5f * (float)(n + 1) * fabsf(a20));
  }
  return fast;
}

// stage xs[CLEN][64] by summing 4 bf16 x_proj split-K partials (rowbase in rows)
__device__ __forceinline__ void stage_xs(float (*xs)[64], const u16* xp,
                                         size_t rowbase, int tid) {
  size_t base = rowbase * 64;
  const size_t P = (size_t)ROWS2 * 64;
#pragma unroll
  for (int i = 0; i < (CLEN * 64) / (8 * 256); ++i) {   // CLEN=64 -> 2 iters
    size_t e = base + ((size_t)tid + i * 256) * 8;
    us8 a = *(const us8*)(xp + e);
    us8 b = *(const us8*)(xp + P + e);
    us8 c = *(const us8*)(xp + 2 * P + e);
    us8 d = *(const us8*)(xp + 3 * P + e);
    float* dst = &xs[0][0] + ((size_t)tid + i * 256) * 8;
#pragma unroll
    for (int j = 0; j < 8; ++j)
      dst[j] = (bf2f(a[j]) + bf2f(b[j])) + (bf2f(c[j]) + bf2f(d[j]));
  }
}

// dt = softplus(dot(xs[t][0..31], w2) + bias), 4 independent accumulator chains
__device__ __forceinline__ float dt_of(const float (*xs)[64], int t,
                                       const f32x2* w2, float bias) {
  const f32x2* x = (const f32x2*)&xs[t][0];
  f32x2 a0 = {bias, 0.f}, a1 = {0.f, 0.f}, a2 = {0.f, 0.f}, a3 = {0.f, 0.f};
#pragma unroll
  for (int j = 0; j < 4; ++j) {
    a0 = pk_fma(x[4 * j],     w2[4 * j],     a0);
    a1 = pk_fma(x[4 * j + 1], w2[4 * j + 1], a1);
    a2 = pk_fma(x[4 * j + 2], w2[4 * j + 2], a2);
    a3 = pk_fma(x[4 * j + 3], w2[4 * j + 3], a3);
  }
  float a = (a0.x + a0.y) + (a1.x + a1.y) + ((a2.x + a2.y) + (a3.x + a3.y));
  return (a > 15.f) ? a : __logf(1.f + __expf(a));
}

// ---------------- pass 1: dt + local scan + y_loc + S (both dirs) ----------------
__global__ __launch_bounds__(256) void dtscan1_k(u16* uS,
                                                 const u16* __restrict__ xp,
                                                 const float* __restrict__ dtw_t,
                                                 const float* __restrict__ dtb,
                                                 const float* __restrict__ alog_,
                                                 const float* __restrict__ Dp,
                                                 int layer,
                                                 u16* __restrict__ ylg,
                                                 float* __restrict__ chk) {
  __shared__ float xs[CLEN][64];                  // 16 kB
  int blk = blockIdx.x;            // 1024 = nb(8) x chunks(32) x dgroup(4)
  int db = blk & 3;
  int c  = (blk >> 2) & (NCHUNK - 1);
  int nb = blk >> 7;               // dir*4 + b
  int dir = nb >> 2;
  int tid = threadIdx.x;
  int d  = db * 256 + tid;
  int li = dir * 2 + layer;
  const float* dtwT = dtw_t + (size_t)li * DTR * DI;
  const float* alog = alog_ + (size_t)li * DI * NST;
  int t0 = c * CLEN;
  size_t rowbase = (size_t)nb * L_ + t0;
  stage_xs(xs, xp, rowbase, tid);
  f32x2 w2[16];
#pragma unroll
  for (int j = 0; j < 16; ++j)
    w2[j] = (f32x2){dtwT[(size_t)(2 * j) * DI + d], dtwT[(size_t)(2 * j + 1) * DI + d]};
  float bias = dtb[(size_t)li * DI + d];
  float Dv = Dp[(size_t)li * DI + d];
  float a20;
  bool fast = a_fast(alog, d, a20);
  __syncthreads();
  float S = 0.f;
  size_t ubase = rowbase * DI + d;
  f32x2 h2[8];
#pragma unroll
  for (int q = 0; q < 8; ++q) h2[q] = (f32x2){0.f, 0.f};
  float uv = bf2f(uS[ubase]);
  for (int t = 0; t < CLEN; ++t) {
    float uv_nx = (t + 1 < CLEN) ? bf2f(uS[ubase + DI]) : 0.f;
    float dtv = dt_of(xs, t, w2, bias);
    float du = dtv * uv;
    S += dtv;
    f32x2 accA = {0.f, 0.f}, accB = {0.f, 0.f};
    if (fast) {
      float p1 = exp2f(dtv * a20);
      float p2 = p1 * p1;
      f32x2 pw = {p1, p2};
      f32x2 pst = {p2, p2};
      f32x2 du2 = {du, du};
#pragma unroll
      for (int k = 0; k < 4; ++k) {
        f32x4 bv = *(const f32x4*)&xs[t][DTR + k * 4];
        f32x4 cv = *(const f32x4*)&xs[t][DTR + NST + k * 4];
        f32x2 blo = __builtin_shufflevector(bv, bv, 0, 1);
        f32x2 bhi = __builtin_shufflevector(bv, bv, 2, 3);
        f32x2 clo = __builtin_shufflevector(cv, cv, 0, 1);
        f32x2 chi = __builtin_shufflevector(cv, cv, 2, 3);
        h2[2 * k]     = pk_fma(pw, h2[2 * k], pk_mul(du2, blo));
        accA          = pk_fma(h2[2 * k], clo, accA);
        pw = pk_mul(pw, pst);
        h2[2 * k + 1] = pk_fma(pw, h2[2 * k + 1], pk_mul(du2, bhi));
        accB          = pk_fma(h2[2 * k + 1], chi, accB);
        if (k < 3) pw = pk_mul(pw, pst);
      }
    } else {
#pragma unroll
      for (int q = 0; q < 8; ++q) {
        float e0 = exp2f(dtv * -__expf(alog[d * NST + 2 * q]) * LN2R);
        float e1 = exp2f(dtv * -__expf(alog[d * NST + 2 * q + 1]) * LN2R);
        f32x2 bv = *(const f32x2*)&xs[t][DTR + q * 2];
        f32x2 cv = *(const f32x2*)&xs[t][DTR + NST + q * 2];
        h2[q] = pk_fma((f32x2){e0, e1}, h2[q], pk_mul((f32x2){du, du}, bv));
        if (q & 1) accB = pk_fma(h2[q], cv, accB);
        else       accA = pk_fma(h2[q], cv, accA);
      }
    }
    float yloc = (accA.x + accA.y) + (accB.x + accB.y) + uv * Dv;
    u32 pk = cvtpk_bf16(yloc, S);   // 1 instr: lo=bf16(yloc), hi=bf16(S)
    ylg[ubase] = (u16)pk;
    uS[ubase]  = (u16)(pk >> 16);   // after uv read; same thread, same slot
    uv = uv_nx;
    ubase += DI;
  }
  const size_t H = (size_t)8 * NCHUNK * DI * NST;
  size_t idx = ((size_t)(nb * NCHUNK + c) * DI + d) * NST;
#pragma unroll
  for (int n = 0; n < NST; ++n) {
    float an = -__expf(alog[d * NST + n]) * LN2R;
    chk[idx + n]     = exp2f(an * S);
    chk[H + idx + n] = (n & 1) ? h2[n >> 1].y : h2[n >> 1].x;
  }
}

// pass 2: sequential chunk combine (both dirs)
__global__ __launch_bounds__(256) void scan2_k(float* __restrict__ chk) {
  int j = blockIdx.x * 256 + threadIdx.x;   // 131072 = 8*DI*NST
  int n = j & 15;
  int d = (j >> 4) & (DI - 1);
  int nb = j >> 14;
  const size_t H = (size_t)8 * NCHUNK * DI * NST;
  float h = 0.f;
  for (int c = 0; c < NCHUNK; ++c) {
    size_t idx = ((size_t)(nb * NCHUNK + c) * DI + d) * NST + n;
    float a = chk[idx];
    float hl = chk[H + idx];
    chk[H + idx] = h;
    h = a * h + hl;
  }
}

// pass 3 (lite): y = y_loc + sum_n C_t[n]*exp2(A2[n]*S_t)*h0[n]; fused gate.
__global__ __launch_bounds__(256) void scan3lite_k(const u16* __restrict__ uS,
                                                   const u16* __restrict__ xp,
                                                   const float* __restrict__ alog_,
                                                   int layer,
                                                   const float* __restrict__ chk,
                                                   const u16* __restrict__ xzz,
                                                   u16* ylg) {
  __shared__ float xc[CLEN][NST];                 // 4 kB: C columns only
  int blk = blockIdx.x;
  int db = blk & 3;
  int c  = (blk >> 2) & (NCHUNK - 1);
  int nb = blk >> 7;
  int dir = nb >> 2;
  int tid = threadIdx.x;
  int d  = db * 256 + tid;
  int li = dir * 2 + layer;
  const float* alog = alog_ + (size_t)li * DI * NST;
  int t0 = c * CLEN;
  size_t rowbase = (size_t)nb * L_ + t0;
  {
    int r = tid >> 2, v = tid & 3;                // 64 rows x 4 vec4
    const size_t P = (size_t)ROWS2 * 64;
    size_t e = (rowbase + r) * 64 + DTR + NST + v * 4;
    us4 a = *(const us4*)(xp + e);
    us4 b = *(const us4*)(xp + P + e);
    us4 c2 = *(const us4*)(xp + 2 * P + e);
    us4 d2 = *(const us4*)(xp + 3 * P + e);
#pragma unroll
    for (int j = 0; j < 4; ++j)
      xc[r][v * 4 + j] = (bf2f(a[j]) + bf2f(b[j])) + (bf2f(c2[j]) + bf2f(d2[j]));
  }
  float a20;
  bool fast = a_fast(alog, d, a20);
  const size_t H = (size_t)8 * NCHUNK * DI * NST;
  size_t cidx = ((size_t)(nb * NCHUNK + c) * DI + d) * NST;
  f32x2 h2[8];
#pragma unroll
  for (int q = 0; q < 8; ++q) h2[q] = *(const f32x2*)&chk[H + cidx + 2 * q];
  float A2g[NST];
  if (!fast) {
#pragma unroll
    for (int n = 0; n < NST; ++n) A2g[n] = -__expf(alog[d * NST + n]) * LN2R;
  }
  __syncthreads();
  size_t ubase = rowbase * DI + d;
  float S = bf2f(uS[ubase]);
  for (int t = 0; t < CLEN; ++t) {
    float S_nx = (t + 1 < CLEN) ? bf2f(uS[ubase + DI]) : 0.f;
    f32x2 corrA = {0.f, 0.f}, corrB = {0.f, 0.f};
    if (fast) {
      float w1 = exp2f(a20 * S);
      float w2_ = w1 * w1;
      f32x2 pw = {w1, w2_};
      f32x2 pst = {w2_, w2_};
#pragma unroll
      for (int q = 0; q < 8; ++q) {
        f32x2 cp = *(const f32x2*)&xc[t][2 * q];
        if (q & 1) corrB = pk_fma(pk_mul(pw, h2[q]), cp, corrB);
        else       corrA = pk_fma(pk_mul(pw, h2[q]), cp, corrA);
        if (q < 7) pw = pk_mul(pw, pst);
      }
    } else {
#pragma unroll
      for (int q = 0; q < 8; ++q) {
        f32x2 e = {exp2f(A2g[2 * q] * S), exp2f(A2g[2 * q + 1] * S)};
        f32x2 cp = *(const f32x2*)&xc[t][2 * q];
        if (q & 1) corrB = pk_fma(pk_mul(e, h2[q]), cp, corrB);
        else       corrA = pk_fma(pk_mul(e, h2[q]), cp, corrA);
      }
    }
    float y = bf2f(ylg[ubase]) + (corrA.x + corrA.y) + (corrB.x + corrB.y);
    float z = bf2f(xzz[ubase]);
    float g = y * z * sigmoidf_(z);
    ylg[ubase] = (u16)cvtpk_bf16(g, g);
    S = S_nx;
    ubase += DI;
  }
}

// ---------------- final rmsnorm(hid16+res) -> concat buffer, both dirs ----------------
__global__ __launch_bounds__(256) void fincat_k(const u16* __restrict__ hid,
                                                const float* __restrict__ res,
                                                const float* __restrict__ norm_f,
                                                u16* __restrict__ cat) {
  int row = blockIdx.x;                 // 0..16383
  int dir = row >> 13;
  const float* w = norm_f + (size_t)dir * DM;
  int tid = threadIdx.x;
  int base = row * DM;
  float x0 = bf2f(hid[base + tid]) + res[base + tid];
  float x1 = bf2f(hid[base + 256 + tid]) + res[base + 256 + tid];
  float s = x0 * x0 + x1 * x1;
  for (int off = 32; off; off >>= 1) s += __shfl_xor(s, off);
  __shared__ float ps[4];
  if (!(tid & 63)) ps[tid >> 6] = s;
  __syncthreads();
  float tot = ps[0] + ps[1] + ps[2] + ps[3];
  float rs = 1.f / sqrtf(tot / (float)DM + 1e-5f);
  int r = row & (ROWS - 1);
  int b = r >> 11, l = r & (L_ - 1);
  size_t drow = dir ? ((size_t)(b << 11) + (L_ - 1 - l)) : (size_t)r;
  size_t obase = drow * (2 * DM) + (size_t)dir * DM;
  cat[obase + tid]       = f2bf(x0 * rs * w[tid]);
  cat[obase + 256 + tid] = f2bf(x1 * rs * w[tid + 256]);
}

extern "C" void kernel_launch(void* const* d_in, const int* in_sizes, int n_in,
                              void* d_out, int out_size, void* d_ws, size_t ws_size,
                              hipStream_t stream) {
  const int*   ids      = (const int*)d_in[0];
  const float* embed    = (const float*)d_in[2];
  const float* in_w     = (const float*)d_in[3];
  const float* conv_w   = (const float*)d_in[4];
  const float* conv_b   = (const float*)d_in[5];
  const float* x_w      = (const float*)d_in[6];
  const float* dt_w     = (const float*)d_in[7];
  const float* dt_bias  = (const float*)d_in[8];
  const float* A_log    = (const float*)d_in[9];
  const float* Dp       = (const float*)d_in[10];
  const float* out_w    = (const float*)d_in[11];
  const float* norm_w   = (const float*)d_in[12];
  const float* norm_f   = (const float*)d_in[13];
  const float* proj_w   = (const float*)d_in[14];
  const float* proj_b   = (const float*)d_in[15];

  char* ws = (char*)d_ws;
  size_t off = 0;
  auto alloc = [&](size_t bytes) {
    void* p = ws + off;
    off += (bytes + 255) & ~(size_t)255;
    return p;
  };
  float* res  = (float*)alloc((size_t)ROWS2 * DM * 4);       // 33.6 MB
  u16*   hid16= (u16*)alloc((size_t)ROWS2 * DM * 2);         // 16.8 MB (bf16 hid)
  u16*   xpb  = (u16*)alloc((size_t)4 * ROWS2 * 64 * 2);     //  8.4 MB (x_proj bf16 partials)
  u16*   xnyg = (u16*)alloc((size_t)ROWS2 * DI * 2);         // 33.6 MB (xn | y_loc | yg)
  u16*   xzz  = (u16*)alloc((size_t)ROWS2 * DI * 2);         // 33.6 MB (z half)
  void*  shrd = alloc((size_t)ROWS2 * DI * 2);               // 33.6 MB (xzu | chk | cat)
  u16*   u_h  = (u16*)alloc((size_t)ROWS2 * DI * 2);         // 33.6 MB (uh | S)
  const int N_IN  = 4 * 2 * DI * DM;
  const int N_XW  = 4 * 64 * DI;
  const int N_OW  = 4 * DM * DI;
  const int N_PW  = DM * 2 * DM;
  const int N_DTW = 4 * DTR * DI;
  u16*   in_wb  = (u16*)alloc((size_t)N_IN * 2);             //  8.4 MB
  u16*   x_wb   = (u16*)alloc((size_t)N_XW * 2);
  u16*   out_wb = (u16*)alloc((size_t)N_OW * 2);
  u16*   pr_wb  = (u16*)alloc((size_t)N_PW * 2);
  float* dtw_t  = (float*)alloc((size_t)N_DTW * 4);
  if (off > ws_size) return;

  u16*   xzu = (u16*)shrd;
  float* chk = (float*)shrd;
  u16*   cat = (u16*)shrd;

  cvt_k<<<(N_IN / 4 + 255) / 256, 256, 0, stream>>>(in_w, in_wb, N_IN / 4);
  cvt_k<<<(N_XW / 4 + 255) / 256, 256, 0, stream>>>(x_w, x_wb, N_XW / 4);
  cvt_k<<<(N_OW / 4 + 255) / 256, 256, 0, stream>>>(out_w, out_wb, N_OW / 4);
  cvt_k<<<(N_PW / 4 + 255) / 256, 256, 0, stream>>>(proj_w, pr_wb, N_PW / 4);
  trp_k<<<N_DTW / 256, 256, 0, stream>>>(dt_w, dtw_t);

  embed_k<<<ROWS2 * DM / 256, 256, 0, stream>>>(ids, embed, res);
  for (int i = 0; i < 2; ++i) {
    if (i == 0)
      addnorm_k<false><<<ROWS2, 256, 0, stream>>>(res, hid16, norm_w, i, xnyg);
    else
      addnorm_k<true><<<ROWS2, 256, 0, stream>>>(res, hid16, norm_w, i, xnyg);
    g256_k<<<512, 512, 0, stream>>>(
        xnyg, in_wb + (size_t)i * 2 * DI * DM, xzu, xzz, DM);
    conv_k<<<ROWS2 * DI / 256, 256, 0, stream>>>(xzu, conv_w, conv_b, i, u_h);
    gemm_bt<64, EPI_BF16, 4><<<dim3(ROWS2 / 128, 4), 256, 0, stream>>>(
        u_h, x_wb + (size_t)i * 64 * DI, xpb, nullptr, 64, DI, (size_t)2 * 64 * DI);
    dtscan1_k<<<1024, 256, 0, stream>>>(u_h, xpb, dtw_t, dt_bias, A_log, Dp, i,
                                        xnyg, chk);
    scan2_k<<<512, 256, 0, stream>>>(chk);
    scan3lite_k<<<1024, 256, 0, stream>>>(u_h, xpb, A_log, i, chk, xzz, xnyg);
    gemm_bt<64, EPI_BF16><<<dim3(ROWS2 / 128, DM / 64), 256, 0, stream>>>(
        xnyg, out_wb + (size_t)i * DM * DI, hid16, nullptr, DM, DI, (size_t)2 * DM * DI);
  }
  fincat_k<<<ROWS2, 256, 0, stream>>>(hid16, res, norm_f, cat);
  gemm_bt<64, EPI_BIAS><<<dim3(ROWS / 128, DM / 64), 256, 0, stream>>>(
      cat, pr_wb, (float*)d_out, proj_b, DM, DI, 0);
}

// Round 22
// 720.473 us; speedup vs baseline: 1.0963x; 1.0007x over previous
//
#include <hip/hip_runtime.h>
#include <hip/hip_bf16.h>

#define B_   4
#define L_   2048
#define DM   512
#define DI   1024
#define NST  16
#define DTR  32
#define ROWS  (B_ * L_)        // 8192
#define ROWS2 (2 * ROWS)       // 16384 (both directions)
#define NCHUNK 32
#define CLEN  (L_ / NCHUNK)    // 64
#define LN2R 1.4426950408889634f

typedef unsigned short u16;
typedef unsigned int u32;
typedef __attribute__((ext_vector_type(8))) short bf16x8;
typedef __attribute__((ext_vector_type(8))) unsigned short us8;
typedef __attribute__((ext_vector_type(4))) unsigned short us4;
typedef __attribute__((ext_vector_type(4))) float f32x4;
typedef __attribute__((ext_vector_type(4))) float float4v;
typedef __attribute__((ext_vector_type(2))) float f32x2;

__device__ __forceinline__ float bf2f(u16 h) {
  union { unsigned int u; float f; } v; v.u = ((unsigned int)h) << 16; return v.f;
}
__device__ __forceinline__ u16 f2bf(float f) {
  union { float f; unsigned int u; } v; v.f = f;
  unsigned int u = v.u;
  if ((u & 0x7fffffffu) > 0x7f800000u) return (u16)((u >> 16) | 0x0040u);
  return (u16)((u + 0x7fffu + ((u >> 16) & 1u)) >> 16);
}
// packed f32->bf16x2 (1 instr): low = cvt(a), high = cvt(b)
__device__ __forceinline__ u32 cvtpk_bf16(float a, float b) {
  u32 r; asm("v_cvt_pk_bf16_f32 %0, %1, %2" : "=v"(r) : "v"(a), "v"(b)); return r;
}
__device__ __forceinline__ float sigmoidf_(float x) { return 1.f / (1.f + __expf(-x)); }

__device__ __forceinline__ f32x2 pk_mul(f32x2 a, f32x2 b) {
  f32x2 d; asm("v_pk_mul_f32 %0, %1, %2" : "=v"(d) : "v"(a), "v"(b)); return d;
}
__device__ __forceinline__ f32x2 pk_fma(f32x2 a, f32x2 b, f32x2 c) {
  f32x2 d; asm("v_pk_fma_f32 %0, %1, %2, %3" : "=v"(d) : "v"(a), "v"(b), "v"(c)); return d;
}

__device__ __forceinline__ void gload16(const u16* g, u16* l) {
  __builtin_amdgcn_global_load_lds(
      (const __attribute__((address_space(1))) void*)g,
      (__attribute__((address_space(3))) void*)l, 16, 0, 0);
}

// ---------------- f32 -> bf16 weight conversion ----------------
__global__ __launch_bounds__(256) void cvt_k(const float* __restrict__ in,
                                             u16* __restrict__ out, int n4) {
  int i = blockIdx.x * 256 + threadIdx.x;
  if (i >= n4) return;
  float4v v = *(const float4v*)&in[i * 4];
  u16 o[4];
  o[0] = f2bf(v.x); o[1] = f2bf(v.y); o[2] = f2bf(v.z); o[3] = f2bf(v.w);
  *(ulong1*)&out[i * 4] = *(ulong1*)o;
}

// ---------------- dt_w transpose: [4][DI][DTR] -> [4][DTR][DI] (f32) ----------------
__global__ __launch_bounds__(256) void trp_k(const float* __restrict__ in,
                                             float* __restrict__ out) {
  int o = blockIdx.x * 256 + threadIdx.x;
  int li = o >> 15;
  int k = (o >> 10) & (DTR - 1);
  int d = o & (DI - 1);
  out[o] = in[((size_t)li * DI + d) * DTR + k];
}

// ---------------- embed gather, both directions (bf16 res) ----------------
__global__ __launch_bounds__(256) void embed_k(const int* __restrict__ ids,
                                               const float* __restrict__ emb,
                                               u16* __restrict__ res) {
  int idx = blockIdx.x * 256 + threadIdx.x;   // ROWS2*DM
  int c = idx & (DM - 1);
  int row = idx >> 9;                          // 0..16383
  int dir = row >> 13;
  int r = row & (ROWS - 1);
  int b = r >> 11;
  int l = r & (L_ - 1);
  int sl = dir ? (L_ - 1 - l) : l;
  int id = ids[(b << 11) + sl];
  res[idx] = f2bf(emb[(size_t)dir * 128 * DM + id * DM + c]);
}

// ---------------- (res += hid16); xn = rmsnorm(res) * w (per-dir weights) ----------------
template <bool ADD>
__global__ __launch_bounds__(256) void addnorm_k(u16* __restrict__ res,
                                                 const u16* __restrict__ hid,
                                                 const float* __restrict__ norm_w,
                                                 int layer,
                                                 u16* __restrict__ xn) {
  int row = blockIdx.x;                        // 0..16383
  int dir = row >> 13;
  const float* w = norm_w + (size_t)(dir * 2 + layer) * DM;
  int tid = threadIdx.x;
  int base = row * DM;
  float x0 = bf2f(res[base + tid]);
  float x1 = bf2f(res[base + 256 + tid]);
  if (ADD) {
    x0 += bf2f(hid[base + tid]);
    x1 += bf2f(hid[base + 256 + tid]);
    u32 pk = cvtpk_bf16(x0, x1);
    res[base + tid] = (u16)pk;
    res[base + 256 + tid] = (u16)(pk >> 16);
    x0 = bf2f((u16)pk);                        // keep norm consistent with stored res
    x1 = bf2f((u16)(pk >> 16));
  }
  float s = x0 * x0 + x1 * x1;
  for (int off = 32; off; off >>= 1) s += __shfl_xor(s, off);
  __shared__ float ps[4];
  if (!(tid & 63)) ps[tid >> 6] = s;
  __syncthreads();
  float tot = ps[0] + ps[1] + ps[2] + ps[3];
  float rs = 1.f / sqrtf(tot / (float)DM + 1e-5f);
  xn[base + tid]       = f2bf(x0 * rs * w[tid]);
  xn[base + 256 + tid] = f2bf(x1 * rs * w[tid + 256]);
}

// ---------------- in_proj: 256x256 tile, BK=32, 2 buffers (64 kB LDS -> 2 blk/CU) ----------------
#define MFMA_B16(a, b, c) __builtin_amdgcn_mfma_f32_16x16x32_bf16(a, b, c, 0, 0, 0)

__global__ __launch_bounds__(512) void g256_k(const u16* __restrict__ A,
                                              const u16* __restrict__ W,   // layer base (dir0)
                                              u16* __restrict__ outU,
                                              u16* __restrict__ outZ,
                                              int K) {
  __shared__ u16 As[2][256 * 32];   // 32 kB
  __shared__ u16 Wsh[2][256 * 32];  // 32 kB
  int tid = threadIdx.x;
  int lane = tid & 63;
  int wv = tid >> 6;
  int wr = wv >> 2, wc = wv & 3;    // 2M x 4N waves
  int bid = blockIdx.x;             // 512 blocks: 64 mt x 8 nt
  int xcd = bid & 7, jj = bid >> 3;
  int mt = xcd * 8 + (jj & 7);      // 0..63
  int nt = jj >> 3;                 // 0..7
  int m0 = mt * 256, n0 = nt * 256;
  const u16* Weff = W + (size_t)(m0 >> 13) * (size_t)2 * (2 * DI) * DM;
  f32x4 acc[8][4];
#pragma unroll
  for (int i = 0; i < 8; ++i)
#pragma unroll
    for (int j = 0; j < 4; ++j) acc[i][j] = (f32x4){0.f, 0.f, 0.f, 0.f};
  int rr = lane & 15;
  int sl = lane >> 4;
  int pofs = ((sl + (rr >> 1)) & 3) * 8;    // conflict-free swizzled read slot
  int lr = lane >> 2;
  int ls = ((lane & 3) - (lr >> 1)) & 3;    // matching pre-swizzled source slot

  auto stage = [&](int tau, int buf) {
#pragma unroll
    for (int j = 0; j < 2; ++j) {
      gload16(A + (size_t)(m0 + j * 128 + wv * 16 + lr) * K + tau * 32 + ls * 8,
              &As[buf][(j * 128 + wv * 16) * 32]);
      gload16(Weff + (size_t)(n0 + j * 128 + wv * 16 + lr) * K + tau * 32 + ls * 8,
              &Wsh[buf][(j * 128 + wv * 16) * 32]);
    }
  };

  int NK = K / 32;                  // 16
  stage(0, 0);
  for (int tau = 0; tau < NK; ++tau) {
    int buf = tau & 1;
    bool more = (tau + 1 < NK);
    if (more) stage(tau + 1, buf ^ 1);
    if (more)
      asm volatile("s_waitcnt vmcnt(4)" ::: "memory");
    else
      asm volatile("s_waitcnt vmcnt(0)" ::: "memory");
    __builtin_amdgcn_sched_barrier(0);
    __builtin_amdgcn_s_barrier();
    __builtin_amdgcn_sched_barrier(0);
    bf16x8 af[8], wf[4];
#pragma unroll
    for (int mi = 0; mi < 8; ++mi)
      af[mi] = *(bf16x8*)&As[buf][(wr * 128 + mi * 16 + rr) * 32 + pofs];
#pragma unroll
    for (int ni = 0; ni < 4; ++ni)
      wf[ni] = *(bf16x8*)&Wsh[buf][(wc * 64 + ni * 16 + rr) * 32 + pofs];
    __builtin_amdgcn_s_setprio(1);
#pragma unroll
    for (int mi = 0; mi < 8; ++mi)
#pragma unroll
      for (int ni = 0; ni < 4; ++ni)
        acc[mi][ni] = MFMA_B16(af[mi], wf[ni], acc[mi][ni]);
    __builtin_amdgcn_s_setprio(0);
    asm volatile("s_waitcnt lgkmcnt(0)" ::: "memory");
    __builtin_amdgcn_sched_barrier(0);
    __builtin_amdgcn_s_barrier();
    __builtin_amdgcn_sched_barrier(0);
  }
  int cr = (lane >> 4) << 2;
  int cc = lane & 15;
  u16* outp = (n0 < DI) ? outU : outZ;
  int cb0 = (n0 < DI) ? n0 : (n0 - DI);
#pragma unroll
  for (int mi = 0; mi < 8; ++mi)
#pragma unroll
    for (int ni = 0; ni < 4; ++ni) {
      int row = m0 + wr * 128 + mi * 16 + cr;
      int col = cb0 + wc * 64 + ni * 16 + cc;
#pragma unroll
      for (int j = 0; j < 4; ++j)
        outp[(size_t)(row + j) * DI + col] = f2bf(acc[mi][ni][j]);
    }
}

// ---------------- GEMM (generic): 4-ring, stage-ahead-3, per-dir weight stride ----------------
#define EPI_F32  0
#define EPI_BF16 1
#define EPI_BIAS 2

template <int BN, int EPI, int SK = 1>
__global__ __launch_bounds__(256) void gemm_bt(const u16* __restrict__ A,
                                               const u16* __restrict__ W,
                                               void* __restrict__ outp,
                                               const float* __restrict__ bias,
                                               int N, int K, size_t wsd) {
  constexpr int BM = 128, BK = 32;
  constexpr int NF = BN / 32;
  constexpr int G = (BN == 128) ? 4 : 3;
  __shared__ u16 As[4][BM * BK];
  __shared__ u16 Wsh[4][BN * BK];
  int tid = threadIdx.x;
  int lane = tid & 63;
  int wv = tid >> 6;
  int wr = wv >> 1, wc = wv & 1;
  int m0 = blockIdx.x * BM;
  int n0 = (SK > 1) ? 0 : blockIdx.y * BN;
  int koff = (SK > 1) ? blockIdx.y * (K / SK) : 0;
  int KS = K / SK;
  int NK = KS / BK;
  const u16* Weff = W + (size_t)(m0 >> 13) * wsd;
  f32x4 acc[4][NF];
#pragma unroll
  for (int i = 0; i < 4; ++i)
#pragma unroll
    for (int j = 0; j < NF; ++j) acc[i][j] = (f32x4){0.f, 0.f, 0.f, 0.f};
  int rr = lane & 15;
  int kk = (lane >> 4) << 3;
  int l4 = lane >> 2;
  int c8 = (lane & 3) << 3;
  const u16* Ag = A + (size_t)(m0 + l4) * K + koff + c8;
  const u16* Wg = Weff + (size_t)(n0 + l4) * K + koff + c8;

  auto stage = [&](int k0, int buf) {
    gload16(Ag + (size_t)(wv * 16) * K + k0, &As[buf][wv * 512]);
    gload16(Ag + (size_t)((wv + 4) * 16) * K + k0, &As[buf][(wv + 4) * 512]);
    gload16(Wg + (size_t)(wv * 16) * K + k0, &Wsh[buf][wv * 512]);
    if (BN == 128)
      gload16(Wg + (size_t)((wv + 4) * 16) * K + k0, &Wsh[buf][(wv + 4) * 512]);
  };

  stage(0, 0); stage(BK, 1); stage(2 * BK, 2);
  for (int k = 0; k < NK; ++k) {
    if (k < NK - 2)
      asm volatile("s_waitcnt vmcnt(%0)" :: "n"(2 * G) : "memory");
    else if (k == NK - 2)
      asm volatile("s_waitcnt vmcnt(%0)" :: "n"(G) : "memory");
    else
      asm volatile("s_waitcnt vmcnt(0)" ::: "memory");
    __builtin_amdgcn_s_barrier();
    __builtin_amdgcn_sched_barrier(0);
    if (k + 3 < NK) stage((k + 3) * BK, (k + 3) & 3);
    __builtin_amdgcn_sched_barrier(0);
    int cur = k & 3;
    bf16x8 af[4], wf[NF];
#pragma unroll
    for (int mi = 0; mi < 4; ++mi)
      af[mi] = *(bf16x8*)&As[cur][(wr * 64 + mi * 16 + rr) * BK + kk];
#pragma unroll
    for (int ni = 0; ni < NF; ++ni)
      wf[ni] = *(bf16x8*)&Wsh[cur][(wc * (BN / 2) + ni * 16 + rr) * BK + kk];
#pragma unroll
    for (int mi = 0; mi < 4; ++mi)
#pragma unroll
      for (int ni = 0; ni < NF; ++ni)
        acc[mi][ni] = __builtin_amdgcn_mfma_f32_16x16x32_bf16(af[mi], wf[ni], acc[mi][ni], 0, 0, 0);
  }
  int cr = (lane >> 4) << 2;
  int cc = lane & 15;
  size_t poff = (SK > 1) ? (size_t)blockIdx.y * (size_t)gridDim.x * BM * N : 0;
#pragma unroll
  for (int mi = 0; mi < 4; ++mi)
#pragma unroll
    for (int ni = 0; ni < NF; ++ni) {
      int row = m0 + wr * 64 + mi * 16 + cr;
      int col = n0 + wc * (BN / 2) + ni * 16 + cc;
      float bv = (EPI == EPI_BIAS) ? bias[col] : 0.f;
#pragma unroll
      for (int j = 0; j < 4; ++j) {
        float v = acc[mi][ni][j] + bv;
        if (EPI == EPI_BF16)
          ((u16*)outp)[poff + (size_t)(row + j) * N + col] = f2bf(v);
        else
          ((float*)outp)[poff + (size_t)(row + j) * N + col] = v;
      }
    }
}

// ---------------- depthwise causal conv + SiLU, both dirs ----------------
__global__ __launch_bounds__(256) void conv_k(const u16* __restrict__ xzu,
                                              const float* __restrict__ conv_w,
                                              const float* __restrict__ conv_b,
                                              int layer,
                                              u16* __restrict__ uh) {
  int idx = blockIdx.x * 256 + threadIdx.x;        // ROWS2*DI
  int c = idx & (DI - 1);
  int row = idx >> 10;
  int dir = row >> 13;
  int l = row & (L_ - 1);
  const float* cw = conv_w + (size_t)(dir * 2 + layer) * DI * 4;
  const float* cb = conv_b + (size_t)(dir * 2 + layer) * DI;
  float acc = cb[c];
#pragma unroll
  for (int j = 0; j < 4; ++j) {
    int ls = l + j - 3;
    if (ls >= 0)
      acc += bf2f(xzu[(size_t)(row + j - 3) * DI + c]) * cw[c * 4 + j];
  }
  float s = acc * sigmoidf_(acc);
  uh[idx] = f2bf(s);
}

// A-structure check
__device__ __forceinline__ bool a_fast(const float* alog, int d, float& a20) {
  a20 = -__expf(alog[d * NST]) * LN2R;
  bool fast = true;
#pragma unroll
  for (int n = 1; n < NST; ++n) {
    float an = -__expf(alog[d * NST + n]) * LN2R;
    fast &= (fabsf(an - (float)(n + 1) * a20) <= 1e-5f * (float)(n + 1) * fabsf(a20));
  }
  return fast;
}

// stage xs[CLEN][64] by summing 4 bf16 x_proj split-K partials (rowbase in rows)
__device__ __forceinline__ void stage_xs(float (*xs)[64], const u16* xp,
                                         size_t rowbase, int tid) {
  size_t base = rowbase * 64;
  const size_t P = (size_t)ROWS2 * 64;
#pragma unroll
  for (int i = 0; i < (CLEN * 64) / (8 * 256); ++i) {   // CLEN=64 -> 2 iters
    size_t e = base + ((size_t)tid + i * 256) * 8;
    us8 a = *(const us8*)(xp + e);
    us8 b = *(const us8*)(xp + P + e);
    us8 c = *(const us8*)(xp + 2 * P + e);
    us8 d = *(const us8*)(xp + 3 * P + e);
    float* dst = &xs[0][0] + ((size_t)tid + i * 256) * 8;
#pragma unroll
    for (int j = 0; j < 8; ++j)
      dst[j] = (bf2f(a[j]) + bf2f(b[j])) + (bf2f(c[j]) + bf2f(d[j]));
  }
}

// dt = softplus(dot(xs[t][0..31], w2) + bias), 4 independent accumulator chains
__device__ __forceinline__ float dt_of(const float (*xs)[64], int t,
                                       const f32x2* w2, float bias) {
  const f32x2* x = (const f32x2*)&xs[t][0];
  f32x2 a0 = {bias, 0.f}, a1 = {0.f, 0.f}, a2 = {0.f, 0.f}, a3 = {0.f, 0.f};
#pragma unroll
  for (int j = 0; j < 4; ++j) {
    a0 = pk_fma(x[4 * j],     w2[4 * j],     a0);
    a1 = pk_fma(x[4 * j + 1], w2[4 * j + 1], a1);
    a2 = pk_fma(x[4 * j + 2], w2[4 * j + 2], a2);
    a3 = pk_fma(x[4 * j + 3], w2[4 * j + 3], a3);
  }
  float a = (a0.x + a0.y) + (a1.x + a1.y) + ((a2.x + a2.y) + (a3.x + a3.y));
  return (a > 15.f) ? a : __logf(1.f + __expf(a));
}

// ---------------- pass 1: dt + local scan + y_loc + S (both dirs) ----------------
__global__ __launch_bounds__(256) void dtscan1_k(u16* uS,
                                                 const u16* __restrict__ xp,
                                                 const float* __restrict__ dtw_t,
                                                 const float* __restrict__ dtb,
                                                 const float* __restrict__ alog_,
                                                 const float* __restrict__ Dp,
                                                 int layer,
                                                 u16* __restrict__ ylg,
                                                 float* __restrict__ chk) {
  __shared__ float xs[CLEN][64];                  // 16 kB
  int blk = blockIdx.x;            // 1024 = nb(8) x chunks(32) x dgroup(4)
  int db = blk & 3;
  int c  = (blk >> 2) & (NCHUNK - 1);
  int nb = blk >> 7;               // dir*4 + b
  int dir = nb >> 2;
  int tid = threadIdx.x;
  int d  = db * 256 + tid;
  int li = dir * 2 + layer;
  const float* dtwT = dtw_t + (size_t)li * DTR * DI;
  const float* alog = alog_ + (size_t)li * DI * NST;
  int t0 = c * CLEN;
  size_t rowbase = (size_t)nb * L_ + t0;
  stage_xs(xs, xp, rowbase, tid);
  f32x2 w2[16];
#pragma unroll
  for (int j = 0; j < 16; ++j)
    w2[j] = (f32x2){dtwT[(size_t)(2 * j) * DI + d], dtwT[(size_t)(2 * j + 1) * DI + d]};
  float bias = dtb[(size_t)li * DI + d];
  float Dv = Dp[(size_t)li * DI + d];
  float a20;
  bool fast = a_fast(alog, d, a20);
  __syncthreads();
  float S = 0.f;
  size_t ubase = rowbase * DI + d;
  f32x2 h2[8];
#pragma unroll
  for (int q = 0; q < 8; ++q) h2[q] = (f32x2){0.f, 0.f};
  float uv = bf2f(uS[ubase]);
  for (int t = 0; t < CLEN; ++t) {
    float uv_nx = (t + 1 < CLEN) ? bf2f(uS[ubase + DI]) : 0.f;
    float dtv = dt_of(xs, t, w2, bias);
    float du = dtv * uv;
    S += dtv;
    f32x2 accA = {0.f, 0.f}, accB = {0.f, 0.f};
    if (fast) {
      float p1 = exp2f(dtv * a20);
      float p2 = p1 * p1;
      f32x2 pw = {p1, p2};
      f32x2 pst = {p2, p2};
      f32x2 du2 = {du, du};
#pragma unroll
      for (int k = 0; k < 4; ++k) {
        f32x4 bv = *(const f32x4*)&xs[t][DTR + k * 4];
        f32x4 cv = *(const f32x4*)&xs[t][DTR + NST + k * 4];
        f32x2 blo = __builtin_shufflevector(bv, bv, 0, 1);
        f32x2 bhi = __builtin_shufflevector(bv, bv, 2, 3);
        f32x2 clo = __builtin_shufflevector(cv, cv, 0, 1);
        f32x2 chi = __builtin_shufflevector(cv, cv, 2, 3);
        h2[2 * k]     = pk_fma(pw, h2[2 * k], pk_mul(du2, blo));
        accA          = pk_fma(h2[2 * k], clo, accA);
        pw = pk_mul(pw, pst);
        h2[2 * k + 1] = pk_fma(pw, h2[2 * k + 1], pk_mul(du2, bhi));
        accB          = pk_fma(h2[2 * k + 1], chi, accB);
        if (k < 3) pw = pk_mul(pw, pst);
      }
    } else {
#pragma unroll
      for (int q = 0; q < 8; ++q) {
        float e0 = exp2f(dtv * -__expf(alog[d * NST + 2 * q]) * LN2R);
        float e1 = exp2f(dtv * -__expf(alog[d * NST + 2 * q + 1]) * LN2R);
        f32x2 bv = *(const f32x2*)&xs[t][DTR + q * 2];
        f32x2 cv = *(const f32x2*)&xs[t][DTR + NST + q * 2];
        h2[q] = pk_fma((f32x2){e0, e1}, h2[q], pk_mul((f32x2){du, du}, bv));
        if (q & 1) accB = pk_fma(h2[q], cv, accB);
        else       accA = pk_fma(h2[q], cv, accA);
      }
    }
    float yloc = (accA.x + accA.y) + (accB.x + accB.y) + uv * Dv;
    u32 pk = cvtpk_bf16(yloc, S);   // 1 instr: lo=bf16(yloc), hi=bf16(S)
    ylg[ubase] = (u16)pk;
    uS[ubase]  = (u16)(pk >> 16);   // after uv read; same thread, same slot
    uv = uv_nx;
    ubase += DI;
  }
  const size_t H = (size_t)8 * NCHUNK * DI * NST;
  size_t idx = ((size_t)(nb * NCHUNK + c) * DI + d) * NST;
#pragma unroll
  for (int n = 0; n < NST; ++n) {
    float an = -__expf(alog[d * NST + n]) * LN2R;
    chk[idx + n]     = exp2f(an * S);
    chk[H + idx + n] = (n & 1) ? h2[n >> 1].y : h2[n >> 1].x;
  }
}

// pass 2: sequential chunk combine (both dirs)
__global__ __launch_bounds__(256) void scan2_k(float* __restrict__ chk) {
  int j = blockIdx.x * 256 + threadIdx.x;   // 131072 = 8*DI*NST
  int n = j & 15;
  int d = (j >> 4) & (DI - 1);
  int nb = j >> 14;
  const size_t H = (size_t)8 * NCHUNK * DI * NST;
  float h = 0.f;
  for (int c = 0; c < NCHUNK; ++c) {
    size_t idx = ((size_t)(nb * NCHUNK + c) * DI + d) * NST + n;
    float a = chk[idx];
    float hl = chk[H + idx];
    chk[H + idx] = h;
    h = a * h + hl;
  }
}

// pass 3 (lite): y = y_loc + sum_n C_t[n]*exp2(A2[n]*S_t)*h0[n]; fused gate.
__global__ __launch_bounds__(256) void scan3lite_k(const u16* __restrict__ uS,
                                                   const u16* __restrict__ xp,
                                                   const float* __restrict__ alog_,
                                                   int layer,
                                                   const float* __restrict__ chk,
                                                   const u16* __restrict__ xzz,
                                                   u16* ylg) {
  __shared__ float xc[CLEN][NST];                 // 4 kB: C columns only
  int blk = blockIdx.x;
  int db = blk & 3;
  int c  = (blk >> 2) & (NCHUNK - 1);
  int nb = blk >> 7;
  int dir = nb >> 2;
  int tid = threadIdx.x;
  int d  = db * 256 + tid;
  int li = dir * 2 + layer;
  const float* alog = alog_ + (size_t)li * DI * NST;
  int t0 = c * CLEN;
  size_t rowbase = (size_t)nb * L_ + t0;
  {
    int r = tid >> 2, v = tid & 3;                // 64 rows x 4 vec4
    const size_t P = (size_t)ROWS2 * 64;
    size_t e = (rowbase + r) * 64 + DTR + NST + v * 4;
    us4 a = *(const us4*)(xp + e);
    us4 b = *(const us4*)(xp + P + e);
    us4 c2 = *(const us4*)(xp + 2 * P + e);
    us4 d2 = *(const us4*)(xp + 3 * P + e);
#pragma unroll
    for (int j = 0; j < 4; ++j)
      xc[r][v * 4 + j] = (bf2f(a[j]) + bf2f(b[j])) + (bf2f(c2[j]) + bf2f(d2[j]));
  }
  float a20;
  bool fast = a_fast(alog, d, a20);
  const size_t H = (size_t)8 * NCHUNK * DI * NST;
  size_t cidx = ((size_t)(nb * NCHUNK + c) * DI + d) * NST;
  f32x2 h2[8];
#pragma unroll
  for (int q = 0; q < 8; ++q) h2[q] = *(const f32x2*)&chk[H + cidx + 2 * q];
  float A2g[NST];
  if (!fast) {
#pragma unroll
    for (int n = 0; n < NST; ++n) A2g[n] = -__expf(alog[d * NST + n]) * LN2R;
  }
  __syncthreads();
  size_t ubase = rowbase * DI + d;
  float S = bf2f(uS[ubase]);
  for (int t = 0; t < CLEN; ++t) {
    float S_nx = (t + 1 < CLEN) ? bf2f(uS[ubase + DI]) : 0.f;
    f32x2 corrA = {0.f, 0.f}, corrB = {0.f, 0.f};
    if (fast) {
      float w1 = exp2f(a20 * S);
      float w2_ = w1 * w1;
      f32x2 pw = {w1, w2_};
      f32x2 pst = {w2_, w2_};
#pragma unroll
      for (int q = 0; q < 8; ++q) {
        f32x2 cp = *(const f32x2*)&xc[t][2 * q];
        if (q & 1) corrB = pk_fma(pk_mul(pw, h2[q]), cp, corrB);
        else       corrA = pk_fma(pk_mul(pw, h2[q]), cp, corrA);
        if (q < 7) pw = pk_mul(pw, pst);
      }
    } else {
#pragma unroll
      for (int q = 0; q < 8; ++q) {
        f32x2 e = {exp2f(A2g[2 * q] * S), exp2f(A2g[2 * q + 1] * S)};
        f32x2 cp = *(const f32x2*)&xc[t][2 * q];
        if (q & 1) corrB = pk_fma(pk_mul(e, h2[q]), cp, corrB);
        else       corrA = pk_fma(pk_mul(e, h2[q]), cp, corrA);
      }
    }
    float y = bf2f(ylg[ubase]) + (corrA.x + corrA.y) + (corrB.x + corrB.y);
    float z = bf2f(xzz[ubase]);
    float g = y * z * sigmoidf_(z);
    ylg[ubase] = (u16)cvtpk_bf16(g, g);
    S = S_nx;
    ubase += DI;
  }
}

// ---------------- final rmsnorm(hid16+res16) -> concat buffer, both dirs ----------------
__global__ __launch_bounds__(256) void fincat_k(const u16* __restrict__ hid,
                                                const u16* __restrict__ res,
                                                const float* __restrict__ norm_f,
                                                u16* __restrict__ cat) {
  int row = blockIdx.x;                 // 0..16383
  int dir = row >> 13;
  const float* w = norm_f + (size_t)dir * DM;
  int tid = threadIdx.x;
  int base = row * DM;
  float x0 = bf2f(hid[base + tid]) + bf2f(res[base + tid]);
  float x1 = bf2f(hid[base + 256 + tid]) + bf2f(res[base + 256 + tid]);
  float s = x0 * x0 + x1 * x1;
  for (int off = 32; off; off >>= 1) s += __shfl_xor(s, off);
  __shared__ float ps[4];
  if (!(tid & 63)) ps[tid >> 6] = s;
  __syncthreads();
  float tot = ps[0] + ps[1] + ps[2] + ps[3];
  float rs = 1.f / sqrtf(tot / (float)DM + 1e-5f);
  int r = row & (ROWS - 1);
  int b = r >> 11, l = r & (L_ - 1);
  size_t drow = dir ? ((size_t)(b << 11) + (L_ - 1 - l)) : (size_t)r;
  size_t obase = drow * (2 * DM) + (size_t)dir * DM;
  cat[obase + tid]       = f2bf(x0 * rs * w[tid]);
  cat[obase + 256 + tid] = f2bf(x1 * rs * w[tid + 256]);
}

extern "C" void kernel_launch(void* const* d_in, const int* in_sizes, int n_in,
                              void* d_out, int out_size, void* d_ws, size_t ws_size,
                              hipStream_t stream) {
  const int*   ids      = (const int*)d_in[0];
  const float* embed    = (const float*)d_in[2];
  const float* in_w     = (const float*)d_in[3];
  const float* conv_w   = (const float*)d_in[4];
  const float* conv_b   = (const float*)d_in[5];
  const float* x_w      = (const float*)d_in[6];
  const float* dt_w     = (const float*)d_in[7];
  const float* dt_bias  = (const float*)d_in[8];
  const float* A_log    = (const float*)d_in[9];
  const float* Dp       = (const float*)d_in[10];
  const float* out_w    = (const float*)d_in[11];
  const float* norm_w   = (const float*)d_in[12];
  const float* norm_f   = (const float*)d_in[13];
  const float* proj_w   = (const float*)d_in[14];
  const float* proj_b   = (const float*)d_in[15];

  char* ws = (char*)d_ws;
  size_t off = 0;
  auto alloc = [&](size_t bytes) {
    void* p = ws + off;
    off += (bytes + 255) & ~(size_t)255;
    return p;
  };
  u16*   res16= (u16*)alloc((size_t)ROWS2 * DM * 2);         // 16.8 MB (bf16 res)
  u16*   hid16= (u16*)alloc((size_t)ROWS2 * DM * 2);         // 16.8 MB (bf16 hid)
  u16*   xpb  = (u16*)alloc((size_t)4 * ROWS2 * 64 * 2);     //  8.4 MB (x_proj bf16 partials)
  u16*   xnyg = (u16*)alloc((size_t)ROWS2 * DI * 2);         // 33.6 MB (xn | y_loc | yg)
  u16*   xzz  = (u16*)alloc((size_t)ROWS2 * DI * 2);         // 33.6 MB (z half)
  void*  shrd = alloc((size_t)ROWS2 * DI * 2);               // 33.6 MB (xzu | chk | cat)
  u16*   u_h  = (u16*)alloc((size_t)ROWS2 * DI * 2);         // 33.6 MB (uh | S)
  const int N_IN  = 4 * 2 * DI * DM;
  const int N_XW  = 4 * 64 * DI;
  const int N_OW  = 4 * DM * DI;
  const int N_PW  = DM * 2 * DM;
  const int N_DTW = 4 * DTR * DI;
  u16*   in_wb  = (u16*)alloc((size_t)N_IN * 2);             //  8.4 MB
  u16*   x_wb   = (u16*)alloc((size_t)N_XW * 2);
  u16*   out_wb = (u16*)alloc((size_t)N_OW * 2);
  u16*   pr_wb  = (u16*)alloc((size_t)N_PW * 2);
  float* dtw_t  = (float*)alloc((size_t)N_DTW * 4);
  if (off > ws_size) return;

  u16*   xzu = (u16*)shrd;
  float* chk = (float*)shrd;
  u16*   cat = (u16*)shrd;

  cvt_k<<<(N_IN / 4 + 255) / 256, 256, 0, stream>>>(in_w, in_wb, N_IN / 4);
  cvt_k<<<(N_XW / 4 + 255) / 256, 256, 0, stream>>>(x_w, x_wb, N_XW / 4);
  cvt_k<<<(N_OW / 4 + 255) / 256, 256, 0, stream>>>(out_w, out_wb, N_OW / 4);
  cvt_k<<<(N_PW / 4 + 255) / 256, 256, 0, stream>>>(proj_w, pr_wb, N_PW / 4);
  trp_k<<<N_DTW / 256, 256, 0, stream>>>(dt_w, dtw_t);

  embed_k<<<ROWS2 * DM / 256, 256, 0, stream>>>(ids, embed, res16);
  for (int i = 0; i < 2; ++i) {
    if (i == 0)
      addnorm_k<false><<<ROWS2, 256, 0, stream>>>(res16, hid16, norm_w, i, xnyg);
    else
      addnorm_k<true><<<ROWS2, 256, 0, stream>>>(res16, hid16, norm_w, i, xnyg);
    g256_k<<<512, 512, 0, stream>>>(
        xnyg, in_wb + (size_t)i * 2 * DI * DM, xzu, xzz, DM);
    conv_k<<<ROWS2 * DI / 256, 256, 0, stream>>>(xzu, conv_w, conv_b, i, u_h);
    gemm_bt<64, EPI_BF16, 4><<<dim3(ROWS2 / 128, 4), 256, 0, stream>>>(
        u_h, x_wb + (size_t)i * 64 * DI, xpb, nullptr, 64, DI, (size_t)2 * 64 * DI);
    dtscan1_k<<<1024, 256, 0, stream>>>(u_h, xpb, dtw_t, dt_bias, A_log, Dp, i,
                                        xnyg, chk);
    scan2_k<<<512, 256, 0, stream>>>(chk);
    scan3lite_k<<<1024, 256, 0, stream>>>(u_h, xpb, A_log, i, chk, xzz, xnyg);
    gemm_bt<64, EPI_BF16><<<dim3(ROWS2 / 128, DM / 64), 256, 0, stream>>>(
        xnyg, out_wb + (size_t)i * DM * DI, hid16, nullptr, DM, DI, (size_t)2 * DM * DI);
  }
  fincat_k<<<ROWS2, 256, 0, stream>>>(hid16, res16, norm_f, cat);
  gemm_bt<64, EPI_BIAS><<<dim3(ROWS / 128, DM / 64), 256, 0, stream>>>(
      cat, pr_wb, (float*)d_out, proj_b, DM, DI, 0);
}